// Round 1
// 1190.478 us; speedup vs baseline: 1.4425x; 1.4425x over previous
//
#include <hip/hip_runtime.h>
#include <math.h>

#define PIXN 4096

typedef _Float16 f16;
typedef short s16x8 __attribute__((ext_vector_type(8)));
typedef unsigned short u16x4 __attribute__((ext_vector_type(4)));
typedef float f32x4 __attribute__((ext_vector_type(4)));

__device__ __forceinline__ f16 f2h(float f) { return (f16)f; }
__device__ __forceinline__ float h2f(f16 h) { return (float)h; }

// bf16 round-to-nearest-even via bit trick; residual f - bf2f(f2bf(f)) is exact in fp32.
__device__ __forceinline__ unsigned short f2bf(float f) {
  unsigned u = __float_as_uint(f);
  u += 0x7fffu + ((u >> 16) & 1u);
  return (unsigned short)(u >> 16);
}
__device__ __forceinline__ float bf2f(unsigned short h) {
  return __uint_as_float(((unsigned)h) << 16);
}

enum { ACT_NONE = 0, ACT_LRELU = 1, ACT_SIG144 = 2 };
enum { IN_NCHW = 0, IN_FLAT = 1, IN_UVPAIR = 2, IN_QKV = 3 };
enum { OUT_FLAT = 0, OUT_NCHWRES = 1 };

// ---------------- fused weight prep ----------------
__device__ __forceinline__ void wtrans_dev(const float* __restrict__ w, float* __restrict__ wT,
                                           int srcCIN, int cinOff, int dstCIN, int COUTv,
                                           int total, int idx) {
  if (idx >= total) return;
  int co = idx % COUTv;
  int t = idx / COUTv;
  int ci = t % dstCIN;
  int tap = t / dstCIN;
  wT[idx] = w[((long)co * srcCIN + cinOff + ci) * 9 + tap];
}

// MFMA weight prep: layout [tap][kc][kch][co][8e], hi plane then lo plane (each `total` elems).
__device__ __forceinline__ void wprep_mfma(const float* __restrict__ w, unsigned short* __restrict__ dst,
                                           int srcCIN, int cinOff, int COUTv, int COUTP,
                                           int total, int idx) {
  if (idx >= total) return;
  int e = idx & 7;
  int t = idx >> 3;
  int co = t % COUTP; t /= COUTP;
  int kch = t & 3; t >>= 2;
  int kc = t % 3;
  int tap = t / 3;
  int ci = kc * 32 + kch * 8 + e;
  float v = 0.f;
  if (co < COUTv) v = w[((long)co * srcCIN + cinOff + ci) * 9 + tap];
  unsigned short h = f2bf(v);
  dst[idx] = h;
  dst[total + idx] = f2bf(v - bf2f(h));
}

__global__ __launch_bounds__(256) void prep_all(
    const float* __restrict__ cf_w, const float* __restrict__ oc1_w,
    const float* __restrict__ oc2_w, const float* __restrict__ om_w,
    const float* __restrict__ cl_w,
    const float* __restrict__ wq, const float* __restrict__ wk, const float* __restrict__ wv,
    const float* __restrict__ bq, const float* __restrict__ bk, const float* __restrict__ bv,
    float* __restrict__ T0, float* __restrict__ T4,
    unsigned short* __restrict__ WB1, unsigned short* __restrict__ WB2,
    unsigned short* __restrict__ WB3,
    float* __restrict__ WQKV, float* __restrict__ BQKV) {
  int idx = blockIdx.x * 256 + threadIdx.x;
  switch (blockIdx.y) {
    case 0: wtrans_dev(cf_w, T0, 64, 0, 64, 96, 55296, idx); break;
    case 1: wtrans_dev(cl_w, T4, 96, 0, 96, 64, 55296, idx); break;
    case 2: {
      if (idx < 96 * 288) {
        int e288 = idx % 288;
        int c = idx / 288;
        int m = e288 / 96, e = e288 % 96;
        const float* wm = (m == 0) ? wq : (m == 1) ? wk : wv;
        WQKV[idx] = wm[e * 96 + c];
      }
      if (idx < 288) {
        int m = idx / 96, e = idx % 96;
        const float* bm = (m == 0) ? bq : (m == 1) ? bk : bv;
        BQKV[idx] = bm[e];
      }
      break;
    }
    case 3: wprep_mfma(oc1_w, WB1, 192, 0, 96, 96, 82944, idx); break;
    case 4: wprep_mfma(oc1_w, WB1 + 2 * 82944, 192, 96, 96, 96, 82944, idx); break;
    case 5: wprep_mfma(oc2_w, WB2, 96, 0, 96, 96, 82944, idx); break;
    default: wprep_mfma(om_w, WB3, 96, 0, 216, 224, 193536, idx); break;
  }
}

// ---------------- fp32 3x3 conv, GEMV-style (kept for emb + final) ----------------
template <int CIN, int COUT, int CG, int ACT, int IMODE, int OMODE, bool QKVIN>
__global__ __launch_bounds__(256) void conv3x3v4(
    const float* __restrict__ in, const float* __restrict__ in2,
    const float* __restrict__ bias_in,
    const float* __restrict__ wT,
    const float* __restrict__ bias,
    float* __restrict__ out,
    const float* __restrict__ resid) {
  constexpr int NOCG = COUT / CG;
  constexpr int NCH = CIN / 8;
  const int y0 = blockIdx.x * 4;
  const int iz = blockIdx.y;
  const int cg = blockIdx.z;
  const int tid = threadIdx.x;
  const int x = tid & 63;
  const int wv = tid >> 6;
  const int ocb = cg * NOCG;

  __shared__ float lds[6 * 66 * 9];

  const float* baseA;
  const float* wTe = wT;
  if constexpr (IMODE == IN_NCHW) {
    baseA = in + (long)iz * (CIN * PIXN);
  } else {
    baseA = in + (long)iz * (PIXN * CIN);
  }

  float acc[NOCG];
#pragma unroll
  for (int j = 0; j < NOCG; ++j) acc[j] = bias ? bias[ocb + j] : 0.f;

#pragma unroll 1
  for (int ch = 0; ch < NCH; ++ch) {
    __syncthreads();
    if constexpr (IMODE == IN_NCHW) {
      for (int i = tid; i < 8 * 396; i += 256) {
        int cin = i / 396;
        int t = i - cin * 396;
        int r = t / 66, px = t - r * 66;
        int yy = y0 - 1 + r, xx = px - 1;
        float v = 0.f;
        if ((unsigned)yy < 64u && (unsigned)xx < 64u)
          v = baseA[(long)(ch * 8 + cin) * PIXN + yy * 64 + xx];
        lds[t * 9 + cin] = v;
      }
    } else {
      for (int i = tid; i < 396 * 2; i += 256) {
        int c4 = i & 1, t = i >> 1;
        int r = t / 66, px = t - r * 66;
        int yy = y0 - 1 + r, xx = px - 1;
        float4 v = make_float4(0.f, 0.f, 0.f, 0.f);
        if ((unsigned)yy < 64u && (unsigned)xx < 64u)
          v = *reinterpret_cast<const float4*>(
              baseA + (long)(yy * 64 + xx) * CIN + ch * 8 + c4 * 4);
        int b0 = t * 9 + c4 * 4;
        lds[b0] = v.x; lds[b0 + 1] = v.y; lds[b0 + 2] = v.z; lds[b0 + 3] = v.w;
      }
    }
    __syncthreads();

#pragma unroll
    for (int r = 0; r < 3; ++r) {
#pragma unroll
      for (int kx = 0; kx < 3; ++kx) {
        const float* wp = wTe + ((long)((r * 3 + kx) * CIN + ch * 8)) * COUT + ocb;
        const int lb = ((wv + r) * 66 + x + kx) * 9;
#pragma unroll 2
        for (int cin = 0; cin < 8; ++cin) {
          float xv = lds[lb + cin];
          const float* wpc = wp + cin * COUT;
#pragma unroll
          for (int j = 0; j < NOCG; ++j)
            acc[j] = fmaf(xv, wpc[j], acc[j]);
        }
      }
    }
  }

  const int yo = y0 + wv;
#pragma unroll
  for (int j = 0; j < NOCG; ++j) {
    if (ACT == ACT_LRELU) acc[j] = acc[j] >= 0.f ? acc[j] : 0.1f * acc[j];
  }
  if constexpr (OMODE == OUT_FLAT) {
    float* orow = out + ((long)iz * PIXN + yo * 64 + x) * COUT + ocb;
#pragma unroll
    for (int j4 = 0; j4 < NOCG / 4; ++j4) {
      float4 v = make_float4(acc[j4 * 4], acc[j4 * 4 + 1], acc[j4 * 4 + 2], acc[j4 * 4 + 3]);
      *reinterpret_cast<float4*>(orow + j4 * 4) = v;
    }
  } else {
#pragma unroll
    for (int j = 0; j < NOCG; ++j) {
      int oc = ocb + j;
      long oo = (long)iz * (COUT * PIXN) + (long)oc * PIXN + yo * 64 + x;
      out[oo] = acc[j] + resid[oo];
    }
  }
}

// ---------------- bf16x3-split MFMA 3x3 conv ----------------
// Block: 512 thr = 8 waves; tile = 128 px (2 rows) x COUTP.
// Wave (wm 0..3, wn 0..1): 2 m-tiles of 16 px, NTW n-tiles of 16 co.
// A (input, hi+lo bf16) staged ONCE: [ci8(12)][4 rows][66 px][8] with padded ci8 stride.
// B (weights) double-buffered per K-step (tap,kc): straight copy of prepped layout
// [kch][co][8].  D += Ah*Bh + Al*Bh + Ah*Bl  (Al*Bl ~2^-18, dropped).
template <int CIN, int COUT, int COUTP, int IMODE, int ACT>
__global__ __launch_bounds__(512, 2) void conv3x3m(
    const float* __restrict__ in, const float* __restrict__ in2,
    const float* __restrict__ bias_in,
    const unsigned short* __restrict__ WB,
    const float* __restrict__ bias,
    float* __restrict__ out) {
  constexpr int NCI8 = CIN / 8;            // 12
  constexpr int KC = CIN / 32;             // 3
  constexpr int NT = COUTP / 16;           // 6 or 14
  constexpr int NTW = NT / 2;
  constexpr int KSTEPS = 9 * KC;           // 27
  constexpr int AST = 4 * 66 * 8 + 8;      // padded ci8 stride (elems)
  constexpr int APL = NCI8 * AST;          // per-plane A elems
  constexpr int BSTEP = COUTP * 32;        // per-plane B elems per K-step
  constexpr int TOTB = 9 * KC * BSTEP;     // per-plane B elems total
  constexpr int N4 = BSTEP / 8;            // float4 per plane per step
  constexpr int NBPT = (N4 + 511) / 512;   // per-thread copy count

  __shared__ __align__(16) unsigned short Abuf[2 * APL];
  __shared__ __align__(16) unsigned short Bbuf[2][2 * BSTEP];

  const int tid = threadIdx.x;
  const int lane = tid & 63;
  const int wid = tid >> 6;
  const int wm = wid & 3;
  const int wn = wid >> 2;
  const int iz = blockIdx.y;
  const int y0 = blockIdx.x * 2;

  const float* baseA;
  const float* baseB2 = nullptr;
  const unsigned short* wbe = WB;
  int LDV;
  if constexpr (IMODE == IN_UVPAIR) {
    int pair = iz >> 2, b = iz & 3;
    int jj = pair >> 1, rr2 = pair & 1;
    int ii = (rr2 == 0) ? (jj == 0 ? 1 : 0) : (jj == 2 ? 1 : 2);
    baseA = in + (long)(b * 3 + jj) * (PIXN * 96);
    baseB2 = in2 + (long)(b * 3 + ii) * (PIXN * 96);
    LDV = 96;
  } else if constexpr (IMODE == IN_QKV) {
    int sel = iz / 12, img = iz % 12;
    baseA = in + (long)img * (PIXN * 288) + sel * 96;
    wbe = WB + (long)sel * (2 * TOTB);
    LDV = 288;
  } else {
    baseA = in + (long)iz * ((long)PIXN * CIN);
    LDV = CIN;
  }

  // ---- stage A once (fp32 -> bf16 hi/lo) ----
  constexpr int NSTG = 4 * 66 * (CIN / 4);
  for (int i = tid; i < NSTG; i += 512) {
    int ci4 = i % (CIN / 4);
    int t = i / (CIN / 4);
    int xp = t % 66, rr = t / 66;
    int y = y0 + rr - 1, x = xp - 1;
    float4 v = make_float4(0.f, 0.f, 0.f, 0.f);
    if ((unsigned)y < 64u && (unsigned)x < 64u) {
      long off = (long)(y * 64 + x) * LDV + ci4 * 4;
      if constexpr (IMODE == IN_UVPAIR) {
        float4 u = *reinterpret_cast<const float4*>(baseA + off);
        float4 w2 = *reinterpret_cast<const float4*>(baseB2 + off);
        float4 bi = *reinterpret_cast<const float4*>(bias_in + ci4 * 4);
        v.x = u.x + w2.x + bi.x; v.x = v.x >= 0.f ? v.x : 0.1f * v.x;
        v.y = u.y + w2.y + bi.y; v.y = v.y >= 0.f ? v.y : 0.1f * v.y;
        v.z = u.z + w2.z + bi.z; v.z = v.z >= 0.f ? v.z : 0.1f * v.z;
        v.w = u.w + w2.w + bi.w; v.w = v.w >= 0.f ? v.w : 0.1f * v.w;
      } else {
        v = *reinterpret_cast<const float4*>(baseA + off);
      }
    }
    unsigned short h0 = f2bf(v.x), h1 = f2bf(v.y), h2 = f2bf(v.z), h3 = f2bf(v.w);
    u16x4 hv = {h0, h1, h2, h3};
    u16x4 lv = {f2bf(v.x - bf2f(h0)), f2bf(v.y - bf2f(h1)),
                f2bf(v.z - bf2f(h2)), f2bf(v.w - bf2f(h3))};
    int base = (ci4 >> 1) * AST + (rr * 66 + xp) * 8 + (ci4 & 1) * 4;
    *reinterpret_cast<u16x4*>(&Abuf[base]) = hv;
    *reinterpret_cast<u16x4*>(&Abuf[APL + base]) = lv;
  }

  // ---- init acc ----
  f32x4 acc[2][NTW];
#pragma unroll
  for (int nt2 = 0; nt2 < NTW; ++nt2) {
    int co = (wn * NTW + nt2) * 16 + (lane & 15);
    float b0 = 0.f;
    if (bias != nullptr && co < COUT) b0 = bias[co];
#pragma unroll
    for (int mt2 = 0; mt2 < 2; ++mt2) {
      acc[mt2][nt2][0] = b0; acc[mt2][nt2][1] = b0;
      acc[mt2][nt2][2] = b0; acc[mt2][nt2][3] = b0;
    }
  }

  // ---- prologue: stage B step 0 ----
  {
    const float4* srcH = reinterpret_cast<const float4*>(wbe);
    const float4* srcL = reinterpret_cast<const float4*>(wbe + (long)TOTB);
    float4* dH = reinterpret_cast<float4*>(&Bbuf[0][0]);
    float4* dL = reinterpret_cast<float4*>(&Bbuf[0][BSTEP]);
#pragma unroll
    for (int j = 0; j < NBPT; ++j) {
      int idx = tid + j * 512;
      if (idx < N4) { dH[idx] = srcH[idx]; dL[idx] = srcL[idx]; }
    }
  }
  __syncthreads();

  float4 rbh[NBPT], rbl[NBPT];
#pragma unroll 1
  for (int s = 0; s < KSTEPS; ++s) {
    const int cur = s & 1;
    // issue next-step B loads early (latency hides under MFMA cluster)
    if (s + 1 < KSTEPS) {
      const float4* srcH = reinterpret_cast<const float4*>(wbe + (long)(s + 1) * BSTEP);
      const float4* srcL = reinterpret_cast<const float4*>(wbe + (long)TOTB + (long)(s + 1) * BSTEP);
#pragma unroll
      for (int j = 0; j < NBPT; ++j) {
        int idx = tid + j * 512;
        if (idx < N4) { rbh[j] = srcH[idx]; rbl[j] = srcL[idx]; }
      }
    }

    const int tap = s / KC, kc = s % KC;
    const int dy = tap / 3, dx = tap % 3;

    // A fragments (shared across all n-tiles)
    s16x8 ah[2], al[2];
    {
      int ci8 = kc * 4 + (lane >> 4);
      int m = lane & 15;
#pragma unroll
      for (int mt2 = 0; mt2 < 2; ++mt2) {
        int px = (wm * 2 + mt2) * 16 + m;
        int r = px >> 6, x = px & 63;
        int aoff = ci8 * AST + ((r + dy) * 66 + (x + dx)) * 8;
        ah[mt2] = *reinterpret_cast<const s16x8*>(&Abuf[aoff]);
        al[mt2] = *reinterpret_cast<const s16x8*>(&Abuf[APL + aoff]);
      }
    }

#pragma unroll
    for (int nt2 = 0; nt2 < NTW; ++nt2) {
      int boff = ((lane >> 4) * COUTP + (wn * NTW + nt2) * 16 + (lane & 15)) * 8;
      s16x8 bh = *reinterpret_cast<const s16x8*>(&Bbuf[cur][boff]);
      s16x8 bl = *reinterpret_cast<const s16x8*>(&Bbuf[cur][BSTEP + boff]);
#pragma unroll
      for (int mt2 = 0; mt2 < 2; ++mt2) {
        acc[mt2][nt2] = __builtin_amdgcn_mfma_f32_16x16x32_bf16(ah[mt2], bh, acc[mt2][nt2], 0, 0, 0);
        acc[mt2][nt2] = __builtin_amdgcn_mfma_f32_16x16x32_bf16(al[mt2], bh, acc[mt2][nt2], 0, 0, 0);
        acc[mt2][nt2] = __builtin_amdgcn_mfma_f32_16x16x32_bf16(ah[mt2], bl, acc[mt2][nt2], 0, 0, 0);
      }
    }

    // write next-step B into the other buffer (vmcnt wait lands after MFMAs)
    if (s + 1 < KSTEPS) {
      float4* dH = reinterpret_cast<float4*>(&Bbuf[cur ^ 1][0]);
      float4* dL = reinterpret_cast<float4*>(&Bbuf[cur ^ 1][BSTEP]);
#pragma unroll
      for (int j = 0; j < NBPT; ++j) {
        int idx = tid + j * 512;
        if (idx < N4) { dH[idx] = rbh[j]; dL[idx] = rbl[j]; }
      }
    }
    __syncthreads();
  }

  // ---- epilogue ----
  const long obase = (long)iz * PIXN + blockIdx.x * 128;
#pragma unroll
  for (int mt2 = 0; mt2 < 2; ++mt2) {
#pragma unroll
    for (int nt2 = 0; nt2 < NTW; ++nt2) {
      int co = (wn * NTW + nt2) * 16 + (lane & 15);
      if (COUTP > COUT && co >= COUT) continue;
#pragma unroll
      for (int r = 0; r < 4; ++r) {
        int px = (wm * 2 + mt2) * 16 + (lane >> 4) * 4 + r;
        float v = acc[mt2][nt2][r];
        if constexpr (ACT == ACT_LRELU) v = v >= 0.f ? v : 0.1f * v;
        if constexpr (ACT == ACT_SIG144) {
          if (co >= 144) v = 1.f / (1.f + expf(-v));
        }
        out[(obase + px) * COUT + co] = v;
      }
    }
  }
}

// ---------------- 1x1 qkv projection, GEMV-style ----------------
__global__ __launch_bounds__(256) void gemm1x1v2(const float* __restrict__ in,
                                                 const float* __restrict__ wT,
                                                 const float* __restrict__ bias,
                                                 float* __restrict__ out) {
  const int pcb = blockIdx.x;
  const int img = blockIdx.y;
  const int cg = blockIdx.z;
  const int tid = threadIdx.x;
  __shared__ float lds[256 * 33];
  float acc[96];
#pragma unroll
  for (int j = 0; j < 96; ++j) acc[j] = bias[cg * 96 + j];
  const float* ibase = in + ((long)img * PIXN + pcb * 256) * 96;
#pragma unroll 1
  for (int cc = 0; cc < 96; cc += 32) {
    __syncthreads();
    for (int i = tid; i < 2048; i += 256) {
      int px = i >> 3, c4 = i & 7;
      float4 v = *reinterpret_cast<const float4*>(ibase + (long)px * 96 + cc + c4 * 4);
      int b0 = px * 33 + c4 * 4;
      lds[b0] = v.x; lds[b0 + 1] = v.y; lds[b0 + 2] = v.z; lds[b0 + 3] = v.w;
    }
    __syncthreads();
#pragma unroll 2
    for (int c = 0; c < 32; ++c) {
      float xv = lds[tid * 33 + c];
      const float* wp = wT + (long)(cc + c) * 288 + cg * 96;
#pragma unroll
      for (int j = 0; j < 96; ++j) acc[j] = fmaf(xv, wp[j], acc[j]);
    }
  }
  float* orow = out + ((long)img * PIXN + pcb * 256 + tid) * 288 + cg * 96;
#pragma unroll
  for (int j4 = 0; j4 < 24; ++j4) {
    float4 v = make_float4(acc[j4 * 4], acc[j4 * 4 + 1], acc[j4 * 4 + 2], acc[j4 * 4 + 3]);
    *reinterpret_cast<float4*>(orow + j4 * 4) = v;
  }
}

// ---------------- deformable sampling helpers (fp32; mask pre-sigmoided) ----------------
__device__ __forceinline__ float dsampK(const float* __restrict__ kimg,
                                        const float* __restrict__ s_om,
                                        int g, int n, int y, int x, int c) {
  float oy = s_om[g * 9 + n];
  float ox = s_om[72 + g * 9 + n];
  float m = s_om[144 + g * 9 + n];
  float py = oy + (float)(y + n / 3 - 1);
  float px = ox + (float)(x + n % 3 - 1);
  float y0 = floorf(py), x0 = floorf(px);
  float wy = py - y0, wx = px - x0;
  float acc = 0.f;
#pragma unroll
  for (int dy = 0; dy < 2; ++dy) {
#pragma unroll
    for (int dx = 0; dx < 2; ++dx) {
      float yc = y0 + dy, xc = x0 + dx;
      if (yc >= 0.f && yc < 64.f && xc >= 0.f && xc < 64.f) {
        float w = (dy ? wy : 1.f - wy) * (dx ? wx : 1.f - wx);
        acc = fmaf(w, kimg[(long)((int)yc * 64 + (int)xc) * 288 + 96 + c], acc);
      }
    }
  }
  return acc * m;
}

__device__ __forceinline__ float dsampV(const float* __restrict__ kimg,
                                        const float* __restrict__ s_om,
                                        int g, int n, int y, int x, int c) {
  float oy = s_om[g * 9 + n];
  float ox = s_om[72 + g * 9 + n];
  float m = s_om[144 + g * 9 + n];
  float py = oy + (float)(y + n / 3 - 1);
  float px = ox + (float)(x + n % 3 - 1);
  float y0 = floorf(py), x0 = floorf(px);
  float wy = py - y0, wx = px - x0;
  float acc = 0.f;
#pragma unroll
  for (int dy = 0; dy < 2; ++dy) {
#pragma unroll
    for (int dx = 0; dx < 2; ++dx) {
      float yc = y0 + dy, xc = x0 + dx;
      if (yc >= 0.f && yc < 64.f && xc >= 0.f && xc < 64.f) {
        float w = (dy ? wy : 1.f - wy) * (dx ? wx : 1.f - wx);
        acc = fmaf(w, kimg[(long)((int)yc * 64 + (int)xc) * 288 + 192 + c], acc);
      }
    }
  }
  return acc * m;
}

// ---------------- attn v2: 4 px/block, cached sampled-K, V-only select ----------------
__global__ __launch_bounds__(256) void attn2_k(const float* __restrict__ qkv,
                                               const float* __restrict__ om,
                                               float* __restrict__ w_buf,
                                               f16* __restrict__ vre) {
  const int pair = blockIdx.y;
  const int jj = pair >> 1, rr = pair & 1;
  const int ii = (rr == 0) ? (jj == 0 ? 1 : 0) : (jj == 2 ? 1 : 2);
  const int wv = threadIdx.x >> 6;
  const int lane = threadIdx.x & 63;
  const int bp = blockIdx.x * 4 + wv;
  const int b = bp >> 12;
  const int p = bp & 4095;
  const int y = p >> 6, x = p & 63;

  __shared__ float s_om_all[4 * 216];
  float* s_om = s_om_all + wv * 216;
  const float* omrow = om + ((long)pair * 4 * PIXN + bp) * 216;
  for (int i = lane; i < 216; i += 64) s_om[i] = omrow[i];
  __syncthreads();

  const float* qrow = qkv + ((long)(b * 3 + jj) * PIXN + p) * 288;
  const float* kimg = qkv + (long)(b * 3 + ii) * PIXN * 288;
  float q0 = qrow[lane];
  float q1 = 0.f;
  if (lane < 32) q1 = qrow[64 + lane];
  const int c0 = lane, g0 = lane / 12;
  const int c1 = 64 + lane, g1 = (64 + lane) / 12;

  float rel[9], ka0[9], ka1[9];
#pragma unroll
  for (int n = 0; n < 9; ++n) {
    ka0[n] = dsampK(kimg, s_om, g0, n, y, x, c0);
    float part = q0 * ka0[n];
    ka1[n] = 0.f;
    if (lane < 32) {
      ka1[n] = dsampK(kimg, s_om, g1, n, y, x, c1);
      part = fmaf(q1, ka1[n], part);
    }
#pragma unroll
    for (int off = 32; off > 0; off >>= 1) part += __shfl_xor(part, off, 64);
    rel[n] = part;
  }
  int i0 = 0; float v0 = rel[0]; float ks00 = ka0[0], ks10 = ka1[0];
#pragma unroll
  for (int n = 1; n < 9; ++n) {
    bool t = rel[n] > v0;
    v0 = t ? rel[n] : v0; i0 = t ? n : i0;
    ks00 = t ? ka0[n] : ks00; ks10 = t ? ka1[n] : ks10;
  }
  int i1 = 0; float v1 = -3.4e38f; float ks01 = 0.f, ks11 = 0.f;
#pragma unroll
  for (int n = 0; n < 9; ++n) {
    bool t = (n != i0) && rel[n] > v1;
    v1 = t ? rel[n] : v1; i1 = t ? n : i1;
    ks01 = t ? ka0[n] : ks01; ks11 = t ? ka1[n] : ks11;
  }
  float e = expf(v1 - v0);
  float cw0 = 1.f / (1.f + e);
  float cw1 = e * cw0;

  float wpart = q0 * (cw0 * ks00 + cw1 * ks01);
  float va = dsampV(kimg, s_om, g0, i0, y, x, c0);
  float vb = dsampV(kimg, s_om, g0, i1, y, x, c0);
  vre[((long)pair * 16384 + bp) * 96 + c0] = f2h(cw0 * va + cw1 * vb);
  if (lane < 32) {
    wpart = fmaf(q1, cw0 * ks10 + cw1 * ks11, wpart);
    float ua = dsampV(kimg, s_om, g1, i0, y, x, c1);
    float ub = dsampV(kimg, s_om, g1, i1, y, x, c1);
    vre[((long)pair * 16384 + bp) * 96 + c1] = f2h(cw0 * ua + cw1 * ub);
  }
#pragma unroll
  for (int off = 32; off > 0; off >>= 1) wpart += __shfl_xor(wpart, off, 64);
  if (lane == 0) w_buf[(long)pair * 16384 + bp] = wpart;
}

// ---------------- merge: softmax over the 2 source frames -> f_t fp32 flat ----------------
__global__ __launch_bounds__(256) void merge_k(const float* __restrict__ w_buf,
                                               const f16* __restrict__ vre,
                                               float* __restrict__ f_t) {
  long idx = (long)blockIdx.x * 256 + threadIdx.x;
  const long TOT = (long)4 * 3 * PIXN * 24;
  if (idx >= TOT) return;
  int c4 = idx % 24;
  long t = idx / 24;
  int p = t % PIXN;
  long t2 = t / PIXN;
  int jj = t2 % 3;
  int b = (int)(t2 / 3);
  long bpi = (long)b * PIXN + p;
  int pr0 = jj * 2, pr1 = jj * 2 + 1;
  float w0 = w_buf[(long)pr0 * 16384 + bpi];
  float w1 = w_buf[(long)pr1 * 16384 + bpi];
  float mx = fmaxf(w0, w1);
  float e0 = expf(w0 - mx), e1 = expf(w1 - mx);
  float inv = 1.f / (e0 + e1);
  float s0 = e0 * inv, s1 = e1 * inv;
  const f16* va = &vre[((long)pr0 * 16384 + bpi) * 96 + c4 * 4];
  const f16* vb = &vre[((long)pr1 * 16384 + bpi) * 96 + c4 * 4];
  float4 r;
  r.x = s0 * h2f(va[0]) + s1 * h2f(vb[0]);
  r.y = s0 * h2f(va[1]) + s1 * h2f(vb[1]);
  r.z = s0 * h2f(va[2]) + s1 * h2f(vb[2]);
  r.w = s0 * h2f(va[3]) + s1 * h2f(vb[3]);
  *reinterpret_cast<float4*>(f_t + ((long)(b * 3 + jj) * PIXN + p) * 96 + c4 * 4) = r;
}

// ---------------- host ----------------
extern "C" void kernel_launch(void* const* d_in, const int* in_sizes, int n_in,
                              void* d_out, int out_size, void* d_ws, size_t ws_size,
                              hipStream_t stream) {
  const float* fea = (const float*)d_in[0];
  const float* cf_w = (const float*)d_in[1];
  const float* cf_b = (const float*)d_in[2];
  const float* wq = (const float*)d_in[3];
  const float* bq = (const float*)d_in[4];
  const float* wk = (const float*)d_in[5];
  const float* bk = (const float*)d_in[6];
  const float* wv = (const float*)d_in[7];
  const float* bv = (const float*)d_in[8];
  const float* oc1_w = (const float*)d_in[9];
  const float* oc1_b = (const float*)d_in[10];
  const float* oc2_w = (const float*)d_in[11];
  const float* oc2_b = (const float*)d_in[12];
  const float* om_w = (const float*)d_in[13];
  const float* om_b = (const float*)d_in[14];
  const float* cl_w = (const float*)d_in[15];
  const float* cl_b = (const float*)d_in[16];

  char* base = (char*)d_ws;
  size_t o = 0;
  auto carve = [&](size_t bytes) { char* p = base + o; o += (bytes + 255) & ~255UL; return p; };

  float* T0 = (float*)carve(55296UL * 4);
  float* T4 = (float*)carve(55296UL * 4);
  unsigned short* WB1 = (unsigned short*)carve(2UL * 2 * 82944 * 2);   // [sel][hi|lo]
  unsigned short* WB2 = (unsigned short*)carve(2UL * 82944 * 2);
  unsigned short* WB3 = (unsigned short*)carve(2UL * 193536 * 2);
  float* WQKV = (float*)carve(27648UL * 4);
  float* BQKV = (float*)carve(288UL * 4);

  // Z: emb (4.7M floats) early; om (21.2M, stride 216) later (emb dead)
  float* Z = (float*)carve(21233664UL * 4);
  float* emb_t = Z;
  float* om_t = Z;
  float* qkv_t = (float*)carve(14155776UL * 4);
  float* U_t = (float*)carve(4718592UL * 4);
  float* V_t = (float*)carve(4718592UL * 4);   // must stay contiguous after U_t
  float* off2_t = (float*)carve(9437184UL * 4);
  float* w_buf = (float*)carve(98304UL * 4);
  float* f_t = U_t;
  f16* vre_b = (f16*)V_t;

  // --- all weight prep in one launch (7 jobs on grid.y) ---
  prep_all<<<dim3(756, 7), 256, 0, stream>>>(cf_w, oc1_w, oc2_w, om_w, cl_w,
                                             wq, wk, wv, bq, bk, bv,
                                             T0, T4, WB1, WB2, WB3, WQKV, BQKV);

  // --- emb conv (fp32): NCHW in -> NHWC flat; NOCG=48 ---
  conv3x3v4<64, 96, 2, ACT_NONE, IN_NCHW, OUT_FLAT, false><<<dim3(16, 12, 2), 256, 0, stream>>>(
      fea, nullptr, nullptr, T0, cf_b, emb_t, nullptr);
  // --- qkv 1x1 (fp32) ---
  gemm1x1v2<<<dim3(16, 12, 3), 256, 0, stream>>>(emb_t, WQKV, BQKV, qkv_t);

  // --- off1 split (MFMA bf16x3): U = convA(q_img), V = convB(k_img) ---
  conv3x3m<96, 96, 96, IN_QKV, ACT_NONE><<<dim3(32, 24), 512, 0, stream>>>(
      qkv_t, nullptr, nullptr, WB1, nullptr, U_t);

  // --- off2 (MFMA bf16x3) with fused off1 epilogue: stage lrelu(U+V+b1) ---
  conv3x3m<96, 96, 96, IN_UVPAIR, ACT_LRELU><<<dim3(32, 24), 512, 0, stream>>>(
      U_t, V_t, oc1_b, WB2, oc2_b, off2_t);

  // --- om conv (MFMA bf16x3, COUT 216 padded to 224) + fused sigmoid ---
  conv3x3m<96, 216, 224, IN_FLAT, ACT_SIG144><<<dim3(32, 24), 512, 0, stream>>>(
      off2_t, nullptr, nullptr, WB3, om_b, om_t);

  // --- fused deformable attention (fp32 selection path; om stride 216) ---
  attn2_k<<<dim3(4096, 6), 256, 0, stream>>>(qkv_t, om_t, w_buf, vre_b);
  merge_k<<<4608, 256, 0, stream>>>(w_buf, vre_b, f_t);

  // --- final conv + residual -> NCHW fp32; NOCG=32 ---
  conv3x3v4<96, 64, 2, ACT_NONE, IN_FLAT, OUT_NCHWRES, false><<<dim3(16, 12, 2), 256, 0, stream>>>(
      f_t, nullptr, nullptr, T4, cl_b, (float*)d_out, fea);
}

// Round 2
// 929.409 us; speedup vs baseline: 1.8476x; 1.2809x over previous
//
#include <hip/hip_runtime.h>
#include <math.h>

#define PIXN 4096

typedef _Float16 f16;
typedef short s16x8 __attribute__((ext_vector_type(8)));
typedef unsigned short u16x4 __attribute__((ext_vector_type(4)));
typedef float f32x4 __attribute__((ext_vector_type(4)));

__device__ __forceinline__ f16 f2h(float f) { return (f16)f; }
__device__ __forceinline__ float h2f(f16 h) { return (float)h; }

// bf16 round-to-nearest-even via bit trick; residual f - bf2f(f2bf(f)) is exact in fp32.
__device__ __forceinline__ unsigned short f2bf(float f) {
  unsigned u = __float_as_uint(f);
  u += 0x7fffu + ((u >> 16) & 1u);
  return (unsigned short)(u >> 16);
}
__device__ __forceinline__ float bf2f(unsigned short h) {
  return __uint_as_float(((unsigned)h) << 16);
}

enum { ACT_NONE = 0, ACT_LRELU = 1, ACT_SIG144 = 2 };
enum { IN_NCHW = 0, IN_FLAT = 1, IN_UVPAIR = 2, IN_QKV = 3 };
enum { OUT_FLAT = 0, OUT_NCHWRES = 1 };

// ---------------- fused weight prep ----------------
__device__ __forceinline__ void wtrans_dev(const float* __restrict__ w, float* __restrict__ wT,
                                           int srcCIN, int cinOff, int dstCIN, int COUTv,
                                           int total, int idx) {
  if (idx >= total) return;
  int co = idx % COUTv;
  int t = idx / COUTv;
  int ci = t % dstCIN;
  int tap = t / dstCIN;
  wT[idx] = w[((long)co * srcCIN + cinOff + ci) * 9 + tap];
}

// MFMA weight prep: layout [tap][kc][kch][co][8e], hi plane then lo plane (each `total` elems).
__device__ __forceinline__ void wprep_mfma(const float* __restrict__ w, unsigned short* __restrict__ dst,
                                           int srcCIN, int cinOff, int COUTv, int COUTP,
                                           int total, int idx) {
  if (idx >= total) return;
  int e = idx & 7;
  int t = idx >> 3;
  int co = t % COUTP; t /= COUTP;
  int kch = t & 3; t >>= 2;
  int kc = t % 3;
  int tap = t / 3;
  int ci = kc * 32 + kch * 8 + e;
  float v = 0.f;
  if (co < COUTv) v = w[((long)co * srcCIN + cinOff + ci) * 9 + tap];
  unsigned short h = f2bf(v);
  dst[idx] = h;
  dst[total + idx] = f2bf(v - bf2f(h));
}

__global__ __launch_bounds__(256) void prep_all(
    const float* __restrict__ cf_w, const float* __restrict__ oc1_w,
    const float* __restrict__ oc2_w, const float* __restrict__ om_w,
    const float* __restrict__ cl_w,
    const float* __restrict__ wq, const float* __restrict__ wk, const float* __restrict__ wv,
    const float* __restrict__ bq, const float* __restrict__ bk, const float* __restrict__ bv,
    float* __restrict__ T0, float* __restrict__ T4,
    unsigned short* __restrict__ WB1, unsigned short* __restrict__ WB2,
    unsigned short* __restrict__ WB3,
    float* __restrict__ WQKV, float* __restrict__ BQKV) {
  int idx = blockIdx.x * 256 + threadIdx.x;
  switch (blockIdx.y) {
    case 0: wtrans_dev(cf_w, T0, 64, 0, 64, 96, 55296, idx); break;
    case 1: wtrans_dev(cl_w, T4, 96, 0, 96, 64, 55296, idx); break;
    case 2: {
      if (idx < 96 * 288) {
        int e288 = idx % 288;
        int c = idx / 288;
        int m = e288 / 96, e = e288 % 96;
        const float* wm = (m == 0) ? wq : (m == 1) ? wk : wv;
        WQKV[idx] = wm[e * 96 + c];
      }
      if (idx < 288) {
        int m = idx / 96, e = idx % 96;
        const float* bm = (m == 0) ? bq : (m == 1) ? bk : bv;
        BQKV[idx] = bm[e];
      }
      break;
    }
    case 3: wprep_mfma(oc1_w, WB1, 192, 0, 96, 96, 82944, idx); break;
    case 4: wprep_mfma(oc1_w, WB1 + 2 * 82944, 192, 96, 96, 96, 82944, idx); break;
    case 5: wprep_mfma(oc2_w, WB2, 96, 0, 96, 96, 82944, idx); break;
    default: wprep_mfma(om_w, WB3, 96, 0, 216, 224, 193536, idx); break;
  }
}

// ---------------- fp32 3x3 conv, GEMV-style (kept for emb + final) ----------------
template <int CIN, int COUT, int CG, int ACT, int IMODE, int OMODE, bool QKVIN>
__global__ __launch_bounds__(256) void conv3x3v4(
    const float* __restrict__ in, const float* __restrict__ in2,
    const float* __restrict__ bias_in,
    const float* __restrict__ wT,
    const float* __restrict__ bias,
    float* __restrict__ out,
    const float* __restrict__ resid) {
  constexpr int NOCG = COUT / CG;
  constexpr int NCH = CIN / 8;
  const int y0 = blockIdx.x * 4;
  const int iz = blockIdx.y;
  const int cg = blockIdx.z;
  const int tid = threadIdx.x;
  const int x = tid & 63;
  const int wv = tid >> 6;
  const int ocb = cg * NOCG;

  __shared__ float lds[6 * 66 * 9];

  const float* baseA;
  const float* wTe = wT;
  if constexpr (IMODE == IN_NCHW) {
    baseA = in + (long)iz * (CIN * PIXN);
  } else {
    baseA = in + (long)iz * (PIXN * CIN);
  }

  float acc[NOCG];
#pragma unroll
  for (int j = 0; j < NOCG; ++j) acc[j] = bias ? bias[ocb + j] : 0.f;

#pragma unroll 1
  for (int ch = 0; ch < NCH; ++ch) {
    __syncthreads();
    if constexpr (IMODE == IN_NCHW) {
      for (int i = tid; i < 8 * 396; i += 256) {
        int cin = i / 396;
        int t = i - cin * 396;
        int r = t / 66, px = t - r * 66;
        int yy = y0 - 1 + r, xx = px - 1;
        float v = 0.f;
        if ((unsigned)yy < 64u && (unsigned)xx < 64u)
          v = baseA[(long)(ch * 8 + cin) * PIXN + yy * 64 + xx];
        lds[t * 9 + cin] = v;
      }
    } else {
      for (int i = tid; i < 396 * 2; i += 256) {
        int c4 = i & 1, t = i >> 1;
        int r = t / 66, px = t - r * 66;
        int yy = y0 - 1 + r, xx = px - 1;
        float4 v = make_float4(0.f, 0.f, 0.f, 0.f);
        if ((unsigned)yy < 64u && (unsigned)xx < 64u)
          v = *reinterpret_cast<const float4*>(
              baseA + (long)(yy * 64 + xx) * CIN + ch * 8 + c4 * 4);
        int b0 = t * 9 + c4 * 4;
        lds[b0] = v.x; lds[b0 + 1] = v.y; lds[b0 + 2] = v.z; lds[b0 + 3] = v.w;
      }
    }
    __syncthreads();

#pragma unroll
    for (int r = 0; r < 3; ++r) {
#pragma unroll
      for (int kx = 0; kx < 3; ++kx) {
        const float* wp = wTe + ((long)((r * 3 + kx) * CIN + ch * 8)) * COUT + ocb;
        const int lb = ((wv + r) * 66 + x + kx) * 9;
#pragma unroll 2
        for (int cin = 0; cin < 8; ++cin) {
          float xv = lds[lb + cin];
          const float* wpc = wp + cin * COUT;
#pragma unroll
          for (int j = 0; j < NOCG; ++j)
            acc[j] = fmaf(xv, wpc[j], acc[j]);
        }
      }
    }
  }

  const int yo = y0 + wv;
#pragma unroll
  for (int j = 0; j < NOCG; ++j) {
    if (ACT == ACT_LRELU) acc[j] = acc[j] >= 0.f ? acc[j] : 0.1f * acc[j];
  }
  if constexpr (OMODE == OUT_FLAT) {
    float* orow = out + ((long)iz * PIXN + yo * 64 + x) * COUT + ocb;
#pragma unroll
    for (int j4 = 0; j4 < NOCG / 4; ++j4) {
      float4 v = make_float4(acc[j4 * 4], acc[j4 * 4 + 1], acc[j4 * 4 + 2], acc[j4 * 4 + 3]);
      *reinterpret_cast<float4*>(orow + j4 * 4) = v;
    }
  } else {
#pragma unroll
    for (int j = 0; j < NOCG; ++j) {
      int oc = ocb + j;
      long oo = (long)iz * (COUT * PIXN) + (long)oc * PIXN + yo * 64 + x;
      out[oo] = acc[j] + resid[oo];
    }
  }
}

// ---------------- bf16x3-split MFMA 3x3 conv ----------------
template <int CIN, int COUT, int COUTP, int IMODE, int ACT>
__global__ __launch_bounds__(512, 2) void conv3x3m(
    const float* __restrict__ in, const float* __restrict__ in2,
    const float* __restrict__ bias_in,
    const unsigned short* __restrict__ WB,
    const float* __restrict__ bias,
    float* __restrict__ out) {
  constexpr int NCI8 = CIN / 8;            // 12
  constexpr int KC = CIN / 32;             // 3
  constexpr int NT = COUTP / 16;           // 6 or 14
  constexpr int NTW = NT / 2;
  constexpr int KSTEPS = 9 * KC;           // 27
  constexpr int AST = 4 * 66 * 8 + 8;      // padded ci8 stride (elems)
  constexpr int APL = NCI8 * AST;          // per-plane A elems
  constexpr int BSTEP = COUTP * 32;        // per-plane B elems per K-step
  constexpr int TOTB = 9 * KC * BSTEP;     // per-plane B elems total
  constexpr int N4 = BSTEP / 8;            // float4 per plane per step
  constexpr int NBPT = (N4 + 511) / 512;   // per-thread copy count

  __shared__ __align__(16) unsigned short Abuf[2 * APL];
  __shared__ __align__(16) unsigned short Bbuf[2][2 * BSTEP];

  const int tid = threadIdx.x;
  const int lane = tid & 63;
  const int wid = tid >> 6;
  const int wm = wid & 3;
  const int wn = wid >> 2;
  const int iz = blockIdx.y;
  const int y0 = blockIdx.x * 2;

  const float* baseA;
  const float* baseB2 = nullptr;
  const unsigned short* wbe = WB;
  int LDV;
  if constexpr (IMODE == IN_UVPAIR) {
    int pair = iz >> 2, b = iz & 3;
    int jj = pair >> 1, rr2 = pair & 1;
    int ii = (rr2 == 0) ? (jj == 0 ? 1 : 0) : (jj == 2 ? 1 : 2);
    baseA = in + (long)(b * 3 + jj) * (PIXN * 96);
    baseB2 = in2 + (long)(b * 3 + ii) * (PIXN * 96);
    LDV = 96;
  } else if constexpr (IMODE == IN_QKV) {
    int sel = iz / 12, img = iz % 12;
    baseA = in + (long)img * (PIXN * 288) + sel * 96;
    wbe = WB + (long)sel * (2 * TOTB);
    LDV = 288;
  } else {
    baseA = in + (long)iz * ((long)PIXN * CIN);
    LDV = CIN;
  }

  // ---- stage A once (fp32 -> bf16 hi/lo) ----
  constexpr int NSTG = 4 * 66 * (CIN / 4);
  for (int i = tid; i < NSTG; i += 512) {
    int ci4 = i % (CIN / 4);
    int t = i / (CIN / 4);
    int xp = t % 66, rr = t / 66;
    int y = y0 + rr - 1, x = xp - 1;
    float4 v = make_float4(0.f, 0.f, 0.f, 0.f);
    if ((unsigned)y < 64u && (unsigned)x < 64u) {
      long off = (long)(y * 64 + x) * LDV + ci4 * 4;
      if constexpr (IMODE == IN_UVPAIR) {
        float4 u = *reinterpret_cast<const float4*>(baseA + off);
        float4 w2 = *reinterpret_cast<const float4*>(baseB2 + off);
        float4 bi = *reinterpret_cast<const float4*>(bias_in + ci4 * 4);
        v.x = u.x + w2.x + bi.x; v.x = v.x >= 0.f ? v.x : 0.1f * v.x;
        v.y = u.y + w2.y + bi.y; v.y = v.y >= 0.f ? v.y : 0.1f * v.y;
        v.z = u.z + w2.z + bi.z; v.z = v.z >= 0.f ? v.z : 0.1f * v.z;
        v.w = u.w + w2.w + bi.w; v.w = v.w >= 0.f ? v.w : 0.1f * v.w;
      } else {
        v = *reinterpret_cast<const float4*>(baseA + off);
      }
    }
    unsigned short h0 = f2bf(v.x), h1 = f2bf(v.y), h2 = f2bf(v.z), h3 = f2bf(v.w);
    u16x4 hv = {h0, h1, h2, h3};
    u16x4 lv = {f2bf(v.x - bf2f(h0)), f2bf(v.y - bf2f(h1)),
                f2bf(v.z - bf2f(h2)), f2bf(v.w - bf2f(h3))};
    int base = (ci4 >> 1) * AST + (rr * 66 + xp) * 8 + (ci4 & 1) * 4;
    *reinterpret_cast<u16x4*>(&Abuf[base]) = hv;
    *reinterpret_cast<u16x4*>(&Abuf[APL + base]) = lv;
  }

  // ---- init acc ----
  f32x4 acc[2][NTW];
#pragma unroll
  for (int nt2 = 0; nt2 < NTW; ++nt2) {
    int co = (wn * NTW + nt2) * 16 + (lane & 15);
    float b0 = 0.f;
    if (bias != nullptr && co < COUT) b0 = bias[co];
#pragma unroll
    for (int mt2 = 0; mt2 < 2; ++mt2) {
      acc[mt2][nt2][0] = b0; acc[mt2][nt2][1] = b0;
      acc[mt2][nt2][2] = b0; acc[mt2][nt2][3] = b0;
    }
  }

  // ---- prologue: stage B step 0 ----
  {
    const float4* srcH = reinterpret_cast<const float4*>(wbe);
    const float4* srcL = reinterpret_cast<const float4*>(wbe + (long)TOTB);
    float4* dH = reinterpret_cast<float4*>(&Bbuf[0][0]);
    float4* dL = reinterpret_cast<float4*>(&Bbuf[0][BSTEP]);
#pragma unroll
    for (int j = 0; j < NBPT; ++j) {
      int idx = tid + j * 512;
      if (idx < N4) { dH[idx] = srcH[idx]; dL[idx] = srcL[idx]; }
    }
  }
  __syncthreads();

  float4 rbh[NBPT], rbl[NBPT];
#pragma unroll 1
  for (int s = 0; s < KSTEPS; ++s) {
    const int cur = s & 1;
    if (s + 1 < KSTEPS) {
      const float4* srcH = reinterpret_cast<const float4*>(wbe + (long)(s + 1) * BSTEP);
      const float4* srcL = reinterpret_cast<const float4*>(wbe + (long)TOTB + (long)(s + 1) * BSTEP);
#pragma unroll
      for (int j = 0; j < NBPT; ++j) {
        int idx = tid + j * 512;
        if (idx < N4) { rbh[j] = srcH[idx]; rbl[j] = srcL[idx]; }
      }
    }

    const int tap = s / KC, kc = s % KC;
    const int dy = tap / 3, dx = tap % 3;

    s16x8 ah[2], al[2];
    {
      int ci8 = kc * 4 + (lane >> 4);
      int m = lane & 15;
#pragma unroll
      for (int mt2 = 0; mt2 < 2; ++mt2) {
        int px = (wm * 2 + mt2) * 16 + m;
        int r = px >> 6, x = px & 63;
        int aoff = ci8 * AST + ((r + dy) * 66 + (x + dx)) * 8;
        ah[mt2] = *reinterpret_cast<const s16x8*>(&Abuf[aoff]);
        al[mt2] = *reinterpret_cast<const s16x8*>(&Abuf[APL + aoff]);
      }
    }

#pragma unroll
    for (int nt2 = 0; nt2 < NTW; ++nt2) {
      int boff = ((lane >> 4) * COUTP + (wn * NTW + nt2) * 16 + (lane & 15)) * 8;
      s16x8 bh = *reinterpret_cast<const s16x8*>(&Bbuf[cur][boff]);
      s16x8 bl = *reinterpret_cast<const s16x8*>(&Bbuf[cur][BSTEP + boff]);
#pragma unroll
      for (int mt2 = 0; mt2 < 2; ++mt2) {
        acc[mt2][nt2] = __builtin_amdgcn_mfma_f32_16x16x32_bf16(ah[mt2], bh, acc[mt2][nt2], 0, 0, 0);
        acc[mt2][nt2] = __builtin_amdgcn_mfma_f32_16x16x32_bf16(al[mt2], bh, acc[mt2][nt2], 0, 0, 0);
        acc[mt2][nt2] = __builtin_amdgcn_mfma_f32_16x16x32_bf16(ah[mt2], bl, acc[mt2][nt2], 0, 0, 0);
      }
    }

    if (s + 1 < KSTEPS) {
      float4* dH = reinterpret_cast<float4*>(&Bbuf[cur ^ 1][0]);
      float4* dL = reinterpret_cast<float4*>(&Bbuf[cur ^ 1][BSTEP]);
#pragma unroll
      for (int j = 0; j < NBPT; ++j) {
        int idx = tid + j * 512;
        if (idx < N4) { dH[idx] = rbh[j]; dL[idx] = rbl[j]; }
      }
    }
    __syncthreads();
  }

  // ---- epilogue ----
  const long obase = (long)iz * PIXN + blockIdx.x * 128;
#pragma unroll
  for (int mt2 = 0; mt2 < 2; ++mt2) {
#pragma unroll
    for (int nt2 = 0; nt2 < NTW; ++nt2) {
      int co = (wn * NTW + nt2) * 16 + (lane & 15);
      if (COUTP > COUT && co >= COUT) continue;
#pragma unroll
      for (int r = 0; r < 4; ++r) {
        int px = (wm * 2 + mt2) * 16 + (lane >> 4) * 4 + r;
        float v = acc[mt2][nt2][r];
        if constexpr (ACT == ACT_LRELU) v = v >= 0.f ? v : 0.1f * v;
        if constexpr (ACT == ACT_SIG144) {
          if (co >= 144) v = 1.f / (1.f + expf(-v));
        }
        out[(obase + px) * COUT + co] = v;
      }
    }
  }
}

// ---------------- 1x1 qkv projection, GEMV-style ----------------
__global__ __launch_bounds__(256) void gemm1x1v2(const float* __restrict__ in,
                                                 const float* __restrict__ wT,
                                                 const float* __restrict__ bias,
                                                 float* __restrict__ out) {
  const int pcb = blockIdx.x;
  const int img = blockIdx.y;
  const int cg = blockIdx.z;
  const int tid = threadIdx.x;
  __shared__ float lds[256 * 33];
  float acc[96];
#pragma unroll
  for (int j = 0; j < 96; ++j) acc[j] = bias[cg * 96 + j];
  const float* ibase = in + ((long)img * PIXN + pcb * 256) * 96;
#pragma unroll 1
  for (int cc = 0; cc < 96; cc += 32) {
    __syncthreads();
    for (int i = tid; i < 2048; i += 256) {
      int px = i >> 3, c4 = i & 7;
      float4 v = *reinterpret_cast<const float4*>(ibase + (long)px * 96 + cc + c4 * 4);
      int b0 = px * 33 + c4 * 4;
      lds[b0] = v.x; lds[b0 + 1] = v.y; lds[b0 + 2] = v.z; lds[b0 + 3] = v.w;
    }
    __syncthreads();
#pragma unroll 2
    for (int c = 0; c < 32; ++c) {
      float xv = lds[tid * 33 + c];
      const float* wp = wT + (long)(cc + c) * 288 + cg * 96;
#pragma unroll
      for (int j = 0; j < 96; ++j) acc[j] = fmaf(xv, wp[j], acc[j]);
    }
  }
  float* orow = out + ((long)img * PIXN + pcb * 256 + tid) * 288 + cg * 96;
#pragma unroll
  for (int j4 = 0; j4 < 24; ++j4) {
    float4 v = make_float4(acc[j4 * 4], acc[j4 * 4 + 1], acc[j4 * 4 + 2], acc[j4 * 4 + 3]);
    *reinterpret_cast<float4*>(orow + j4 * 4) = v;
  }
}

// ---------------- attn v3: 2 px/wave, 3 ch/lane, LDS-precomputed bilinear setup ----------------
// Setup per (pixel, g, n): 4 corner weights (mask+bounds folded) + 4 base indices
// (pos*288+96, K base; V adds +96).  K loop: broadcast LDS read + 12 gathers + fmafs.
#define CWSLOT 580  // 72*8 + 4 pad (breaks ph bank collision; residual 2-way is free)
__global__ __launch_bounds__(256) void attn3_k(const float* __restrict__ qkv,
                                               const float* __restrict__ om,
                                               float* __restrict__ w_buf,
                                               f16* __restrict__ vre) {
  const int pair = blockIdx.y;
  const int jj = pair >> 1, rr = pair & 1;
  const int ii = (rr == 0) ? (jj == 0 ? 1 : 0) : (jj == 2 ? 1 : 2);
  const int wv = threadIdx.x >> 6;
  const int lane = threadIdx.x & 63;
  const int bp0 = blockIdx.x * 8 + wv * 2;  // even; both px same b

  __shared__ float s_om[8 * 216];
  __shared__ float s_cw[8 * CWSLOT];

  // om rows for 2 consecutive pixels are contiguous: 432 floats
  {
    const float* omrow = om + ((long)pair * 16384 + bp0) * 216;
    float* dst = s_om + wv * 432;
    for (int i = lane; i < 432; i += 64) dst[i] = omrow[i];
  }
  __syncthreads();

  // setup: 144 combos per wave (2 px x 8 g x 9 n)
  for (int t = lane; t < 144; t += 64) {
    int ph = t / 72, cmb = t - ph * 72;
    int g = cmb / 9, n = cmb - g * 9;
    int p = (bp0 + ph) & 4095;
    int y = p >> 6, x = p & 63;
    const float* so = s_om + (wv * 2 + ph) * 216;
    float oy = so[g * 9 + n], ox = so[72 + g * 9 + n], m = so[144 + g * 9 + n];
    float py = oy + (float)(y + n / 3 - 1);
    float px = ox + (float)(x + n % 3 - 1);
    float y0f = floorf(py), x0f = floorf(px);
    float wy = py - y0f, wx = px - x0f;
    float* dst = s_cw + (wv * 2 + ph) * CWSLOT + cmb * 8;
#pragma unroll
    for (int dy = 0; dy < 2; ++dy) {
#pragma unroll
      for (int dx = 0; dx < 2; ++dx) {
        float yc = y0f + dy, xc = x0f + dx;
        bool valid = (yc >= 0.f) & (yc < 64.f) & (xc >= 0.f) & (xc < 64.f);
        float w = (dy ? wy : 1.f - wy) * (dx ? wx : 1.f - wx) * m;
        w = valid ? w : 0.f;
        int yi = (int)fminf(fmaxf(yc, 0.f), 63.f);
        int xi = (int)fminf(fmaxf(xc, 0.f), 63.f);
        int idx = (yi * 64 + xi) * 288 + 96;  // K base; V adds +96
        dst[dy * 2 + dx] = w;
        dst[4 + dy * 2 + dx] = __int_as_float(idx);
      }
    }
  }
  __syncthreads();

  const int ph = lane >> 5;
  const int li = lane & 31;
  const int bp = bp0 + ph;
  const int b = bp >> 12;
  const int cb = li * 3;       // channel base 0..93
  const int g = li >> 2;       // == (3*li)/12
  const float* kimg = qkv + (long)(b * 3 + ii) * (PIXN * 288);
  const float* qrow = qkv + ((long)(b * 3 + jj) * PIXN + (bp & 4095)) * 288 + cb;
  const float q0 = qrow[0], q1 = qrow[1], q2 = qrow[2];
  const float* cw = s_cw + (wv * 2 + ph) * CWSLOT + g * 9 * 8;

  float ka[9][3];
  float rel[9];
#pragma unroll
  for (int n = 0; n < 9; ++n) {
    float4 w4 = *reinterpret_cast<const float4*>(cw + n * 8);
    float4 i4 = *reinterpret_cast<const float4*>(cw + n * 8 + 4);
    int ia = __float_as_int(i4.x) + cb, ib = __float_as_int(i4.y) + cb;
    int ic = __float_as_int(i4.z) + cb, id = __float_as_int(i4.w) + cb;
#pragma unroll
    for (int j = 0; j < 3; ++j) {
      float a = w4.x * kimg[ia + j];
      a = fmaf(w4.y, kimg[ib + j], a);
      a = fmaf(w4.z, kimg[ic + j], a);
      a = fmaf(w4.w, kimg[id + j], a);
      ka[n][j] = a;
    }
    float part = q0 * ka[n][0];
    part = fmaf(q1, ka[n][1], part);
    part = fmaf(q2, ka[n][2], part);
#pragma unroll
    for (int off = 16; off > 0; off >>= 1) part += __shfl_xor(part, off, 64);
    rel[n] = part;
  }

  // top-2 selection (rel uniform within each half-wave; first-index wins ties)
  int i0 = 0; float v0 = rel[0];
  float ks0a = ka[0][0], ks0b = ka[0][1], ks0c = ka[0][2];
#pragma unroll
  for (int n = 1; n < 9; ++n) {
    bool t = rel[n] > v0;
    v0 = t ? rel[n] : v0; i0 = t ? n : i0;
    ks0a = t ? ka[n][0] : ks0a; ks0b = t ? ka[n][1] : ks0b; ks0c = t ? ka[n][2] : ks0c;
  }
  int i1 = 0; float v1 = -3.4e38f;
  float ks1a = 0.f, ks1b = 0.f, ks1c = 0.f;
#pragma unroll
  for (int n = 0; n < 9; ++n) {
    bool t = (n != i0) && rel[n] > v1;
    v1 = t ? rel[n] : v1; i1 = t ? n : i1;
    ks1a = t ? ka[n][0] : ks1a; ks1b = t ? ka[n][1] : ks1b; ks1c = t ? ka[n][2] : ks1c;
  }
  float e = expf(v1 - v0);
  float cw0 = 1.f / (1.f + e), cw1 = e * cw0;

  float wpart = q0 * (cw0 * ks0a + cw1 * ks1a);
  wpart = fmaf(q1, cw0 * ks0b + cw1 * ks1b, wpart);
  wpart = fmaf(q2, cw0 * ks0c + cw1 * ks1c, wpart);
#pragma unroll
  for (int off = 16; off > 0; off >>= 1) wpart += __shfl_xor(wpart, off, 64);
  if (li == 0) w_buf[(long)pair * 16384 + bp] = wpart;

  // V phase: reuse setup for the two selected taps
  float4 wA = *reinterpret_cast<const float4*>(cw + i0 * 8);
  float4 iA = *reinterpret_cast<const float4*>(cw + i0 * 8 + 4);
  float4 wB = *reinterpret_cast<const float4*>(cw + i1 * 8);
  float4 iB = *reinterpret_cast<const float4*>(cw + i1 * 8 + 4);
  int a0 = __float_as_int(iA.x) + 96 + cb, a1 = __float_as_int(iA.y) + 96 + cb;
  int a2 = __float_as_int(iA.z) + 96 + cb, a3 = __float_as_int(iA.w) + 96 + cb;
  int b0 = __float_as_int(iB.x) + 96 + cb, b1 = __float_as_int(iB.y) + 96 + cb;
  int b2 = __float_as_int(iB.z) + 96 + cb, b3 = __float_as_int(iB.w) + 96 + cb;
  f16* vrow = vre + ((long)pair * 16384 + bp) * 96 + cb;
#pragma unroll
  for (int j = 0; j < 3; ++j) {
    float va = wA.x * kimg[a0 + j];
    va = fmaf(wA.y, kimg[a1 + j], va);
    va = fmaf(wA.z, kimg[a2 + j], va);
    va = fmaf(wA.w, kimg[a3 + j], va);
    float vb = wB.x * kimg[b0 + j];
    vb = fmaf(wB.y, kimg[b1 + j], vb);
    vb = fmaf(wB.z, kimg[b2 + j], vb);
    vb = fmaf(wB.w, kimg[b3 + j], vb);
    vrow[j] = f2h(cw0 * va + cw1 * vb);
  }
}

// ---------------- merge: softmax over the 2 source frames -> f_t fp32 flat ----------------
__global__ __launch_bounds__(256) void merge_k(const float* __restrict__ w_buf,
                                               const f16* __restrict__ vre,
                                               float* __restrict__ f_t) {
  long idx = (long)blockIdx.x * 256 + threadIdx.x;
  const long TOT = (long)4 * 3 * PIXN * 24;
  if (idx >= TOT) return;
  int c4 = idx % 24;
  long t = idx / 24;
  int p = t % PIXN;
  long t2 = t / PIXN;
  int jj = t2 % 3;
  int b = (int)(t2 / 3);
  long bpi = (long)b * PIXN + p;
  int pr0 = jj * 2, pr1 = jj * 2 + 1;
  float w0 = w_buf[(long)pr0 * 16384 + bpi];
  float w1 = w_buf[(long)pr1 * 16384 + bpi];
  float mx = fmaxf(w0, w1);
  float e0 = expf(w0 - mx), e1 = expf(w1 - mx);
  float inv = 1.f / (e0 + e1);
  float s0 = e0 * inv, s1 = e1 * inv;
  const f16* va = &vre[((long)pr0 * 16384 + bpi) * 96 + c4 * 4];
  const f16* vb = &vre[((long)pr1 * 16384 + bpi) * 96 + c4 * 4];
  float4 r;
  r.x = s0 * h2f(va[0]) + s1 * h2f(vb[0]);
  r.y = s0 * h2f(va[1]) + s1 * h2f(vb[1]);
  r.z = s0 * h2f(va[2]) + s1 * h2f(vb[2]);
  r.w = s0 * h2f(va[3]) + s1 * h2f(vb[3]);
  *reinterpret_cast<float4*>(f_t + ((long)(b * 3 + jj) * PIXN + p) * 96 + c4 * 4) = r;
}

// ---------------- host ----------------
extern "C" void kernel_launch(void* const* d_in, const int* in_sizes, int n_in,
                              void* d_out, int out_size, void* d_ws, size_t ws_size,
                              hipStream_t stream) {
  const float* fea = (const float*)d_in[0];
  const float* cf_w = (const float*)d_in[1];
  const float* cf_b = (const float*)d_in[2];
  const float* wq = (const float*)d_in[3];
  const float* bq = (const float*)d_in[4];
  const float* wk = (const float*)d_in[5];
  const float* bk = (const float*)d_in[6];
  const float* wv = (const float*)d_in[7];
  const float* bv = (const float*)d_in[8];
  const float* oc1_w = (const float*)d_in[9];
  const float* oc1_b = (const float*)d_in[10];
  const float* oc2_w = (const float*)d_in[11];
  const float* oc2_b = (const float*)d_in[12];
  const float* om_w = (const float*)d_in[13];
  const float* om_b = (const float*)d_in[14];
  const float* cl_w = (const float*)d_in[15];
  const float* cl_b = (const float*)d_in[16];

  char* base = (char*)d_ws;
  size_t o = 0;
  auto carve = [&](size_t bytes) { char* p = base + o; o += (bytes + 255) & ~255UL; return p; };

  float* T0 = (float*)carve(55296UL * 4);
  float* T4 = (float*)carve(55296UL * 4);
  unsigned short* WB1 = (unsigned short*)carve(2UL * 2 * 82944 * 2);   // [sel][hi|lo]
  unsigned short* WB2 = (unsigned short*)carve(2UL * 82944 * 2);
  unsigned short* WB3 = (unsigned short*)carve(2UL * 193536 * 2);
  float* WQKV = (float*)carve(27648UL * 4);
  float* BQKV = (float*)carve(288UL * 4);

  // Z: emb (4.7M floats) early; om (21.2M, stride 216) later (emb dead)
  float* Z = (float*)carve(21233664UL * 4);
  float* emb_t = Z;
  float* om_t = Z;
  float* qkv_t = (float*)carve(14155776UL * 4);
  float* U_t = (float*)carve(4718592UL * 4);
  float* V_t = (float*)carve(4718592UL * 4);   // must stay contiguous after U_t
  float* off2_t = (float*)carve(9437184UL * 4);
  float* w_buf = (float*)carve(98304UL * 4);
  float* f_t = U_t;
  f16* vre_b = (f16*)V_t;

  // --- all weight prep in one launch (7 jobs on grid.y) ---
  prep_all<<<dim3(756, 7), 256, 0, stream>>>(cf_w, oc1_w, oc2_w, om_w, cl_w,
                                             wq, wk, wv, bq, bk, bv,
                                             T0, T4, WB1, WB2, WB3, WQKV, BQKV);

  // --- emb conv (fp32): NCHW in -> NHWC flat; NOCG=48 ---
  conv3x3v4<64, 96, 2, ACT_NONE, IN_NCHW, OUT_FLAT, false><<<dim3(16, 12, 2), 256, 0, stream>>>(
      fea, nullptr, nullptr, T0, cf_b, emb_t, nullptr);
  // --- qkv 1x1 (fp32) ---
  gemm1x1v2<<<dim3(16, 12, 3), 256, 0, stream>>>(emb_t, WQKV, BQKV, qkv_t);

  // --- off1 split (MFMA bf16x3): U = convA(q_img), V = convB(k_img) ---
  conv3x3m<96, 96, 96, IN_QKV, ACT_NONE><<<dim3(32, 24), 512, 0, stream>>>(
      qkv_t, nullptr, nullptr, WB1, nullptr, U_t);

  // --- off2 (MFMA bf16x3) with fused off1 epilogue: stage lrelu(U+V+b1) ---
  conv3x3m<96, 96, 96, IN_UVPAIR, ACT_LRELU><<<dim3(32, 24), 512, 0, stream>>>(
      U_t, V_t, oc1_b, WB2, oc2_b, off2_t);

  // --- om conv (MFMA bf16x3, COUT 216 padded to 224) + fused sigmoid ---
  conv3x3m<96, 216, 224, IN_FLAT, ACT_SIG144><<<dim3(32, 24), 512, 0, stream>>>(
      off2_t, nullptr, nullptr, WB3, om_b, om_t);

  // --- fused deformable attention (fp32; 2 px/wave, 3 ch/lane, LDS setup) ---
  attn3_k<<<dim3(2048, 6), 256, 0, stream>>>(qkv_t, om_t, w_buf, vre_b);
  merge_k<<<4608, 256, 0, stream>>>(w_buf, vre_b, f_t);

  // --- final conv + residual -> NCHW fp32; NOCG=32 ---
  conv3x3v4<96, 64, 2, ACT_NONE, IN_FLAT, OUT_NCHWRES, false><<<dim3(16, 12, 2), 256, 0, stream>>>(
      f_t, nullptr, nullptr, T4, cl_b, (float*)d_out, fea);
}

// Round 3
// 872.022 us; speedup vs baseline: 1.9692x; 1.0658x over previous
//
#include <hip/hip_runtime.h>
#include <math.h>

#define PIXN 4096

typedef _Float16 f16;
typedef short s16x8 __attribute__((ext_vector_type(8)));
typedef unsigned short u16x4 __attribute__((ext_vector_type(4)));
typedef float f32x4 __attribute__((ext_vector_type(4)));

__device__ __forceinline__ f16 f2h(float f) { return (f16)f; }
__device__ __forceinline__ float h2f(f16 h) { return (float)h; }

// bf16 round-to-nearest-even via bit trick; residual f - bf2f(f2bf(f)) is exact in fp32.
__device__ __forceinline__ unsigned short f2bf(float f) {
  unsigned u = __float_as_uint(f);
  u += 0x7fffu + ((u >> 16) & 1u);
  return (unsigned short)(u >> 16);
}
__device__ __forceinline__ float bf2f(unsigned short h) {
  return __uint_as_float(((unsigned)h) << 16);
}

enum { ACT_NONE = 0, ACT_LRELU = 1, ACT_SIG144 = 2 };
enum { IN_NCHW = 0, IN_FLAT = 1, IN_UVPAIR = 2, IN_QKV = 3 };
enum { OUT_FLAT = 0, OUT_NCHWRES = 1 };

// ---------------- fused weight prep ----------------
__device__ __forceinline__ void wtrans_dev(const float* __restrict__ w, float* __restrict__ wT,
                                           int srcCIN, int cinOff, int dstCIN, int COUTv,
                                           int total, int idx) {
  if (idx >= total) return;
  int co = idx % COUTv;
  int t = idx / COUTv;
  int ci = t % dstCIN;
  int tap = t / dstCIN;
  wT[idx] = w[((long)co * srcCIN + cinOff + ci) * 9 + tap];
}

// MFMA weight prep: layout [tap][kc][kch][co][8e], hi plane then lo plane (each `total` elems).
__device__ __forceinline__ void wprep_mfma(const float* __restrict__ w, unsigned short* __restrict__ dst,
                                           int srcCIN, int cinOff, int COUTv, int COUTP,
                                           int total, int idx) {
  if (idx >= total) return;
  int e = idx & 7;
  int t = idx >> 3;
  int co = t % COUTP; t /= COUTP;
  int kch = t & 3; t >>= 2;
  int kc = t % 3;
  int tap = t / 3;
  int ci = kc * 32 + kch * 8 + e;
  float v = 0.f;
  if (co < COUTv) v = w[((long)co * srcCIN + cinOff + ci) * 9 + tap];
  unsigned short h = f2bf(v);
  dst[idx] = h;
  dst[total + idx] = f2bf(v - bf2f(h));
}

__global__ __launch_bounds__(256) void prep_all(
    const float* __restrict__ cf_w, const float* __restrict__ oc1_w,
    const float* __restrict__ oc2_w, const float* __restrict__ om_w,
    const float* __restrict__ cl_w,
    const float* __restrict__ wq, const float* __restrict__ wk, const float* __restrict__ wv,
    const float* __restrict__ bq, const float* __restrict__ bk, const float* __restrict__ bv,
    float* __restrict__ T0, float* __restrict__ T4,
    unsigned short* __restrict__ WB1, unsigned short* __restrict__ WB2,
    unsigned short* __restrict__ WB3,
    float* __restrict__ WQKV, float* __restrict__ BQKV) {
  int idx = blockIdx.x * 256 + threadIdx.x;
  switch (blockIdx.y) {
    case 0: wtrans_dev(cf_w, T0, 64, 0, 64, 96, 55296, idx); break;
    case 1: wtrans_dev(cl_w, T4, 96, 0, 96, 64, 55296, idx); break;
    case 2: {
      if (idx < 96 * 288) {
        int e288 = idx % 288;
        int c = idx / 288;
        int m = e288 / 96, e = e288 % 96;
        const float* wm = (m == 0) ? wq : (m == 1) ? wk : wv;
        WQKV[idx] = wm[e * 96 + c];
      }
      if (idx < 288) {
        int m = idx / 96, e = idx % 96;
        const float* bm = (m == 0) ? bq : (m == 1) ? bk : bv;
        BQKV[idx] = bm[e];
      }
      break;
    }
    case 3: wprep_mfma(oc1_w, WB1, 192, 0, 96, 96, 82944, idx); break;
    case 4: wprep_mfma(oc1_w, WB1 + 2 * 82944, 192, 96, 96, 96, 82944, idx); break;
    case 5: wprep_mfma(oc2_w, WB2, 96, 0, 96, 96, 82944, idx); break;
    default: wprep_mfma(om_w, WB3, 96, 0, 216, 224, 193536, idx); break;
  }
}

// ---------------- fp32 3x3 conv, GEMV-style (kept for emb + final) ----------------
template <int CIN, int COUT, int CG, int ACT, int IMODE, int OMODE, bool QKVIN>
__global__ __launch_bounds__(256) void conv3x3v4(
    const float* __restrict__ in, const float* __restrict__ in2,
    const float* __restrict__ bias_in,
    const float* __restrict__ wT,
    const float* __restrict__ bias,
    float* __restrict__ out,
    const float* __restrict__ resid) {
  constexpr int NOCG = COUT / CG;
  constexpr int NCH = CIN / 8;
  const int y0 = blockIdx.x * 4;
  const int iz = blockIdx.y;
  const int cg = blockIdx.z;
  const int tid = threadIdx.x;
  const int x = tid & 63;
  const int wv = tid >> 6;
  const int ocb = cg * NOCG;

  __shared__ float lds[6 * 66 * 9];

  const float* baseA;
  const float* wTe = wT;
  if constexpr (IMODE == IN_NCHW) {
    baseA = in + (long)iz * (CIN * PIXN);
  } else {
    baseA = in + (long)iz * (PIXN * CIN);
  }

  float acc[NOCG];
#pragma unroll
  for (int j = 0; j < NOCG; ++j) acc[j] = bias ? bias[ocb + j] : 0.f;

#pragma unroll 1
  for (int ch = 0; ch < NCH; ++ch) {
    __syncthreads();
    if constexpr (IMODE == IN_NCHW) {
      for (int i = tid; i < 8 * 396; i += 256) {
        int cin = i / 396;
        int t = i - cin * 396;
        int r = t / 66, px = t - r * 66;
        int yy = y0 - 1 + r, xx = px - 1;
        float v = 0.f;
        if ((unsigned)yy < 64u && (unsigned)xx < 64u)
          v = baseA[(long)(ch * 8 + cin) * PIXN + yy * 64 + xx];
        lds[t * 9 + cin] = v;
      }
    } else {
      for (int i = tid; i < 396 * 2; i += 256) {
        int c4 = i & 1, t = i >> 1;
        int r = t / 66, px = t - r * 66;
        int yy = y0 - 1 + r, xx = px - 1;
        float4 v = make_float4(0.f, 0.f, 0.f, 0.f);
        if ((unsigned)yy < 64u && (unsigned)xx < 64u)
          v = *reinterpret_cast<const float4*>(
              baseA + (long)(yy * 64 + xx) * CIN + ch * 8 + c4 * 4);
        int b0 = t * 9 + c4 * 4;
        lds[b0] = v.x; lds[b0 + 1] = v.y; lds[b0 + 2] = v.z; lds[b0 + 3] = v.w;
      }
    }
    __syncthreads();

#pragma unroll
    for (int r = 0; r < 3; ++r) {
#pragma unroll
      for (int kx = 0; kx < 3; ++kx) {
        const float* wp = wTe + ((long)((r * 3 + kx) * CIN + ch * 8)) * COUT + ocb;
        const int lb = ((wv + r) * 66 + x + kx) * 9;
#pragma unroll 2
        for (int cin = 0; cin < 8; ++cin) {
          float xv = lds[lb + cin];
          const float* wpc = wp + cin * COUT;
#pragma unroll
          for (int j = 0; j < NOCG; ++j)
            acc[j] = fmaf(xv, wpc[j], acc[j]);
        }
      }
    }
  }

  const int yo = y0 + wv;
#pragma unroll
  for (int j = 0; j < NOCG; ++j) {
    if (ACT == ACT_LRELU) acc[j] = acc[j] >= 0.f ? acc[j] : 0.1f * acc[j];
  }
  if constexpr (OMODE == OUT_FLAT) {
    float* orow = out + ((long)iz * PIXN + yo * 64 + x) * COUT + ocb;
#pragma unroll
    for (int j4 = 0; j4 < NOCG / 4; ++j4) {
      float4 v = make_float4(acc[j4 * 4], acc[j4 * 4 + 1], acc[j4 * 4 + 2], acc[j4 * 4 + 3]);
      *reinterpret_cast<float4*>(orow + j4 * 4) = v;
    }
  } else {
#pragma unroll
    for (int j = 0; j < NOCG; ++j) {
      int oc = ocb + j;
      long oo = (long)iz * (COUT * PIXN) + (long)oc * PIXN + yo * 64 + x;
      out[oo] = acc[j] + resid[oo];
    }
  }
}

// ---------------- bf16x3-split MFMA 3x3 conv, per-kc A staging ----------------
// Block: 512 thr = 8 waves; tile = 128 px (2 rows) x COUTP.
// A staged ONE kc-group (32 ci) at a time -> Abuf 34 KB; off convs keep B dbuf
// (58.5 KB total), om uses single-B + reg prefetch (62.6 KB) -> 2 blocks/CU.
template <int CIN, int COUT, int COUTP, int IMODE, int ACT, bool BDB>
__global__ __launch_bounds__(512, 4) void conv3x3m(
    const float* __restrict__ in, const float* __restrict__ in2,
    const float* __restrict__ bias_in,
    const unsigned short* __restrict__ WB,
    const float* __restrict__ bias,
    float* __restrict__ out) {
  constexpr int KC = CIN / 32;             // 3
  constexpr int NT = COUTP / 16;           // 6 or 14
  constexpr int NTW = NT / 2;
  constexpr int AST = 4 * 66 * 8 + 8;      // padded ci8 stride (elems)
  constexpr int APL = 4 * AST;             // per-plane A elems (one kc = 4 ci8)
  constexpr int BSTEP = COUTP * 32;        // per-plane B elems per K-step
  constexpr int TOTB = 9 * KC * BSTEP;     // per-plane B elems total
  constexpr int N4 = BSTEP / 8;            // float4 per plane per step
  constexpr int NBPT = (N4 + 511) / 512;   // per-thread copy count
  constexpr int NBUF = BDB ? 2 : 1;

  __shared__ __align__(16) unsigned short Abuf[2 * APL];
  __shared__ __align__(16) unsigned short Bbuf[NBUF][2 * BSTEP];

  const int tid = threadIdx.x;
  const int lane = tid & 63;
  const int wid = tid >> 6;
  const int wm = wid & 3;
  const int wn = wid >> 2;
  const int iz = blockIdx.y;
  const int y0 = blockIdx.x * 2;

  const float* baseA;
  const float* baseB2 = nullptr;
  const unsigned short* wbe = WB;
  int LDV;
  if constexpr (IMODE == IN_UVPAIR) {
    int pair = iz >> 2, b = iz & 3;
    int jj = pair >> 1, rr2 = pair & 1;
    int ii = (rr2 == 0) ? (jj == 0 ? 1 : 0) : (jj == 2 ? 1 : 2);
    baseA = in + (long)(b * 3 + jj) * (PIXN * 96);
    baseB2 = in2 + (long)(b * 3 + ii) * (PIXN * 96);
    LDV = 96;
  } else if constexpr (IMODE == IN_QKV) {
    int sel = iz / 12, img = iz % 12;
    baseA = in + (long)img * (PIXN * 288) + sel * 96;
    wbe = WB + (long)sel * (2 * TOTB);
    LDV = 288;
  } else {
    baseA = in + (long)iz * ((long)PIXN * CIN);
    LDV = CIN;
  }

  // ---- stage A for one kc group (32 ci): fp32 -> bf16 hi/lo ----
  auto stageA = [&](int kc) {
    for (int i = tid; i < 4 * 66 * 8; i += 512) {
      int ci4 = i & 7;             // 0..7 within this kc
      int t = i >> 3;
      int xp = t % 66, rr = t / 66;
      int y = y0 + rr - 1, x = xp - 1;
      float4 v = make_float4(0.f, 0.f, 0.f, 0.f);
      if ((unsigned)y < 64u && (unsigned)x < 64u) {
        long off = (long)(y * 64 + x) * LDV + kc * 32 + ci4 * 4;
        if constexpr (IMODE == IN_UVPAIR) {
          float4 u = *reinterpret_cast<const float4*>(baseA + off);
          float4 w2 = *reinterpret_cast<const float4*>(baseB2 + off);
          float4 bi = *reinterpret_cast<const float4*>(bias_in + kc * 32 + ci4 * 4);
          v.x = u.x + w2.x + bi.x; v.x = v.x >= 0.f ? v.x : 0.1f * v.x;
          v.y = u.y + w2.y + bi.y; v.y = v.y >= 0.f ? v.y : 0.1f * v.y;
          v.z = u.z + w2.z + bi.z; v.z = v.z >= 0.f ? v.z : 0.1f * v.z;
          v.w = u.w + w2.w + bi.w; v.w = v.w >= 0.f ? v.w : 0.1f * v.w;
        } else {
          v = *reinterpret_cast<const float4*>(baseA + off);
        }
      }
      unsigned short h0 = f2bf(v.x), h1 = f2bf(v.y), h2 = f2bf(v.z), h3 = f2bf(v.w);
      u16x4 hv = {h0, h1, h2, h3};
      u16x4 lv = {f2bf(v.x - bf2f(h0)), f2bf(v.y - bf2f(h1)),
                  f2bf(v.z - bf2f(h2)), f2bf(v.w - bf2f(h3))};
      int base = (ci4 >> 1) * AST + (rr * 66 + xp) * 8 + (ci4 & 1) * 4;
      *reinterpret_cast<u16x4*>(&Abuf[base]) = hv;
      *reinterpret_cast<u16x4*>(&Abuf[APL + base]) = lv;
    }
  };

  // ---- init acc ----
  f32x4 acc[2][NTW];
#pragma unroll
  for (int nt2 = 0; nt2 < NTW; ++nt2) {
    int co = (wn * NTW + nt2) * 16 + (lane & 15);
    float b0 = 0.f;
    if (bias != nullptr && co < COUT) b0 = bias[co];
#pragma unroll
    for (int mt2 = 0; mt2 < 2; ++mt2) {
      acc[mt2][nt2][0] = b0; acc[mt2][nt2][1] = b0;
      acc[mt2][nt2][2] = b0; acc[mt2][nt2][3] = b0;
    }
  }

  // ---- prologue: stage A(kc=0) + B step (tap0,kc0) ----
  stageA(0);
  {
    const float4* srcH = reinterpret_cast<const float4*>(wbe);
    const float4* srcL = reinterpret_cast<const float4*>(wbe + (long)TOTB);
    float4* dH = reinterpret_cast<float4*>(&Bbuf[0][0]);
    float4* dL = reinterpret_cast<float4*>(&Bbuf[0][BSTEP]);
#pragma unroll
    for (int j = 0; j < NBPT; ++j) {
      int idx = tid + j * 512;
      if (idx < N4) { dH[idx] = srcH[idx]; dL[idx] = srcL[idx]; }
    }
  }
  __syncthreads();

  float4 rbh[NBPT], rbl[NBPT];
  int sgl = 0;
#pragma unroll 1
  for (int kc = 0; kc < KC; ++kc) {
#pragma unroll 1
    for (int tap = 0; tap < 9; ++tap, ++sgl) {
      const int cur = BDB ? (sgl & 1) : 0;
      const bool last = (sgl == 9 * KC - 1);
      // issue next-step B loads early (latency hides under MFMA cluster)
      if (!last) {
        int ntap = tap + 1, nkc = kc;
        if (ntap == 9) { ntap = 0; nkc = kc + 1; }
        long bo = (long)(ntap * KC + nkc) * BSTEP;
        const float4* srcH = reinterpret_cast<const float4*>(wbe + bo);
        const float4* srcL = reinterpret_cast<const float4*>(wbe + (long)TOTB + bo);
#pragma unroll
        for (int j = 0; j < NBPT; ++j) {
          int idx = tid + j * 512;
          if (idx < N4) { rbh[j] = srcH[idx]; rbl[j] = srcL[idx]; }
        }
      }

      const int dy = tap / 3, dx = tap % 3;

      // A fragments (ci8 = lane>>4 within staged kc)
      s16x8 ah[2], al[2];
      {
        int ci8 = lane >> 4;
        int m = lane & 15;
#pragma unroll
        for (int mt2 = 0; mt2 < 2; ++mt2) {
          int px = (wm * 2 + mt2) * 16 + m;
          int r = px >> 6, x = px & 63;
          int aoff = ci8 * AST + ((r + dy) * 66 + (x + dx)) * 8;
          ah[mt2] = *reinterpret_cast<const s16x8*>(&Abuf[aoff]);
          al[mt2] = *reinterpret_cast<const s16x8*>(&Abuf[APL + aoff]);
        }
      }

#pragma unroll
      for (int nt2 = 0; nt2 < NTW; ++nt2) {
        int boff = ((lane >> 4) * COUTP + (wn * NTW + nt2) * 16 + (lane & 15)) * 8;
        s16x8 bh = *reinterpret_cast<const s16x8*>(&Bbuf[cur][boff]);
        s16x8 bl = *reinterpret_cast<const s16x8*>(&Bbuf[cur][BSTEP + boff]);
#pragma unroll
        for (int mt2 = 0; mt2 < 2; ++mt2) {
          acc[mt2][nt2] = __builtin_amdgcn_mfma_f32_16x16x32_bf16(ah[mt2], bh, acc[mt2][nt2], 0, 0, 0);
          acc[mt2][nt2] = __builtin_amdgcn_mfma_f32_16x16x32_bf16(al[mt2], bh, acc[mt2][nt2], 0, 0, 0);
          acc[mt2][nt2] = __builtin_amdgcn_mfma_f32_16x16x32_bf16(ah[mt2], bl, acc[mt2][nt2], 0, 0, 0);
        }
      }

      if constexpr (BDB) {
        // dbuf: write next-step B into the other buffer, barrier once per step
        if (!last) {
          float4* dH = reinterpret_cast<float4*>(&Bbuf[cur ^ 1][0]);
          float4* dL = reinterpret_cast<float4*>(&Bbuf[cur ^ 1][BSTEP]);
#pragma unroll
          for (int j = 0; j < NBPT; ++j) {
            int idx = tid + j * 512;
            if (idx < N4) { dH[idx] = rbh[j]; dL[idx] = rbl[j]; }
          }
        }
        if (tap == 8 && kc + 1 < KC) {
          __syncthreads();          // all A-reads of this kc done
          stageA(kc + 1);
        }
        __syncthreads();
      } else {
        // single-B: drain reads, then overwrite
        __syncthreads();
        if (!last) {
          float4* dH = reinterpret_cast<float4*>(&Bbuf[0][0]);
          float4* dL = reinterpret_cast<float4*>(&Bbuf[0][BSTEP]);
#pragma unroll
          for (int j = 0; j < NBPT; ++j) {
            int idx = tid + j * 512;
            if (idx < N4) { dH[idx] = rbh[j]; dL[idx] = rbl[j]; }
          }
        }
        if (tap == 8 && kc + 1 < KC) stageA(kc + 1);
        __syncthreads();
      }
    }
  }

  // ---- epilogue ----
  const long obase = (long)iz * PIXN + blockIdx.x * 128;
#pragma unroll
  for (int mt2 = 0; mt2 < 2; ++mt2) {
#pragma unroll
    for (int nt2 = 0; nt2 < NTW; ++nt2) {
      int co = (wn * NTW + nt2) * 16 + (lane & 15);
      if (COUTP > COUT && co >= COUT) continue;
#pragma unroll
      for (int r = 0; r < 4; ++r) {
        int px = (wm * 2 + mt2) * 16 + (lane >> 4) * 4 + r;
        float v = acc[mt2][nt2][r];
        if constexpr (ACT == ACT_LRELU) v = v >= 0.f ? v : 0.1f * v;
        if constexpr (ACT == ACT_SIG144) {
          if (co >= 144) v = 1.f / (1.f + expf(-v));
        }
        out[(obase + px) * COUT + co] = v;
      }
    }
  }
}

// ---------------- 1x1 qkv projection, GEMV-style ----------------
__global__ __launch_bounds__(256) void gemm1x1v2(const float* __restrict__ in,
                                                 const float* __restrict__ wT,
                                                 const float* __restrict__ bias,
                                                 float* __restrict__ out) {
  const int pcb = blockIdx.x;
  const int img = blockIdx.y;
  const int cg = blockIdx.z;
  const int tid = threadIdx.x;
  __shared__ float lds[256 * 33];
  float acc[96];
#pragma unroll
  for (int j = 0; j < 96; ++j) acc[j] = bias[cg * 96 + j];
  const float* ibase = in + ((long)img * PIXN + pcb * 256) * 96;
#pragma unroll 1
  for (int cc = 0; cc < 96; cc += 32) {
    __syncthreads();
    for (int i = tid; i < 2048; i += 256) {
      int px = i >> 3, c4 = i & 7;
      float4 v = *reinterpret_cast<const float4*>(ibase + (long)px * 96 + cc + c4 * 4);
      int b0 = px * 33 + c4 * 4;
      lds[b0] = v.x; lds[b0 + 1] = v.y; lds[b0 + 2] = v.z; lds[b0 + 3] = v.w;
    }
    __syncthreads();
#pragma unroll 2
    for (int c = 0; c < 32; ++c) {
      float xv = lds[tid * 33 + c];
      const float* wp = wT + (long)(cc + c) * 288 + cg * 96;
#pragma unroll
      for (int j = 0; j < 96; ++j) acc[j] = fmaf(xv, wp[j], acc[j]);
    }
  }
  float* orow = out + ((long)img * PIXN + pcb * 256 + tid) * 288 + cg * 96;
#pragma unroll
  for (int j4 = 0; j4 < 24; ++j4) {
    float4 v = make_float4(acc[j4 * 4], acc[j4 * 4 + 1], acc[j4 * 4 + 2], acc[j4 * 4 + 3]);
    *reinterpret_cast<float4*>(orow + j4 * 4) = v;
  }
}

// ---------------- attn v3: 2 px/wave, 3 ch/lane, LDS-precomputed bilinear setup ----------------
// Setup per (pixel, g, n): 4 corner weights (mask+bounds folded) + 4 base indices
// (pos*288+96, K base; V adds +96).  K loop: broadcast LDS read + 12 gathers + fmafs.
#define CWSLOT 580  // 72*8 + 4 pad (breaks ph bank collision; residual 2-way is free)
__global__ __launch_bounds__(256) void attn3_k(const float* __restrict__ qkv,
                                               const float* __restrict__ om,
                                               float* __restrict__ w_buf,
                                               f16* __restrict__ vre) {
  const int pair = blockIdx.y;
  const int jj = pair >> 1, rr = pair & 1;
  const int ii = (rr == 0) ? (jj == 0 ? 1 : 0) : (jj == 2 ? 1 : 2);
  const int wv = threadIdx.x >> 6;
  const int lane = threadIdx.x & 63;
  const int bp0 = blockIdx.x * 8 + wv * 2;  // even; both px same b

  __shared__ float s_om[8 * 216];
  __shared__ float s_cw[8 * CWSLOT];

  // om rows for 2 consecutive pixels are contiguous: 432 floats
  {
    const float* omrow = om + ((long)pair * 16384 + bp0) * 216;
    float* dst = s_om + wv * 432;
    for (int i = lane; i < 432; i += 64) dst[i] = omrow[i];
  }
  __syncthreads();

  // setup: 144 combos per wave (2 px x 8 g x 9 n)
  for (int t = lane; t < 144; t += 64) {
    int ph = t / 72, cmb = t - ph * 72;
    int g = cmb / 9, n = cmb - g * 9;
    int p = (bp0 + ph) & 4095;
    int y = p >> 6, x = p & 63;
    const float* so = s_om + (wv * 2 + ph) * 216;
    float oy = so[g * 9 + n], ox = so[72 + g * 9 + n], m = so[144 + g * 9 + n];
    float py = oy + (float)(y + n / 3 - 1);
    float px = ox + (float)(x + n % 3 - 1);
    float y0f = floorf(py), x0f = floorf(px);
    float wy = py - y0f, wx = px - x0f;
    float* dst = s_cw + (wv * 2 + ph) * CWSLOT + cmb * 8;
#pragma unroll
    for (int dy = 0; dy < 2; ++dy) {
#pragma unroll
      for (int dx = 0; dx < 2; ++dx) {
        float yc = y0f + dy, xc = x0f + dx;
        bool valid = (yc >= 0.f) & (yc < 64.f) & (xc >= 0.f) & (xc < 64.f);
        float w = (dy ? wy : 1.f - wy) * (dx ? wx : 1.f - wx) * m;
        w = valid ? w : 0.f;
        int yi = (int)fminf(fmaxf(yc, 0.f), 63.f);
        int xi = (int)fminf(fmaxf(xc, 0.f), 63.f);
        int idx = (yi * 64 + xi) * 288 + 96;  // K base; V adds +96
        dst[dy * 2 + dx] = w;
        dst[4 + dy * 2 + dx] = __int_as_float(idx);
      }
    }
  }
  __syncthreads();

  const int ph = lane >> 5;
  const int li = lane & 31;
  const int bp = bp0 + ph;
  const int b = bp >> 12;
  const int cb = li * 3;       // channel base 0..93
  const int g = li >> 2;       // == (3*li)/12
  const float* kimg = qkv + (long)(b * 3 + ii) * (PIXN * 288);
  const float* qrow = qkv + ((long)(b * 3 + jj) * PIXN + (bp & 4095)) * 288 + cb;
  const float q0 = qrow[0], q1 = qrow[1], q2 = qrow[2];
  const float* cw = s_cw + (wv * 2 + ph) * CWSLOT + g * 9 * 8;

  float ka[9][3];
  float rel[9];
#pragma unroll
  for (int n = 0; n < 9; ++n) {
    float4 w4 = *reinterpret_cast<const float4*>(cw + n * 8);
    float4 i4 = *reinterpret_cast<const float4*>(cw + n * 8 + 4);
    int ia = __float_as_int(i4.x) + cb, ib = __float_as_int(i4.y) + cb;
    int ic = __float_as_int(i4.z) + cb, id = __float_as_int(i4.w) + cb;
#pragma unroll
    for (int j = 0; j < 3; ++j) {
      float a = w4.x * kimg[ia + j];
      a = fmaf(w4.y, kimg[ib + j], a);
      a = fmaf(w4.z, kimg[ic + j], a);
      a = fmaf(w4.w, kimg[id + j], a);
      ka[n][j] = a;
    }
    float part = q0 * ka[n][0];
    part = fmaf(q1, ka[n][1], part);
    part = fmaf(q2, ka[n][2], part);
#pragma unroll
    for (int off = 16; off > 0; off >>= 1) part += __shfl_xor(part, off, 64);
    rel[n] = part;
  }

  // top-2 selection (rel uniform within each half-wave; first-index wins ties)
  int i0 = 0; float v0 = rel[0];
  float ks0a = ka[0][0], ks0b = ka[0][1], ks0c = ka[0][2];
#pragma unroll
  for (int n = 1; n < 9; ++n) {
    bool t = rel[n] > v0;
    v0 = t ? rel[n] : v0; i0 = t ? n : i0;
    ks0a = t ? ka[n][0] : ks0a; ks0b = t ? ka[n][1] : ks0b; ks0c = t ? ka[n][2] : ks0c;
  }
  int i1 = 0; float v1 = -3.4e38f;
  float ks1a = 0.f, ks1b = 0.f, ks1c = 0.f;
#pragma unroll
  for (int n = 0; n < 9; ++n) {
    bool t = (n != i0) && rel[n] > v1;
    v1 = t ? rel[n] : v1; i1 = t ? n : i1;
    ks1a = t ? ka[n][0] : ks1a; ks1b = t ? ka[n][1] : ks1b; ks1c = t ? ka[n][2] : ks1c;
  }
  float e = expf(v1 - v0);
  float cw0 = 1.f / (1.f + e), cw1 = e * cw0;

  float wpart = q0 * (cw0 * ks0a + cw1 * ks1a);
  wpart = fmaf(q1, cw0 * ks0b + cw1 * ks1b, wpart);
  wpart = fmaf(q2, cw0 * ks0c + cw1 * ks1c, wpart);
#pragma unroll
  for (int off = 16; off > 0; off >>= 1) wpart += __shfl_xor(wpart, off, 64);
  if (li == 0) w_buf[(long)pair * 16384 + bp] = wpart;

  // V phase: reuse setup for the two selected taps
  float4 wA = *reinterpret_cast<const float4*>(cw + i0 * 8);
  float4 iA = *reinterpret_cast<const float4*>(cw + i0 * 8 + 4);
  float4 wB = *reinterpret_cast<const float4*>(cw + i1 * 8);
  float4 iB = *reinterpret_cast<const float4*>(cw + i1 * 8 + 4);
  int a0 = __float_as_int(iA.x) + 96 + cb, a1 = __float_as_int(iA.y) + 96 + cb;
  int a2 = __float_as_int(iA.z) + 96 + cb, a3 = __float_as_int(iA.w) + 96 + cb;
  int b0 = __float_as_int(iB.x) + 96 + cb, b1 = __float_as_int(iB.y) + 96 + cb;
  int b2 = __float_as_int(iB.z) + 96 + cb, b3 = __float_as_int(iB.w) + 96 + cb;
  f16* vrow = vre + ((long)pair * 16384 + bp) * 96 + cb;
#pragma unroll
  for (int j = 0; j < 3; ++j) {
    float va = wA.x * kimg[a0 + j];
    va = fmaf(wA.y, kimg[a1 + j], va);
    va = fmaf(wA.z, kimg[a2 + j], va);
    va = fmaf(wA.w, kimg[a3 + j], va);
    float vb = wB.x * kimg[b0 + j];
    vb = fmaf(wB.y, kimg[b1 + j], vb);
    vb = fmaf(wB.z, kimg[b2 + j], vb);
    vb = fmaf(wB.w, kimg[b3 + j], vb);
    vrow[j] = f2h(cw0 * va + cw1 * vb);
  }
}

// ---------------- merge: softmax over the 2 source frames -> f_t fp32 flat ----------------
__global__ __launch_bounds__(256) void merge_k(const float* __restrict__ w_buf,
                                               const f16* __restrict__ vre,
                                               float* __restrict__ f_t) {
  long idx = (long)blockIdx.x * 256 + threadIdx.x;
  const long TOT = (long)4 * 3 * PIXN * 24;
  if (idx >= TOT) return;
  int c4 = idx % 24;
  long t = idx / 24;
  int p = t % PIXN;
  long t2 = t / PIXN;
  int jj = t2 % 3;
  int b = (int)(t2 / 3);
  long bpi = (long)b * PIXN + p;
  int pr0 = jj * 2, pr1 = jj * 2 + 1;
  float w0 = w_buf[(long)pr0 * 16384 + bpi];
  float w1 = w_buf[(long)pr1 * 16384 + bpi];
  float mx = fmaxf(w0, w1);
  float e0 = expf(w0 - mx), e1 = expf(w1 - mx);
  float inv = 1.f / (e0 + e1);
  float s0 = e0 * inv, s1 = e1 * inv;
  const f16* va = &vre[((long)pr0 * 16384 + bpi) * 96 + c4 * 4];
  const f16* vb = &vre[((long)pr1 * 16384 + bpi) * 96 + c4 * 4];
  float4 r;
  r.x = s0 * h2f(va[0]) + s1 * h2f(vb[0]);
  r.y = s0 * h2f(va[1]) + s1 * h2f(vb[1]);
  r.z = s0 * h2f(va[2]) + s1 * h2f(vb[2]);
  r.w = s0 * h2f(va[3]) + s1 * h2f(vb[3]);
  *reinterpret_cast<float4*>(f_t + ((long)(b * 3 + jj) * PIXN + p) * 96 + c4 * 4) = r;
}

// ---------------- host ----------------
extern "C" void kernel_launch(void* const* d_in, const int* in_sizes, int n_in,
                              void* d_out, int out_size, void* d_ws, size_t ws_size,
                              hipStream_t stream) {
  const float* fea = (const float*)d_in[0];
  const float* cf_w = (const float*)d_in[1];
  const float* cf_b = (const float*)d_in[2];
  const float* wq = (const float*)d_in[3];
  const float* bq = (const float*)d_in[4];
  const float* wk = (const float*)d_in[5];
  const float* bk = (const float*)d_in[6];
  const float* wv = (const float*)d_in[7];
  const float* bv = (const float*)d_in[8];
  const float* oc1_w = (const float*)d_in[9];
  const float* oc1_b = (const float*)d_in[10];
  const float* oc2_w = (const float*)d_in[11];
  const float* oc2_b = (const float*)d_in[12];
  const float* om_w = (const float*)d_in[13];
  const float* om_b = (const float*)d_in[14];
  const float* cl_w = (const float*)d_in[15];
  const float* cl_b = (const float*)d_in[16];

  char* base = (char*)d_ws;
  size_t o = 0;
  auto carve = [&](size_t bytes) { char* p = base + o; o += (bytes + 255) & ~255UL; return p; };

  float* T0 = (float*)carve(55296UL * 4);
  float* T4 = (float*)carve(55296UL * 4);
  unsigned short* WB1 = (unsigned short*)carve(2UL * 2 * 82944 * 2);   // [sel][hi|lo]
  unsigned short* WB2 = (unsigned short*)carve(2UL * 82944 * 2);
  unsigned short* WB3 = (unsigned short*)carve(2UL * 193536 * 2);
  float* WQKV = (float*)carve(27648UL * 4);
  float* BQKV = (float*)carve(288UL * 4);

  // Z: emb (4.7M floats) early; om (21.2M, stride 216) later (emb dead)
  float* Z = (float*)carve(21233664UL * 4);
  float* emb_t = Z;
  float* om_t = Z;
  float* qkv_t = (float*)carve(14155776UL * 4);
  float* U_t = (float*)carve(4718592UL * 4);
  float* V_t = (float*)carve(4718592UL * 4);   // must stay contiguous after U_t
  float* off2_t = (float*)carve(9437184UL * 4);
  float* w_buf = (float*)carve(98304UL * 4);
  float* f_t = U_t;
  f16* vre_b = (f16*)V_t;

  // --- all weight prep in one launch (7 jobs on grid.y) ---
  prep_all<<<dim3(756, 7), 256, 0, stream>>>(cf_w, oc1_w, oc2_w, om_w, cl_w,
                                             wq, wk, wv, bq, bk, bv,
                                             T0, T4, WB1, WB2, WB3, WQKV, BQKV);

  // --- emb conv (fp32): NCHW in -> NHWC flat; NOCG=48 ---
  conv3x3v4<64, 96, 2, ACT_NONE, IN_NCHW, OUT_FLAT, false><<<dim3(16, 12, 2), 256, 0, stream>>>(
      fea, nullptr, nullptr, T0, cf_b, emb_t, nullptr);
  // --- qkv 1x1 (fp32) ---
  gemm1x1v2<<<dim3(16, 12, 3), 256, 0, stream>>>(emb_t, WQKV, BQKV, qkv_t);

  // --- off1 split (MFMA bf16x3, B-dbuf): U = convA(q_img), V = convB(k_img) ---
  conv3x3m<96, 96, 96, IN_QKV, ACT_NONE, true><<<dim3(32, 24), 512, 0, stream>>>(
      qkv_t, nullptr, nullptr, WB1, nullptr, U_t);

  // --- off2 (MFMA bf16x3, B-dbuf) with fused off1 epilogue: stage lrelu(U+V+b1) ---
  conv3x3m<96, 96, 96, IN_UVPAIR, ACT_LRELU, true><<<dim3(32, 24), 512, 0, stream>>>(
      U_t, V_t, oc1_b, WB2, oc2_b, off2_t);

  // --- om conv (MFMA bf16x3, COUT 216 padded to 224, single-B) + fused sigmoid ---
  conv3x3m<96, 216, 224, IN_FLAT, ACT_SIG144, false><<<dim3(32, 24), 512, 0, stream>>>(
      off2_t, nullptr, nullptr, WB3, om_b, om_t);

  // --- fused deformable attention (fp32; 2 px/wave, 3 ch/lane, LDS setup) ---
  attn3_k<<<dim3(2048, 6), 256, 0, stream>>>(qkv_t, om_t, w_buf, vre_b);
  merge_k<<<4608, 256, 0, stream>>>(w_buf, vre_b, f_t);

  // --- final conv + residual -> NCHW fp32; NOCG=32 ---
  conv3x3v4<96, 64, 2, ACT_NONE, IN_FLAT, OUT_NCHWRES, false><<<dim3(16, 12, 2), 256, 0, stream>>>(
      f_t, nullptr, nullptr, T4, cl_b, (float*)d_out, fea);
}

// Round 4
// 791.527 us; speedup vs baseline: 2.1695x; 1.1017x over previous
//
#include <hip/hip_runtime.h>
#include <math.h>

#define PIXN 4096

typedef _Float16 f16;
typedef short s16x8 __attribute__((ext_vector_type(8)));
typedef unsigned short u16x4 __attribute__((ext_vector_type(4)));
typedef float f32x4 __attribute__((ext_vector_type(4)));

__device__ __forceinline__ f16 f2h(float f) { return (f16)f; }
__device__ __forceinline__ float h2f(f16 h) { return (float)h; }

// bf16 round-to-nearest-even via bit trick; residual f - bf2f(f2bf(f)) is exact in fp32.
__device__ __forceinline__ unsigned short f2bf(float f) {
  unsigned u = __float_as_uint(f);
  u += 0x7fffu + ((u >> 16) & 1u);
  return (unsigned short)(u >> 16);
}
__device__ __forceinline__ float bf2f(unsigned short h) {
  return __uint_as_float(((unsigned)h) << 16);
}

enum { ACT_NONE = 0, ACT_LRELU = 1, ACT_SIG144 = 2 };
enum { IN_NCHW = 0, IN_FLAT = 1, IN_UVPAIR = 2, IN_QKV = 3 };
enum { OUT_FLAT = 0, OUT_NCHWRES = 1 };

// ---------------- fused weight prep ----------------
__device__ __forceinline__ void wtrans_dev(const float* __restrict__ w, float* __restrict__ wT,
                                           int srcCIN, int cinOff, int dstCIN, int COUTv,
                                           int total, int idx) {
  if (idx >= total) return;
  int co = idx % COUTv;
  int t = idx / COUTv;
  int ci = t % dstCIN;
  int tap = t / dstCIN;
  wT[idx] = w[((long)co * srcCIN + cinOff + ci) * 9 + tap];
}

// MFMA weight prep: layout [tap][kc][kch][co][8e], hi plane then lo plane (each `total` elems).
__device__ __forceinline__ void wprep_mfma(const float* __restrict__ w, unsigned short* __restrict__ dst,
                                           int srcCIN, int cinOff, int COUTv, int COUTP,
                                           int total, int idx) {
  if (idx >= total) return;
  int e = idx & 7;
  int t = idx >> 3;
  int co = t % COUTP; t /= COUTP;
  int kch = t & 3; t >>= 2;
  int kc = t % 3;
  int tap = t / 3;
  int ci = kc * 32 + kch * 8 + e;
  float v = 0.f;
  if (co < COUTv) v = w[((long)co * srcCIN + cinOff + ci) * 9 + tap];
  unsigned short h = f2bf(v);
  dst[idx] = h;
  dst[total + idx] = f2bf(v - bf2f(h));
}

__global__ __launch_bounds__(256) void prep_all(
    const float* __restrict__ cf_w, const float* __restrict__ oc1_w,
    const float* __restrict__ oc2_w, const float* __restrict__ om_w,
    const float* __restrict__ cl_w,
    const float* __restrict__ wq, const float* __restrict__ wk, const float* __restrict__ wv,
    const float* __restrict__ bq, const float* __restrict__ bk, const float* __restrict__ bv,
    float* __restrict__ T0, float* __restrict__ T4,
    unsigned short* __restrict__ WB1, unsigned short* __restrict__ WB2,
    unsigned short* __restrict__ WB3,
    float* __restrict__ WQKV, float* __restrict__ BQKV) {
  int idx = blockIdx.x * 256 + threadIdx.x;
  switch (blockIdx.y) {
    case 0: wtrans_dev(cf_w, T0, 64, 0, 64, 96, 55296, idx); break;
    case 1: wtrans_dev(cl_w, T4, 96, 0, 96, 64, 55296, idx); break;
    case 2: {
      if (idx < 96 * 288) {
        int e288 = idx % 288;
        int c = idx / 288;
        int m = e288 / 96, e = e288 % 96;
        const float* wm = (m == 0) ? wq : (m == 1) ? wk : wv;
        WQKV[idx] = wm[e * 96 + c];
      }
      if (idx < 288) {
        int m = idx / 96, e = idx % 96;
        const float* bm = (m == 0) ? bq : (m == 1) ? bk : bv;
        BQKV[idx] = bm[e];
      }
      break;
    }
    case 3: wprep_mfma(oc1_w, WB1, 192, 0, 96, 96, 82944, idx); break;
    case 4: wprep_mfma(oc1_w, WB1 + 2 * 82944, 192, 96, 96, 96, 82944, idx); break;
    case 5: wprep_mfma(oc2_w, WB2, 96, 0, 96, 96, 82944, idx); break;
    default: wprep_mfma(om_w, WB3, 96, 0, 216, 224, 193536, idx); break;
  }
}

// ---------------- fp32 3x3 conv, GEMV-style (kept for emb + final) ----------------
template <int CIN, int COUT, int CG, int ACT, int IMODE, int OMODE, bool QKVIN>
__global__ __launch_bounds__(256) void conv3x3v4(
    const float* __restrict__ in, const float* __restrict__ in2,
    const float* __restrict__ bias_in,
    const float* __restrict__ wT,
    const float* __restrict__ bias,
    float* __restrict__ out,
    const float* __restrict__ resid) {
  constexpr int NOCG = COUT / CG;
  constexpr int NCH = CIN / 8;
  const int y0 = blockIdx.x * 4;
  const int iz = blockIdx.y;
  const int cg = blockIdx.z;
  const int tid = threadIdx.x;
  const int x = tid & 63;
  const int wv = tid >> 6;
  const int ocb = cg * NOCG;

  __shared__ float lds[6 * 66 * 9];

  const float* baseA;
  const float* wTe = wT;
  if constexpr (IMODE == IN_NCHW) {
    baseA = in + (long)iz * (CIN * PIXN);
  } else {
    baseA = in + (long)iz * (PIXN * CIN);
  }

  float acc[NOCG];
#pragma unroll
  for (int j = 0; j < NOCG; ++j) acc[j] = bias ? bias[ocb + j] : 0.f;

#pragma unroll 1
  for (int ch = 0; ch < NCH; ++ch) {
    __syncthreads();
    if constexpr (IMODE == IN_NCHW) {
      for (int i = tid; i < 8 * 396; i += 256) {
        int cin = i / 396;
        int t = i - cin * 396;
        int r = t / 66, px = t - r * 66;
        int yy = y0 - 1 + r, xx = px - 1;
        float v = 0.f;
        if ((unsigned)yy < 64u && (unsigned)xx < 64u)
          v = baseA[(long)(ch * 8 + cin) * PIXN + yy * 64 + xx];
        lds[t * 9 + cin] = v;
      }
    } else {
      for (int i = tid; i < 396 * 2; i += 256) {
        int c4 = i & 1, t = i >> 1;
        int r = t / 66, px = t - r * 66;
        int yy = y0 - 1 + r, xx = px - 1;
        float4 v = make_float4(0.f, 0.f, 0.f, 0.f);
        if ((unsigned)yy < 64u && (unsigned)xx < 64u)
          v = *reinterpret_cast<const float4*>(
              baseA + (long)(yy * 64 + xx) * CIN + ch * 8 + c4 * 4);
        int b0 = t * 9 + c4 * 4;
        lds[b0] = v.x; lds[b0 + 1] = v.y; lds[b0 + 2] = v.z; lds[b0 + 3] = v.w;
      }
    }
    __syncthreads();

#pragma unroll
    for (int r = 0; r < 3; ++r) {
#pragma unroll
      for (int kx = 0; kx < 3; ++kx) {
        const float* wp = wTe + ((long)((r * 3 + kx) * CIN + ch * 8)) * COUT + ocb;
        const int lb = ((wv + r) * 66 + x + kx) * 9;
#pragma unroll 2
        for (int cin = 0; cin < 8; ++cin) {
          float xv = lds[lb + cin];
          const float* wpc = wp + cin * COUT;
#pragma unroll
          for (int j = 0; j < NOCG; ++j)
            acc[j] = fmaf(xv, wpc[j], acc[j]);
        }
      }
    }
  }

  const int yo = y0 + wv;
#pragma unroll
  for (int j = 0; j < NOCG; ++j) {
    if (ACT == ACT_LRELU) acc[j] = acc[j] >= 0.f ? acc[j] : 0.1f * acc[j];
  }
  if constexpr (OMODE == OUT_FLAT) {
    float* orow = out + ((long)iz * PIXN + yo * 64 + x) * COUT + ocb;
#pragma unroll
    for (int j4 = 0; j4 < NOCG / 4; ++j4) {
      float4 v = make_float4(acc[j4 * 4], acc[j4 * 4 + 1], acc[j4 * 4 + 2], acc[j4 * 4 + 3]);
      *reinterpret_cast<float4*>(orow + j4 * 4) = v;
    }
  } else {
#pragma unroll
    for (int j = 0; j < NOCG; ++j) {
      int oc = ocb + j;
      long oo = (long)iz * (COUT * PIXN) + (long)oc * PIXN + yo * 64 + x;
      out[oo] = acc[j] + resid[oo];
    }
  }
}

// ---------------- bf16x3-split MFMA 3x3 conv, B direct-from-L2 ----------------
// Block: 512 thr = 8 waves (4m x 2n); tile = 128 px x COUTP.
// A in LDS per-kc (34 KB only).  B fragments are lane-addressable in the prepped
// [tap][kc][kch][co][8] layout -> each lane dwordx4-loads its own B from L2,
// ping-pong 1-nt-deep prefetch.  No Bbuf, no per-step barriers (2 per kc restage).
template <int CIN, int COUT, int COUTP, int IMODE, int ACT>
__global__ __launch_bounds__(512, 4) void conv3x3r(
    const float* __restrict__ in, const float* __restrict__ in2,
    const float* __restrict__ bias_in,
    const unsigned short* __restrict__ WB,
    const float* __restrict__ bias,
    float* __restrict__ out) {
  constexpr int KC = CIN / 32;             // 3
  constexpr int NTW = COUTP / 32;          // 3 (off) or 7 (om)
  constexpr int AST = 4 * 66 * 8 + 8;      // padded ci8 stride (elems)
  constexpr int APL = 4 * AST;             // per-plane A elems (one kc = 4 ci8)
  constexpr int BSTEP = COUTP * 32;        // per-plane B elems per K-step
  constexpr int TOTB = 9 * KC * BSTEP;     // per-plane B elems total

  __shared__ __align__(16) unsigned short Abuf[2 * APL];

  const int tid = threadIdx.x;
  const int lane = tid & 63;
  const int wid = tid >> 6;
  const int wm = wid & 3;
  const int wn = wid >> 2;
  const int iz = blockIdx.y;
  const int y0 = blockIdx.x * 2;

  const float* baseA;
  const float* baseB2 = nullptr;
  const unsigned short* wbe = WB;
  int LDV;
  if constexpr (IMODE == IN_UVPAIR) {
    int pair = iz >> 2, b = iz & 3;
    int jj = pair >> 1, rr2 = pair & 1;
    int ii = (rr2 == 0) ? (jj == 0 ? 1 : 0) : (jj == 2 ? 1 : 2);
    baseA = in + (long)(b * 3 + jj) * (PIXN * 96);
    baseB2 = in2 + (long)(b * 3 + ii) * (PIXN * 96);
    LDV = 96;
  } else if constexpr (IMODE == IN_QKV) {
    int sel = iz / 12, img = iz % 12;
    baseA = in + (long)img * (PIXN * 288) + sel * 96;
    wbe = WB + (long)sel * (2 * TOTB);
    LDV = 288;
  } else {
    baseA = in + (long)iz * ((long)PIXN * CIN);
    LDV = CIN;
  }

  // ---- stage A for one kc group (32 ci): fp32 -> bf16 hi/lo ----
  auto stageA = [&](int kc) {
    for (int i = tid; i < 4 * 66 * 8; i += 512) {
      int ci4 = i & 7;             // 0..7 within this kc
      int t = i >> 3;
      int xp = t % 66, rr = t / 66;
      int y = y0 + rr - 1, x = xp - 1;
      float4 v = make_float4(0.f, 0.f, 0.f, 0.f);
      if ((unsigned)y < 64u && (unsigned)x < 64u) {
        long off = (long)(y * 64 + x) * LDV + kc * 32 + ci4 * 4;
        if constexpr (IMODE == IN_UVPAIR) {
          float4 u = *reinterpret_cast<const float4*>(baseA + off);
          float4 w2 = *reinterpret_cast<const float4*>(baseB2 + off);
          float4 bi = *reinterpret_cast<const float4*>(bias_in + kc * 32 + ci4 * 4);
          v.x = u.x + w2.x + bi.x; v.x = v.x >= 0.f ? v.x : 0.1f * v.x;
          v.y = u.y + w2.y + bi.y; v.y = v.y >= 0.f ? v.y : 0.1f * v.y;
          v.z = u.z + w2.z + bi.z; v.z = v.z >= 0.f ? v.z : 0.1f * v.z;
          v.w = u.w + w2.w + bi.w; v.w = v.w >= 0.f ? v.w : 0.1f * v.w;
        } else {
          v = *reinterpret_cast<const float4*>(baseA + off);
        }
      }
      unsigned short h0 = f2bf(v.x), h1 = f2bf(v.y), h2 = f2bf(v.z), h3 = f2bf(v.w);
      u16x4 hv = {h0, h1, h2, h3};
      u16x4 lv = {f2bf(v.x - bf2f(h0)), f2bf(v.y - bf2f(h1)),
                  f2bf(v.z - bf2f(h2)), f2bf(v.w - bf2f(h3))};
      int base = (ci4 >> 1) * AST + (rr * 66 + xp) * 8 + (ci4 & 1) * 4;
      *reinterpret_cast<u16x4*>(&Abuf[base]) = hv;
      *reinterpret_cast<u16x4*>(&Abuf[APL + base]) = lv;
    }
  };

  // ---- init acc ----
  f32x4 acc[2][NTW];
#pragma unroll
  for (int nt = 0; nt < NTW; ++nt) {
    int co = (wn * NTW + nt) * 16 + (lane & 15);
    float b0 = 0.f;
    if (bias != nullptr && co < COUT) b0 = bias[co];
#pragma unroll
    for (int mt2 = 0; mt2 < 2; ++mt2) {
      acc[mt2][nt][0] = b0; acc[mt2][nt][1] = b0;
      acc[mt2][nt][2] = b0; acc[mt2][nt][3] = b0;
    }
  }

  stageA(0);
  __syncthreads();

  // per-lane B fragment offset within a step (elems)
  const int blo = ((lane >> 4) * COUTP + (wn * NTW) * 16 + (lane & 15)) * 8;

  s16x8 b0h, b0l, b1h, b1l;
  {
    const unsigned short* p = wbe + blo;   // step (tap0,kc0), nt0
    b0h = *reinterpret_cast<const s16x8*>(p);
    b0l = *reinterpret_cast<const s16x8*>(p + TOTB);
  }

  long bo = 0;
#pragma unroll 1
  for (int kc = 0; kc < KC; ++kc) {
#pragma unroll 1
    for (int tap = 0; tap < 9; ++tap) {
      const int dy = tap / 3, dx = tap % 3;
      const long bo_next = (tap < 8) ? bo + (long)KC * BSTEP
                                     : ((kc + 1 < KC) ? (long)(kc + 1) * BSTEP : 0);

      // A fragments for this tap (4 x ds_read_b128)
      s16x8 ah[2], al[2];
      {
        int ci8 = lane >> 4;
        int m = lane & 15;
#pragma unroll
        for (int mt2 = 0; mt2 < 2; ++mt2) {
          int px = (wm * 2 + mt2) * 16 + m;
          int r = px >> 6, x = px & 63;
          int aoff = ci8 * AST + ((r + dy) * 66 + (x + dx)) * 8;
          ah[mt2] = *reinterpret_cast<const s16x8*>(&Abuf[aoff]);
          al[mt2] = *reinterpret_cast<const s16x8*>(&Abuf[APL + aoff]);
        }
      }

#pragma unroll
      for (int nt = 0; nt < NTW; ++nt) {
        // prefetch next fragment pair into the other slot (hidden under MFMAs)
        const long nboff = (nt + 1 < NTW) ? (bo + (long)(nt + 1) * 128) : bo_next;
        const unsigned short* np = wbe + nboff + blo;
        if ((nt & 1) == 0) {
          b1h = *reinterpret_cast<const s16x8*>(np);
          b1l = *reinterpret_cast<const s16x8*>(np + TOTB);
        } else {
          b0h = *reinterpret_cast<const s16x8*>(np);
          b0l = *reinterpret_cast<const s16x8*>(np + TOTB);
        }
        const s16x8 bh = (nt & 1) ? b1h : b0h;
        const s16x8 bl = (nt & 1) ? b1l : b0l;
#pragma unroll
        for (int mt2 = 0; mt2 < 2; ++mt2) {
          acc[mt2][nt] = __builtin_amdgcn_mfma_f32_16x16x32_bf16(ah[mt2], bh, acc[mt2][nt], 0, 0, 0);
          acc[mt2][nt] = __builtin_amdgcn_mfma_f32_16x16x32_bf16(al[mt2], bh, acc[mt2][nt], 0, 0, 0);
          acc[mt2][nt] = __builtin_amdgcn_mfma_f32_16x16x32_bf16(ah[mt2], bl, acc[mt2][nt], 0, 0, 0);
        }
      }
      if constexpr (NTW & 1) {   // odd NTW: last prefetch landed in slot 1
        b0h = b1h; b0l = b1l;
      }
      bo = bo_next;
    }
    if (kc + 1 < KC) {
      __syncthreads();           // all A reads of this kc done
      stageA(kc + 1);
      __syncthreads();
    }
  }

  // ---- epilogue ----
  const long obase = (long)iz * PIXN + blockIdx.x * 128;
#pragma unroll
  for (int mt2 = 0; mt2 < 2; ++mt2) {
#pragma unroll
    for (int nt = 0; nt < NTW; ++nt) {
      int co = (wn * NTW + nt) * 16 + (lane & 15);
      if (COUTP > COUT && co >= COUT) continue;
#pragma unroll
      for (int r = 0; r < 4; ++r) {
        int px = (wm * 2 + mt2) * 16 + (lane >> 4) * 4 + r;
        float v = acc[mt2][nt][r];
        if constexpr (ACT == ACT_LRELU) v = v >= 0.f ? v : 0.1f * v;
        if constexpr (ACT == ACT_SIG144) {
          if (co >= 144) v = 1.f / (1.f + expf(-v));
        }
        out[(obase + px) * COUT + co] = v;
      }
    }
  }
}

// ---------------- 1x1 qkv projection, GEMV-style ----------------
__global__ __launch_bounds__(256) void gemm1x1v2(const float* __restrict__ in,
                                                 const float* __restrict__ wT,
                                                 const float* __restrict__ bias,
                                                 float* __restrict__ out) {
  const int pcb = blockIdx.x;
  const int img = blockIdx.y;
  const int cg = blockIdx.z;
  const int tid = threadIdx.x;
  __shared__ float lds[256 * 33];
  float acc[96];
#pragma unroll
  for (int j = 0; j < 96; ++j) acc[j] = bias[cg * 96 + j];
  const float* ibase = in + ((long)img * PIXN + pcb * 256) * 96;
#pragma unroll 1
  for (int cc = 0; cc < 96; cc += 32) {
    __syncthreads();
    for (int i = tid; i < 2048; i += 256) {
      int px = i >> 3, c4 = i & 7;
      float4 v = *reinterpret_cast<const float4*>(ibase + (long)px * 96 + cc + c4 * 4);
      int b0 = px * 33 + c4 * 4;
      lds[b0] = v.x; lds[b0 + 1] = v.y; lds[b0 + 2] = v.z; lds[b0 + 3] = v.w;
    }
    __syncthreads();
#pragma unroll 2
    for (int c = 0; c < 32; ++c) {
      float xv = lds[tid * 33 + c];
      const float* wp = wT + (long)(cc + c) * 288 + cg * 96;
#pragma unroll
      for (int j = 0; j < 96; ++j) acc[j] = fmaf(xv, wp[j], acc[j]);
    }
  }
  float* orow = out + ((long)img * PIXN + pcb * 256 + tid) * 288 + cg * 96;
#pragma unroll
  for (int j4 = 0; j4 < 24; ++j4) {
    float4 v = make_float4(acc[j4 * 4], acc[j4 * 4 + 1], acc[j4 * 4 + 2], acc[j4 * 4 + 3]);
    *reinterpret_cast<float4*>(orow + j4 * 4) = v;
  }
}

// ---------------- attn v3: 2 px/wave, 3 ch/lane, LDS-precomputed bilinear setup ----------------
// Setup per (pixel, g, n): 4 corner weights (mask+bounds folded) + 4 base indices
// (pos*288+96, K base; V adds +96).  K loop: broadcast LDS read + 12 gathers + fmafs.
#define CWSLOT 580  // 72*8 + 4 pad (breaks ph bank collision; residual 2-way is free)
__global__ __launch_bounds__(256) void attn3_k(const float* __restrict__ qkv,
                                               const float* __restrict__ om,
                                               float* __restrict__ w_buf,
                                               f16* __restrict__ vre) {
  const int pair = blockIdx.y;
  const int jj = pair >> 1, rr = pair & 1;
  const int ii = (rr == 0) ? (jj == 0 ? 1 : 0) : (jj == 2 ? 1 : 2);
  const int wv = threadIdx.x >> 6;
  const int lane = threadIdx.x & 63;
  const int bp0 = blockIdx.x * 8 + wv * 2;  // even; both px same b

  __shared__ float s_om[8 * 216];
  __shared__ float s_cw[8 * CWSLOT];

  // om rows for 2 consecutive pixels are contiguous: 432 floats
  {
    const float* omrow = om + ((long)pair * 16384 + bp0) * 216;
    float* dst = s_om + wv * 432;
    for (int i = lane; i < 432; i += 64) dst[i] = omrow[i];
  }
  __syncthreads();

  // setup: 144 combos per wave (2 px x 8 g x 9 n)
  for (int t = lane; t < 144; t += 64) {
    int ph = t / 72, cmb = t - ph * 72;
    int g = cmb / 9, n = cmb - g * 9;
    int p = (bp0 + ph) & 4095;
    int y = p >> 6, x = p & 63;
    const float* so = s_om + (wv * 2 + ph) * 216;
    float oy = so[g * 9 + n], ox = so[72 + g * 9 + n], m = so[144 + g * 9 + n];
    float py = oy + (float)(y + n / 3 - 1);
    float px = ox + (float)(x + n % 3 - 1);
    float y0f = floorf(py), x0f = floorf(px);
    float wy = py - y0f, wx = px - x0f;
    float* dst = s_cw + (wv * 2 + ph) * CWSLOT + cmb * 8;
#pragma unroll
    for (int dy = 0; dy < 2; ++dy) {
#pragma unroll
      for (int dx = 0; dx < 2; ++dx) {
        float yc = y0f + dy, xc = x0f + dx;
        bool valid = (yc >= 0.f) & (yc < 64.f) & (xc >= 0.f) & (xc < 64.f);
        float w = (dy ? wy : 1.f - wy) * (dx ? wx : 1.f - wx) * m;
        w = valid ? w : 0.f;
        int yi = (int)fminf(fmaxf(yc, 0.f), 63.f);
        int xi = (int)fminf(fmaxf(xc, 0.f), 63.f);
        int idx = (yi * 64 + xi) * 288 + 96;  // K base; V adds +96
        dst[dy * 2 + dx] = w;
        dst[4 + dy * 2 + dx] = __int_as_float(idx);
      }
    }
  }
  __syncthreads();

  const int ph = lane >> 5;
  const int li = lane & 31;
  const int bp = bp0 + ph;
  const int b = bp >> 12;
  const int cb = li * 3;       // channel base 0..93
  const int g = li >> 2;       // == (3*li)/12
  const float* kimg = qkv + (long)(b * 3 + ii) * (PIXN * 288);
  const float* qrow = qkv + ((long)(b * 3 + jj) * PIXN + (bp & 4095)) * 288 + cb;
  const float q0 = qrow[0], q1 = qrow[1], q2 = qrow[2];
  const float* cw = s_cw + (wv * 2 + ph) * CWSLOT + g * 9 * 8;

  float ka[9][3];
  float rel[9];
#pragma unroll
  for (int n = 0; n < 9; ++n) {
    float4 w4 = *reinterpret_cast<const float4*>(cw + n * 8);
    float4 i4 = *reinterpret_cast<const float4*>(cw + n * 8 + 4);
    int ia = __float_as_int(i4.x) + cb, ib = __float_as_int(i4.y) + cb;
    int ic = __float_as_int(i4.z) + cb, id = __float_as_int(i4.w) + cb;
#pragma unroll
    for (int j = 0; j < 3; ++j) {
      float a = w4.x * kimg[ia + j];
      a = fmaf(w4.y, kimg[ib + j], a);
      a = fmaf(w4.z, kimg[ic + j], a);
      a = fmaf(w4.w, kimg[id + j], a);
      ka[n][j] = a;
    }
    float part = q0 * ka[n][0];
    part = fmaf(q1, ka[n][1], part);
    part = fmaf(q2, ka[n][2], part);
#pragma unroll
    for (int off = 16; off > 0; off >>= 1) part += __shfl_xor(part, off, 64);
    rel[n] = part;
  }

  // top-2 selection (rel uniform within each half-wave; first-index wins ties)
  int i0 = 0; float v0 = rel[0];
  float ks0a = ka[0][0], ks0b = ka[0][1], ks0c = ka[0][2];
#pragma unroll
  for (int n = 1; n < 9; ++n) {
    bool t = rel[n] > v0;
    v0 = t ? rel[n] : v0; i0 = t ? n : i0;
    ks0a = t ? ka[n][0] : ks0a; ks0b = t ? ka[n][1] : ks0b; ks0c = t ? ka[n][2] : ks0c;
  }
  int i1 = 0; float v1 = -3.4e38f;
  float ks1a = 0.f, ks1b = 0.f, ks1c = 0.f;
#pragma unroll
  for (int n = 0; n < 9; ++n) {
    bool t = (n != i0) && rel[n] > v1;
    v1 = t ? rel[n] : v1; i1 = t ? n : i1;
    ks1a = t ? ka[n][0] : ks1a; ks1b = t ? ka[n][1] : ks1b; ks1c = t ? ka[n][2] : ks1c;
  }
  float e = expf(v1 - v0);
  float cw0 = 1.f / (1.f + e), cw1 = e * cw0;

  float wpart = q0 * (cw0 * ks0a + cw1 * ks1a);
  wpart = fmaf(q1, cw0 * ks0b + cw1 * ks1b, wpart);
  wpart = fmaf(q2, cw0 * ks0c + cw1 * ks1c, wpart);
#pragma unroll
  for (int off = 16; off > 0; off >>= 1) wpart += __shfl_xor(wpart, off, 64);
  if (li == 0) w_buf[(long)pair * 16384 + bp] = wpart;

  // V phase: reuse setup for the two selected taps
  float4 wA = *reinterpret_cast<const float4*>(cw + i0 * 8);
  float4 iA = *reinterpret_cast<const float4*>(cw + i0 * 8 + 4);
  float4 wB = *reinterpret_cast<const float4*>(cw + i1 * 8);
  float4 iB = *reinterpret_cast<const float4*>(cw + i1 * 8 + 4);
  int a0 = __float_as_int(iA.x) + 96 + cb, a1 = __float_as_int(iA.y) + 96 + cb;
  int a2 = __float_as_int(iA.z) + 96 + cb, a3 = __float_as_int(iA.w) + 96 + cb;
  int b0 = __float_as_int(iB.x) + 96 + cb, b1 = __float_as_int(iB.y) + 96 + cb;
  int b2 = __float_as_int(iB.z) + 96 + cb, b3 = __float_as_int(iB.w) + 96 + cb;
  f16* vrow = vre + ((long)pair * 16384 + bp) * 96 + cb;
#pragma unroll
  for (int j = 0; j < 3; ++j) {
    float va = wA.x * kimg[a0 + j];
    va = fmaf(wA.y, kimg[a1 + j], va);
    va = fmaf(wA.z, kimg[a2 + j], va);
    va = fmaf(wA.w, kimg[a3 + j], va);
    float vb = wB.x * kimg[b0 + j];
    vb = fmaf(wB.y, kimg[b1 + j], vb);
    vb = fmaf(wB.z, kimg[b2 + j], vb);
    vb = fmaf(wB.w, kimg[b3 + j], vb);
    vrow[j] = f2h(cw0 * va + cw1 * vb);
  }
}

// ---------------- merge: softmax over the 2 source frames -> f_t fp32 flat ----------------
__global__ __launch_bounds__(256) void merge_k(const float* __restrict__ w_buf,
                                               const f16* __restrict__ vre,
                                               float* __restrict__ f_t) {
  long idx = (long)blockIdx.x * 256 + threadIdx.x;
  const long TOT = (long)4 * 3 * PIXN * 24;
  if (idx >= TOT) return;
  int c4 = idx % 24;
  long t = idx / 24;
  int p = t % PIXN;
  long t2 = t / PIXN;
  int jj = t2 % 3;
  int b = (int)(t2 / 3);
  long bpi = (long)b * PIXN + p;
  int pr0 = jj * 2, pr1 = jj * 2 + 1;
  float w0 = w_buf[(long)pr0 * 16384 + bpi];
  float w1 = w_buf[(long)pr1 * 16384 + bpi];
  float mx = fmaxf(w0, w1);
  float e0 = expf(w0 - mx), e1 = expf(w1 - mx);
  float inv = 1.f / (e0 + e1);
  float s0 = e0 * inv, s1 = e1 * inv;
  const f16* va = &vre[((long)pr0 * 16384 + bpi) * 96 + c4 * 4];
  const f16* vb = &vre[((long)pr1 * 16384 + bpi) * 96 + c4 * 4];
  float4 r;
  r.x = s0 * h2f(va[0]) + s1 * h2f(vb[0]);
  r.y = s0 * h2f(va[1]) + s1 * h2f(vb[1]);
  r.z = s0 * h2f(va[2]) + s1 * h2f(vb[2]);
  r.w = s0 * h2f(va[3]) + s1 * h2f(vb[3]);
  *reinterpret_cast<float4*>(f_t + ((long)(b * 3 + jj) * PIXN + p) * 96 + c4 * 4) = r;
}

// ---------------- host ----------------
extern "C" void kernel_launch(void* const* d_in, const int* in_sizes, int n_in,
                              void* d_out, int out_size, void* d_ws, size_t ws_size,
                              hipStream_t stream) {
  const float* fea = (const float*)d_in[0];
  const float* cf_w = (const float*)d_in[1];
  const float* cf_b = (const float*)d_in[2];
  const float* wq = (const float*)d_in[3];
  const float* bq = (const float*)d_in[4];
  const float* wk = (const float*)d_in[5];
  const float* bk = (const float*)d_in[6];
  const float* wv = (const float*)d_in[7];
  const float* bv = (const float*)d_in[8];
  const float* oc1_w = (const float*)d_in[9];
  const float* oc1_b = (const float*)d_in[10];
  const float* oc2_w = (const float*)d_in[11];
  const float* oc2_b = (const float*)d_in[12];
  const float* om_w = (const float*)d_in[13];
  const float* om_b = (const float*)d_in[14];
  const float* cl_w = (const float*)d_in[15];
  const float* cl_b = (const float*)d_in[16];

  char* base = (char*)d_ws;
  size_t o = 0;
  auto carve = [&](size_t bytes) { char* p = base + o; o += (bytes + 255) & ~255UL; return p; };

  float* T0 = (float*)carve(55296UL * 4);
  float* T4 = (float*)carve(55296UL * 4);
  unsigned short* WB1 = (unsigned short*)carve(2UL * 2 * 82944 * 2);   // [sel][hi|lo]
  unsigned short* WB2 = (unsigned short*)carve(2UL * 82944 * 2);
  unsigned short* WB3 = (unsigned short*)carve(2UL * 193536 * 2);
  float* WQKV = (float*)carve(27648UL * 4);
  float* BQKV = (float*)carve(288UL * 4);

  // Z: emb (4.7M floats) early; om (21.2M, stride 216) later (emb dead)
  float* Z = (float*)carve(21233664UL * 4);
  float* emb_t = Z;
  float* om_t = Z;
  float* qkv_t = (float*)carve(14155776UL * 4);
  float* U_t = (float*)carve(4718592UL * 4);
  float* V_t = (float*)carve(4718592UL * 4);   // must stay contiguous after U_t
  float* off2_t = (float*)carve(9437184UL * 4);
  float* w_buf = (float*)carve(98304UL * 4);
  float* f_t = U_t;
  f16* vre_b = (f16*)V_t;

  // --- all weight prep in one launch (7 jobs on grid.y) ---
  prep_all<<<dim3(756, 7), 256, 0, stream>>>(cf_w, oc1_w, oc2_w, om_w, cl_w,
                                             wq, wk, wv, bq, bk, bv,
                                             T0, T4, WB1, WB2, WB3, WQKV, BQKV);

  // --- emb conv (fp32): NCHW in -> NHWC flat; NOCG=48 ---
  conv3x3v4<64, 96, 2, ACT_NONE, IN_NCHW, OUT_FLAT, false><<<dim3(16, 12, 2), 256, 0, stream>>>(
      fea, nullptr, nullptr, T0, cf_b, emb_t, nullptr);
  // --- qkv 1x1 (fp32) ---
  gemm1x1v2<<<dim3(16, 12, 3), 256, 0, stream>>>(emb_t, WQKV, BQKV, qkv_t);

  // --- off1 split (MFMA bf16x3, B-from-L2): U = convA(q_img), V = convB(k_img) ---
  conv3x3r<96, 96, 96, IN_QKV, ACT_NONE><<<dim3(32, 24), 512, 0, stream>>>(
      qkv_t, nullptr, nullptr, WB1, nullptr, U_t);

  // --- off2 (MFMA bf16x3, B-from-L2) with fused off1 epilogue: stage lrelu(U+V+b1) ---
  conv3x3r<96, 96, 96, IN_UVPAIR, ACT_LRELU><<<dim3(32, 24), 512, 0, stream>>>(
      U_t, V_t, oc1_b, WB2, oc2_b, off2_t);

  // --- om conv (MFMA bf16x3, COUT 216 padded to 224, B-from-L2) + fused sigmoid ---
  conv3x3r<96, 216, 224, IN_FLAT, ACT_SIG144><<<dim3(32, 24), 512, 0, stream>>>(
      off2_t, nullptr, nullptr, WB3, om_b, om_t);

  // --- fused deformable attention (fp32; 2 px/wave, 3 ch/lane, LDS setup) ---
  attn3_k<<<dim3(2048, 6), 256, 0, stream>>>(qkv_t, om_t, w_buf, vre_b);
  merge_k<<<4608, 256, 0, stream>>>(w_buf, vre_b, f_t);

  // --- final conv + residual -> NCHW fp32; NOCG=32 ---
  conv3x3v4<96, 64, 2, ACT_NONE, IN_FLAT, OUT_NCHWRES, false><<<dim3(16, 12, 2), 256, 0, stream>>>(
      f_t, nullptr, nullptr, T4, cl_b, (float*)d_out, fea);
}

// Round 5
// 515.934 us; speedup vs baseline: 3.3284x; 1.5342x over previous
//
#include <hip/hip_runtime.h>
#include <math.h>

#define PIXN 4096

typedef _Float16 f16;
typedef short s16x8 __attribute__((ext_vector_type(8)));
typedef unsigned short u16x4 __attribute__((ext_vector_type(4)));
typedef float f32x4 __attribute__((ext_vector_type(4)));

__device__ __forceinline__ f16 f2h(float f) { return (f16)f; }
__device__ __forceinline__ float h2f(f16 h) { return (float)h; }

// bf16 round-to-nearest-even via bit trick; residual f - bf2f(f2bf(f)) is exact in fp32.
__device__ __forceinline__ unsigned short f2bf(float f) {
  unsigned u = __float_as_uint(f);
  u += 0x7fffu + ((u >> 16) & 1u);
  return (unsigned short)(u >> 16);
}
__device__ __forceinline__ float bf2f(unsigned short h) {
  return __uint_as_float(((unsigned)h) << 16);
}

enum { ACT_NONE = 0, ACT_LRELU = 1, ACT_SIG144 = 2 };
enum { IN_FLAT = 1, IN_UVPAIR = 2, IN_QKV = 3, IN_BF = 4 };
enum { OUT_FLAT = 0, OUT_NCHWRES = 1 };

// ---------------- weight prep ----------------
// MFMA weight prep: layout [tap][kc][kch][co][8e], hi plane then lo plane (each `total` elems).
__device__ __forceinline__ void wprep_mfma(const float* __restrict__ w, unsigned short* __restrict__ dst,
                                           int srcCIN, int cinOff, int COUTv, int COUTP,
                                           int total, int idx) {
  if (idx >= total) return;
  int e = idx & 7;
  int t = idx >> 3;
  int co = t % COUTP; t /= COUTP;
  int kch = t & 3; t >>= 2;
  int KCv = srcCIN == 64 ? 2 : 3;  // not used; kept simple below
  (void)KCv;
  int kc = t % 3;
  int tap = t / 3;
  int ci = kc * 32 + kch * 8 + e;
  float v = 0.f;
  if (co < COUTv) v = w[((long)co * srcCIN + cinOff + ci) * 9 + tap];
  unsigned short h = f2bf(v);
  dst[idx] = h;
  dst[total + idx] = f2bf(v - bf2f(h));
}

__global__ __launch_bounds__(256) void prep_all(
    const float* __restrict__ cf_w, const float* __restrict__ oc1_w,
    const float* __restrict__ oc2_w, const float* __restrict__ om_w,
    const float* __restrict__ cl_w,
    const float* __restrict__ wq, const float* __restrict__ wk, const float* __restrict__ wv,
    const float* __restrict__ bq, const float* __restrict__ bk, const float* __restrict__ bv,
    const float* __restrict__ cf_b,
    unsigned short* __restrict__ WBQ, float* __restrict__ BQ,
    unsigned short* __restrict__ WB1, unsigned short* __restrict__ WB2,
    unsigned short* __restrict__ WB3, unsigned short* __restrict__ WB4) {
  int idx = blockIdx.x * 256 + threadIdx.x;
  switch (blockIdx.y) {
    case 0: {  // composite qkv conv: W'[co,ci,tap] = sum_e wsel[co,e] * cf_w[e,ci,tap]
      if (idx < 288) {
        int m = idx / 96, ep = idx % 96;
        const float* wm = (m == 0) ? wq : (m == 1) ? wk : wv;
        const float* bm = (m == 0) ? bq : (m == 1) ? bk : bv;
        float s = bm[ep];
        for (int c = 0; c < 96; ++c) s = fmaf(wm[ep * 96 + c], cf_b[c], s);
        BQ[idx] = s;
      }
      if (idx < 165888) {
        int e = idx & 7;
        int t = idx >> 3;
        int co = t % 288; t /= 288;
        int kch = t & 3; t >>= 2;
        int kc = t & 1, tap = t >> 1;     // [tap][kc(2)][kch]
        int ci = kc * 32 + kch * 8 + e;
        int m = co / 96, ep = co % 96;
        const float* wm = (m == 0) ? wq : (m == 1) ? wk : wv;
        float s = 0.f;
        for (int c = 0; c < 96; ++c)
          s = fmaf(wm[ep * 96 + c], cf_w[((long)c * 64 + ci) * 9 + tap], s);
        unsigned short h = f2bf(s);
        WBQ[idx] = h;
        WBQ[165888 + idx] = f2bf(s - bf2f(h));
      }
      break;
    }
    case 1: wprep_mfma(oc1_w, WB1, 192, 0, 96, 96, 82944, idx); break;
    case 2: wprep_mfma(oc1_w, WB1 + 2 * 82944, 192, 96, 96, 96, 82944, idx); break;
    case 3: wprep_mfma(oc2_w, WB2, 96, 0, 96, 96, 82944, idx); break;
    case 4: wprep_mfma(om_w, WB3, 96, 0, 216, 224, 193536, idx); break;
    default: wprep_mfma(cl_w, WB4, 96, 0, 64, 64, 55296, idx); break;
  }
}

// ---------------- fea NCHW fp32 -> flat [img][px][64] bf16 hi/lo planes ----------------
__global__ __launch_bounds__(256) void nchw2bf(const float* __restrict__ fea,
                                               unsigned short* __restrict__ hi,
                                               unsigned short* __restrict__ lo) {
  const int y = blockIdx.x;
  const int img = blockIdx.y;
  const int t = threadIdx.x;
  const int x = t & 63, cg = t >> 6;
  __shared__ unsigned short sh[64][68], sl[64][68];
  const float* base = fea + ((long)img * 64) * PIXN + y * 64;
#pragma unroll
  for (int k = 0; k < 16; ++k) {
    int ci = cg * 16 + k;
    float v = base[(long)ci * PIXN + x];
    unsigned short h = f2bf(v);
    sh[x][ci] = h;
    sl[x][ci] = f2bf(v - bf2f(h));
  }
  __syncthreads();
  const long ob = (long)img * PIXN + y * 64;
  for (int i = t; i < 2048; i += 256) {
    int plane = i >> 10;
    int r = i & 1023;
    int px = r >> 4, q4 = r & 15;
    u16x4 v4 = *reinterpret_cast<const u16x4*>(plane ? &sl[px][q4 * 4] : &sh[px][q4 * 4]);
    unsigned short* dst = (plane ? lo : hi) + (ob + px) * 64 + q4 * 4;
    *reinterpret_cast<u16x4*>(dst) = v4;
  }
}

// ---------------- bf16x3-split MFMA 3x3 conv, B direct-from-L2 ----------------
// Block: 512 thr = 8 waves (4m x 2n); tile = 128 px x COG (co-group via blockIdx.z).
// A in LDS per-kc (34 KB).  B fragments lane-addressable in [tap][kc][kch][co][8]
// layout -> dwordx4 from L2, ping-pong 1-nt-deep prefetch.  2 barriers per kc.
template <int CIN, int COUT, int COUTW, int NCOG, int IMODE, int ACT, int OMODE>
__global__ __launch_bounds__(512, 4) void conv3x3r(
    const float* __restrict__ in, const float* __restrict__ in2,
    const float* __restrict__ bias_in,
    const unsigned short* __restrict__ WB,
    const float* __restrict__ bias,
    float* __restrict__ out,
    const float* __restrict__ resid) {
  constexpr int KC = CIN / 32;             // 2 or 3
  constexpr int COG = COUTW / NCOG;
  constexpr int NTW = COG / 32;            // n-tiles per wave (2 wn groups)
  constexpr int AST = 4 * 66 * 8 + 8;      // padded ci8 stride (elems)
  constexpr int APL = 4 * AST;             // per-plane A elems (one kc = 4 ci8)
  constexpr int BSTEP = COUTW * 32;        // per-plane B elems per K-step
  constexpr int TOTB = 9 * KC * BSTEP;     // per-plane B elems total

  __shared__ __align__(16) unsigned short Abuf[2 * APL];

  const int tid = threadIdx.x;
  const int lane = tid & 63;
  const int wid = tid >> 6;
  const int wm = wid & 3;
  const int wn = wid >> 2;
  const int iz = blockIdx.y;
  const int y0 = blockIdx.x * 2;
  const int zoff = (NCOG > 1) ? blockIdx.z * COG : 0;

  const float* baseA = nullptr;
  const float* baseB2 = nullptr;
  const unsigned short* hpl = nullptr;
  const unsigned short* lpl = nullptr;
  const unsigned short* wbe = WB;
  int LDV = CIN;
  if constexpr (IMODE == IN_UVPAIR) {
    int pair = iz >> 2, b = iz & 3;
    int jj = pair >> 1, rr2 = pair & 1;
    int ii = (rr2 == 0) ? (jj == 0 ? 1 : 0) : (jj == 2 ? 1 : 2);
    baseA = in + (long)(b * 3 + jj) * (PIXN * 96);
    baseB2 = in2 + (long)(b * 3 + ii) * (PIXN * 96);
    LDV = 96;
  } else if constexpr (IMODE == IN_QKV) {
    int sel = iz / 12, img = iz % 12;
    baseA = in + (long)img * (PIXN * 288) + sel * 96;
    wbe = WB + (long)sel * (2 * TOTB);
    LDV = 288;
  } else if constexpr (IMODE == IN_BF) {
    hpl = reinterpret_cast<const unsigned short*>(in) + (long)iz * (PIXN * 64);
    lpl = reinterpret_cast<const unsigned short*>(in2) + (long)iz * (PIXN * 64);
  } else {
    baseA = in + (long)iz * ((long)PIXN * CIN);
    LDV = CIN;
  }

  // ---- stage A for one kc group (32 ci) ----
  auto stageA = [&](int kc) {
    if constexpr (IMODE == IN_BF) {
      for (int i = tid; i < 4 * 66 * 4; i += 512) {
        int ci8 = i & 3;
        int t = i >> 2;
        int xp = t % 66, rr = t / 66;
        int y = y0 + rr - 1, x = xp - 1;
        s16x8 hv = {0, 0, 0, 0, 0, 0, 0, 0};
        s16x8 lv = {0, 0, 0, 0, 0, 0, 0, 0};
        if ((unsigned)y < 64u && (unsigned)x < 64u) {
          long off = (long)(y * 64 + x) * 64 + kc * 32 + ci8 * 8;
          hv = *reinterpret_cast<const s16x8*>(hpl + off);
          lv = *reinterpret_cast<const s16x8*>(lpl + off);
        }
        int base = ci8 * AST + (rr * 66 + xp) * 8;
        *reinterpret_cast<s16x8*>(&Abuf[base]) = hv;
        *reinterpret_cast<s16x8*>(&Abuf[APL + base]) = lv;
      }
    } else {
      for (int i = tid; i < 4 * 66 * 8; i += 512) {
        int ci4 = i & 7;
        int t = i >> 3;
        int xp = t % 66, rr = t / 66;
        int y = y0 + rr - 1, x = xp - 1;
        float4 v = make_float4(0.f, 0.f, 0.f, 0.f);
        if ((unsigned)y < 64u && (unsigned)x < 64u) {
          long off = (long)(y * 64 + x) * LDV + kc * 32 + ci4 * 4;
          if constexpr (IMODE == IN_UVPAIR) {
            float4 u = *reinterpret_cast<const float4*>(baseA + off);
            float4 w2 = *reinterpret_cast<const float4*>(baseB2 + off);
            float4 bi = *reinterpret_cast<const float4*>(bias_in + kc * 32 + ci4 * 4);
            v.x = u.x + w2.x + bi.x; v.x = v.x >= 0.f ? v.x : 0.1f * v.x;
            v.y = u.y + w2.y + bi.y; v.y = v.y >= 0.f ? v.y : 0.1f * v.y;
            v.z = u.z + w2.z + bi.z; v.z = v.z >= 0.f ? v.z : 0.1f * v.z;
            v.w = u.w + w2.w + bi.w; v.w = v.w >= 0.f ? v.w : 0.1f * v.w;
          } else {
            v = *reinterpret_cast<const float4*>(baseA + off);
          }
        }
        unsigned short h0 = f2bf(v.x), h1 = f2bf(v.y), h2 = f2bf(v.z), h3 = f2bf(v.w);
        u16x4 hv = {h0, h1, h2, h3};
        u16x4 lv = {f2bf(v.x - bf2f(h0)), f2bf(v.y - bf2f(h1)),
                    f2bf(v.z - bf2f(h2)), f2bf(v.w - bf2f(h3))};
        int base = (ci4 >> 1) * AST + (rr * 66 + xp) * 8 + (ci4 & 1) * 4;
        *reinterpret_cast<u16x4*>(&Abuf[base]) = hv;
        *reinterpret_cast<u16x4*>(&Abuf[APL + base]) = lv;
      }
    }
  };

  // ---- init acc ----
  f32x4 acc[2][NTW];
#pragma unroll
  for (int nt = 0; nt < NTW; ++nt) {
    int co = zoff + (wn * NTW + nt) * 16 + (lane & 15);
    float b0 = 0.f;
    if (bias != nullptr && co < COUT) b0 = bias[co];
#pragma unroll
    for (int mt2 = 0; mt2 < 2; ++mt2) {
      acc[mt2][nt][0] = b0; acc[mt2][nt][1] = b0;
      acc[mt2][nt][2] = b0; acc[mt2][nt][3] = b0;
    }
  }

  stageA(0);
  __syncthreads();

  // per-lane B fragment offset within a step (elems)
  const int blo = ((lane >> 4) * COUTW + zoff + (wn * NTW) * 16 + (lane & 15)) * 8;

  s16x8 b0h, b0l, b1h, b1l;
  {
    const unsigned short* p = wbe + blo;
    b0h = *reinterpret_cast<const s16x8*>(p);
    b0l = *reinterpret_cast<const s16x8*>(p + TOTB);
  }

  long bo = 0;
#pragma unroll 1
  for (int kc = 0; kc < KC; ++kc) {
#pragma unroll 1
    for (int tap = 0; tap < 9; ++tap) {
      const int dy = tap / 3, dx = tap % 3;
      const long bo_next = (tap < 8) ? bo + (long)KC * BSTEP
                                     : ((kc + 1 < KC) ? (long)(kc + 1) * BSTEP : 0);

      s16x8 ah[2], al[2];
      {
        int ci8 = lane >> 4;
        int m = lane & 15;
#pragma unroll
        for (int mt2 = 0; mt2 < 2; ++mt2) {
          int px = (wm * 2 + mt2) * 16 + m;
          int r = px >> 6, x = px & 63;
          int aoff = ci8 * AST + ((r + dy) * 66 + (x + dx)) * 8;
          ah[mt2] = *reinterpret_cast<const s16x8*>(&Abuf[aoff]);
          al[mt2] = *reinterpret_cast<const s16x8*>(&Abuf[APL + aoff]);
        }
      }

#pragma unroll
      for (int nt = 0; nt < NTW; ++nt) {
        const long nboff = (nt + 1 < NTW) ? (bo + (long)(nt + 1) * 128) : bo_next;
        const unsigned short* np = wbe + nboff + blo;
        if ((nt & 1) == 0) {
          b1h = *reinterpret_cast<const s16x8*>(np);
          b1l = *reinterpret_cast<const s16x8*>(np + TOTB);
        } else {
          b0h = *reinterpret_cast<const s16x8*>(np);
          b0l = *reinterpret_cast<const s16x8*>(np + TOTB);
        }
        const s16x8 bh = (nt & 1) ? b1h : b0h;
        const s16x8 bl = (nt & 1) ? b1l : b0l;
#pragma unroll
        for (int mt2 = 0; mt2 < 2; ++mt2) {
          acc[mt2][nt] = __builtin_amdgcn_mfma_f32_16x16x32_bf16(ah[mt2], bh, acc[mt2][nt], 0, 0, 0);
          acc[mt2][nt] = __builtin_amdgcn_mfma_f32_16x16x32_bf16(al[mt2], bh, acc[mt2][nt], 0, 0, 0);
          acc[mt2][nt] = __builtin_amdgcn_mfma_f32_16x16x32_bf16(ah[mt2], bl, acc[mt2][nt], 0, 0, 0);
        }
      }
      if constexpr (NTW & 1) {
        b0h = b1h; b0l = b1l;
      }
      bo = bo_next;
    }
    if (kc + 1 < KC) {
      __syncthreads();
      stageA(kc + 1);
      __syncthreads();
    }
  }

  // ---- epilogue ----
#pragma unroll
  for (int mt2 = 0; mt2 < 2; ++mt2) {
#pragma unroll
    for (int nt = 0; nt < NTW; ++nt) {
      int co = zoff + (wn * NTW + nt) * 16 + (lane & 15);
      if (COUTW > COUT && co >= COUT) continue;
#pragma unroll
      for (int r = 0; r < 4; ++r) {
        int px = (wm * 2 + mt2) * 16 + (lane >> 4) * 4 + r;
        float v = acc[mt2][nt][r];
        if constexpr (ACT == ACT_LRELU) v = v >= 0.f ? v : 0.1f * v;
        if constexpr (ACT == ACT_SIG144) {
          if (co >= 144) v = 1.f / (1.f + expf(-v));
        }
        if constexpr (OMODE == OUT_FLAT) {
          const long obase = (long)iz * PIXN + blockIdx.x * 128;
          out[(obase + px) * COUT + co] = v;
        } else {
          long oo = (long)iz * ((long)COUT * PIXN) + (long)co * PIXN + blockIdx.x * 128 + px;
          out[oo] = v + resid[oo];
        }
      }
    }
  }
}

// ---------------- attn v3: 2 px/wave, 3 ch/lane, LDS-precomputed bilinear setup ----------------
#define CWSLOT 580  // 72*8 + 4 pad
__global__ __launch_bounds__(256) void attn3_k(const float* __restrict__ qkv,
                                               const float* __restrict__ om,
                                               float* __restrict__ w_buf,
                                               f16* __restrict__ vre) {
  const int pair = blockIdx.y;
  const int jj = pair >> 1, rr = pair & 1;
  const int ii = (rr == 0) ? (jj == 0 ? 1 : 0) : (jj == 2 ? 1 : 2);
  const int wv = threadIdx.x >> 6;
  const int lane = threadIdx.x & 63;
  const int bp0 = blockIdx.x * 8 + wv * 2;  // even; both px same b

  __shared__ float s_om[8 * 216];
  __shared__ float s_cw[8 * CWSLOT];

  {
    const float* omrow = om + ((long)pair * 16384 + bp0) * 216;
    float* dst = s_om + wv * 432;
    for (int i = lane; i < 432; i += 64) dst[i] = omrow[i];
  }
  __syncthreads();

  for (int t = lane; t < 144; t += 64) {
    int ph = t / 72, cmb = t - ph * 72;
    int g = cmb / 9, n = cmb - g * 9;
    int p = (bp0 + ph) & 4095;
    int y = p >> 6, x = p & 63;
    const float* so = s_om + (wv * 2 + ph) * 216;
    float oy = so[g * 9 + n], ox = so[72 + g * 9 + n], m = so[144 + g * 9 + n];
    float py = oy + (float)(y + n / 3 - 1);
    float px = ox + (float)(x + n % 3 - 1);
    float y0f = floorf(py), x0f = floorf(px);
    float wy = py - y0f, wx = px - x0f;
    float* dst = s_cw + (wv * 2 + ph) * CWSLOT + cmb * 8;
#pragma unroll
    for (int dy = 0; dy < 2; ++dy) {
#pragma unroll
      for (int dx = 0; dx < 2; ++dx) {
        float yc = y0f + dy, xc = x0f + dx;
        bool valid = (yc >= 0.f) & (yc < 64.f) & (xc >= 0.f) & (xc < 64.f);
        float w = (dy ? wy : 1.f - wy) * (dx ? wx : 1.f - wx) * m;
        w = valid ? w : 0.f;
        int yi = (int)fminf(fmaxf(yc, 0.f), 63.f);
        int xi = (int)fminf(fmaxf(xc, 0.f), 63.f);
        int idx = (yi * 64 + xi) * 288 + 96;  // K base; V adds +96
        dst[dy * 2 + dx] = w;
        dst[4 + dy * 2 + dx] = __int_as_float(idx);
      }
    }
  }
  __syncthreads();

  const int ph = lane >> 5;
  const int li = lane & 31;
  const int bp = bp0 + ph;
  const int b = bp >> 12;
  const int cb = li * 3;
  const int g = li >> 2;
  const float* kimg = qkv + (long)(b * 3 + ii) * (PIXN * 288);
  const float* qrow = qkv + ((long)(b * 3 + jj) * PIXN + (bp & 4095)) * 288 + cb;
  const float q0 = qrow[0], q1 = qrow[1], q2 = qrow[2];
  const float* cw = s_cw + (wv * 2 + ph) * CWSLOT + g * 9 * 8;

  float ka[9][3];
  float rel[9];
#pragma unroll
  for (int n = 0; n < 9; ++n) {
    float4 w4 = *reinterpret_cast<const float4*>(cw + n * 8);
    float4 i4 = *reinterpret_cast<const float4*>(cw + n * 8 + 4);
    int ia = __float_as_int(i4.x) + cb, ib = __float_as_int(i4.y) + cb;
    int ic = __float_as_int(i4.z) + cb, id = __float_as_int(i4.w) + cb;
#pragma unroll
    for (int j = 0; j < 3; ++j) {
      float a = w4.x * kimg[ia + j];
      a = fmaf(w4.y, kimg[ib + j], a);
      a = fmaf(w4.z, kimg[ic + j], a);
      a = fmaf(w4.w, kimg[id + j], a);
      ka[n][j] = a;
    }
    float part = q0 * ka[n][0];
    part = fmaf(q1, ka[n][1], part);
    part = fmaf(q2, ka[n][2], part);
#pragma unroll
    for (int off = 16; off > 0; off >>= 1) part += __shfl_xor(part, off, 64);
    rel[n] = part;
  }

  int i0 = 0; float v0 = rel[0];
  float ks0a = ka[0][0], ks0b = ka[0][1], ks0c = ka[0][2];
#pragma unroll
  for (int n = 1; n < 9; ++n) {
    bool t = rel[n] > v0;
    v0 = t ? rel[n] : v0; i0 = t ? n : i0;
    ks0a = t ? ka[n][0] : ks0a; ks0b = t ? ka[n][1] : ks0b; ks0c = t ? ka[n][2] : ks0c;
  }
  int i1 = 0; float v1 = -3.4e38f;
  float ks1a = 0.f, ks1b = 0.f, ks1c = 0.f;
#pragma unroll
  for (int n = 0; n < 9; ++n) {
    bool t = (n != i0) && rel[n] > v1;
    v1 = t ? rel[n] : v1; i1 = t ? n : i1;
    ks1a = t ? ka[n][0] : ks1a; ks1b = t ? ka[n][1] : ks1b; ks1c = t ? ka[n][2] : ks1c;
  }
  float e = expf(v1 - v0);
  float cw0 = 1.f / (1.f + e), cw1 = e * cw0;

  float wpart = q0 * (cw0 * ks0a + cw1 * ks1a);
  wpart = fmaf(q1, cw0 * ks0b + cw1 * ks1b, wpart);
  wpart = fmaf(q2, cw0 * ks0c + cw1 * ks1c, wpart);
#pragma unroll
  for (int off = 16; off > 0; off >>= 1) wpart += __shfl_xor(wpart, off, 64);
  if (li == 0) w_buf[(long)pair * 16384 + bp] = wpart;

  float4 wA = *reinterpret_cast<const float4*>(cw + i0 * 8);
  float4 iA = *reinterpret_cast<const float4*>(cw + i0 * 8 + 4);
  float4 wB = *reinterpret_cast<const float4*>(cw + i1 * 8);
  float4 iB = *reinterpret_cast<const float4*>(cw + i1 * 8 + 4);
  int a0 = __float_as_int(iA.x) + 96 + cb, a1 = __float_as_int(iA.y) + 96 + cb;
  int a2 = __float_as_int(iA.z) + 96 + cb, a3 = __float_as_int(iA.w) + 96 + cb;
  int b0 = __float_as_int(iB.x) + 96 + cb, b1 = __float_as_int(iB.y) + 96 + cb;
  int b2 = __float_as_int(iB.z) + 96 + cb, b3 = __float_as_int(iB.w) + 96 + cb;
  f16* vrow = vre + ((long)pair * 16384 + bp) * 96 + cb;
#pragma unroll
  for (int j = 0; j < 3; ++j) {
    float va = wA.x * kimg[a0 + j];
    va = fmaf(wA.y, kimg[a1 + j], va);
    va = fmaf(wA.z, kimg[a2 + j], va);
    va = fmaf(wA.w, kimg[a3 + j], va);
    float vb = wB.x * kimg[b0 + j];
    vb = fmaf(wB.y, kimg[b1 + j], vb);
    vb = fmaf(wB.z, kimg[b2 + j], vb);
    vb = fmaf(wB.w, kimg[b3 + j], vb);
    vrow[j] = f2h(cw0 * va + cw1 * vb);
  }
}

// ---------------- merge: softmax over the 2 source frames -> f_t fp32 flat ----------------
__global__ __launch_bounds__(256) void merge_k(const float* __restrict__ w_buf,
                                               const f16* __restrict__ vre,
                                               float* __restrict__ f_t) {
  long idx = (long)blockIdx.x * 256 + threadIdx.x;
  const long TOT = (long)4 * 3 * PIXN * 24;
  if (idx >= TOT) return;
  int c4 = idx % 24;
  long t = idx / 24;
  int p = t % PIXN;
  long t2 = t / PIXN;
  int jj = t2 % 3;
  int b = (int)(t2 / 3);
  long bpi = (long)b * PIXN + p;
  int pr0 = jj * 2, pr1 = jj * 2 + 1;
  float w0 = w_buf[(long)pr0 * 16384 + bpi];
  float w1 = w_buf[(long)pr1 * 16384 + bpi];
  float mx = fmaxf(w0, w1);
  float e0 = expf(w0 - mx), e1 = expf(w1 - mx);
  float inv = 1.f / (e0 + e1);
  float s0 = e0 * inv, s1 = e1 * inv;
  const f16* va = &vre[((long)pr0 * 16384 + bpi) * 96 + c4 * 4];
  const f16* vb = &vre[((long)pr1 * 16384 + bpi) * 96 + c4 * 4];
  float4 r;
  r.x = s0 * h2f(va[0]) + s1 * h2f(vb[0]);
  r.y = s0 * h2f(va[1]) + s1 * h2f(vb[1]);
  r.z = s0 * h2f(va[2]) + s1 * h2f(vb[2]);
  r.w = s0 * h2f(va[3]) + s1 * h2f(vb[3]);
  *reinterpret_cast<float4*>(f_t + ((long)(b * 3 + jj) * PIXN + p) * 96 + c4 * 4) = r;
}

// ---------------- host ----------------
extern "C" void kernel_launch(void* const* d_in, const int* in_sizes, int n_in,
                              void* d_out, int out_size, void* d_ws, size_t ws_size,
                              hipStream_t stream) {
  const float* fea = (const float*)d_in[0];
  const float* cf_w = (const float*)d_in[1];
  const float* cf_b = (const float*)d_in[2];
  const float* wq = (const float*)d_in[3];
  const float* bq = (const float*)d_in[4];
  const float* wk = (const float*)d_in[5];
  const float* bk = (const float*)d_in[6];
  const float* wv = (const float*)d_in[7];
  const float* bv = (const float*)d_in[8];
  const float* oc1_w = (const float*)d_in[9];
  const float* oc1_b = (const float*)d_in[10];
  const float* oc2_w = (const float*)d_in[11];
  const float* oc2_b = (const float*)d_in[12];
  const float* om_w = (const float*)d_in[13];
  const float* om_b = (const float*)d_in[14];
  const float* cl_w = (const float*)d_in[15];
  const float* cl_b = (const float*)d_in[16];

  char* base = (char*)d_ws;
  size_t o = 0;
  auto carve = [&](size_t bytes) { char* p = base + o; o += (bytes + 255) & ~255UL; return p; };

  unsigned short* WBQ = (unsigned short*)carve(2UL * 165888 * 2);  // composite qkv conv
  float* BQ = (float*)carve(288UL * 4);
  unsigned short* WB1 = (unsigned short*)carve(2UL * 2 * 82944 * 2);  // [sel][hi|lo]
  unsigned short* WB2 = (unsigned short*)carve(2UL * 82944 * 2);
  unsigned short* WB3 = (unsigned short*)carve(2UL * 193536 * 2);
  unsigned short* WB4 = (unsigned short*)carve(2UL * 55296 * 2);
  unsigned short* feaH = (unsigned short*)carve(12UL * PIXN * 64 * 2);
  unsigned short* feaL = (unsigned short*)carve(12UL * PIXN * 64 * 2);

  float* om_t = (float*)carve(21233664UL * 4);
  float* qkv_t = (float*)carve(14155776UL * 4);
  float* U_t = (float*)carve(4718592UL * 4);
  float* V_t = (float*)carve(4718592UL * 4);   // must stay contiguous after U_t
  float* off2_t = (float*)carve(9437184UL * 4);
  float* w_buf = (float*)carve(98304UL * 4);
  float* f_t = U_t;
  f16* vre_b = (f16*)V_t;

  // --- weight prep (6 jobs on grid.y) ---
  prep_all<<<dim3(756, 6), 256, 0, stream>>>(cf_w, oc1_w, oc2_w, om_w, cl_w,
                                             wq, wk, wv, bq, bk, bv, cf_b,
                                             WBQ, BQ, WB1, WB2, WB3, WB4);

  // --- fea NCHW -> flat bf16 hi/lo planes ---
  nchw2bf<<<dim3(64, 12), 256, 0, stream>>>(fea, feaH, feaL);

  // --- fused emb+qkv conv (MFMA bf16x3, composite weights), co split in 3 ---
  conv3x3r<64, 288, 288, 3, IN_BF, ACT_NONE, OUT_FLAT><<<dim3(32, 12, 3), 512, 0, stream>>>(
      (const float*)feaH, (const float*)feaL, nullptr, WBQ, BQ, qkv_t, nullptr);

  // --- off1 split (MFMA bf16x3): U = convA(q_img), V = convB(k_img) ---
  conv3x3r<96, 96, 96, 1, IN_QKV, ACT_NONE, OUT_FLAT><<<dim3(32, 24, 1), 512, 0, stream>>>(
      qkv_t, nullptr, nullptr, WB1, nullptr, U_t, nullptr);

  // --- off2 (MFMA bf16x3) with fused off1 epilogue: stage lrelu(U+V+b1) ---
  conv3x3r<96, 96, 96, 1, IN_UVPAIR, ACT_LRELU, OUT_FLAT><<<dim3(32, 24, 1), 512, 0, stream>>>(
      U_t, V_t, oc1_b, WB2, oc2_b, off2_t, nullptr);

  // --- om conv (MFMA bf16x3, COUT 216 padded to 224) + fused sigmoid ---
  conv3x3r<96, 216, 224, 1, IN_FLAT, ACT_SIG144, OUT_FLAT><<<dim3(32, 24, 1), 512, 0, stream>>>(
      off2_t, nullptr, nullptr, WB3, om_b, om_t, nullptr);

  // --- fused deformable attention (fp32; 2 px/wave, 3 ch/lane, LDS setup) ---
  attn3_k<<<dim3(2048, 6), 256, 0, stream>>>(qkv_t, om_t, w_buf, vre_b);
  merge_k<<<4608, 256, 0, stream>>>(w_buf, vre_b, f_t);

  // --- final conv (MFMA bf16x3) + residual -> NCHW fp32 ---
  conv3x3r<96, 64, 64, 1, IN_FLAT, ACT_NONE, OUT_NCHWRES><<<dim3(32, 12, 1), 512, 0, stream>>>(
      f_t, nullptr, nullptr, WB4, cl_b, (float*)d_out, fea);
}

// Round 6
// 491.617 us; speedup vs baseline: 3.4930x; 1.0495x over previous
//
#include <hip/hip_runtime.h>
#include <math.h>

#define PIXN 4096

typedef _Float16 f16;
typedef short s16x8 __attribute__((ext_vector_type(8)));
typedef unsigned short u16x4 __attribute__((ext_vector_type(4)));
typedef float f32x4 __attribute__((ext_vector_type(4)));

__device__ __forceinline__ f16 f2h(float f) { return (f16)f; }
__device__ __forceinline__ float h2f(f16 h) { return (float)h; }

// bf16 round-to-nearest-even via bit trick; residual f - bf2f(f2bf(f)) is exact in fp32.
__device__ __forceinline__ unsigned short f2bf(float f) {
  unsigned u = __float_as_uint(f);
  u += 0x7fffu + ((u >> 16) & 1u);
  return (unsigned short)(u >> 16);
}
__device__ __forceinline__ float bf2f(unsigned short h) {
  return __uint_as_float(((unsigned)h) << 16);
}

enum { ACT_NONE = 0, ACT_LRELU = 1, ACT_SIG144 = 2 };
enum { IN_FLAT = 1, IN_UVPAIR = 2, IN_QKV = 3, IN_BF = 4 };
enum { OUT_FLAT = 0, OUT_NCHWRES = 1 };

// ---------------- weight prep ----------------
// MFMA weight prep: layout [tap][kc][kch][co][8e], hi plane then lo plane (each `total` elems).
__device__ __forceinline__ void wprep_mfma(const float* __restrict__ w, unsigned short* __restrict__ dst,
                                           int srcCIN, int cinOff, int COUTv, int COUTP,
                                           int total, int idx) {
  if (idx >= total) return;
  int e = idx & 7;
  int t = idx >> 3;
  int co = t % COUTP; t /= COUTP;
  int kch = t & 3; t >>= 2;
  int kc = t % 3;
  int tap = t / 3;
  int ci = kc * 32 + kch * 8 + e;
  float v = 0.f;
  if (co < COUTv) v = w[((long)co * srcCIN + cinOff + ci) * 9 + tap];
  unsigned short h = f2bf(v);
  dst[idx] = h;
  dst[total + idx] = f2bf(v - bf2f(h));
}

__global__ __launch_bounds__(256) void prep_all(
    const float* __restrict__ cf_w, const float* __restrict__ oc1_w,
    const float* __restrict__ oc2_w, const float* __restrict__ om_w,
    const float* __restrict__ cl_w,
    const float* __restrict__ wq, const float* __restrict__ wk, const float* __restrict__ wv,
    const float* __restrict__ bq, const float* __restrict__ bk, const float* __restrict__ bv,
    const float* __restrict__ cf_b,
    unsigned short* __restrict__ WBQ, float* __restrict__ BQ,
    unsigned short* __restrict__ WB1, unsigned short* __restrict__ WB2,
    unsigned short* __restrict__ WB3, unsigned short* __restrict__ WB4) {
  int idx = blockIdx.x * 256 + threadIdx.x;
  switch (blockIdx.y) {
    case 0: {  // composite qkv conv: W'[co,ci,tap] = sum_e wsel[co,e] * cf_w[e,ci,tap]
      if (idx < 288) {
        int m = idx / 96, ep = idx % 96;
        const float* wm = (m == 0) ? wq : (m == 1) ? wk : wv;
        const float* bm = (m == 0) ? bq : (m == 1) ? bk : bv;
        float s = bm[ep];
        for (int c = 0; c < 96; ++c) s = fmaf(wm[ep * 96 + c], cf_b[c], s);
        BQ[idx] = s;
      }
      if (idx < 165888) {
        int e = idx & 7;
        int t = idx >> 3;
        int co = t % 288; t /= 288;
        int kch = t & 3; t >>= 2;
        int kc = t & 1, tap = t >> 1;     // [tap][kc(2)][kch]
        int ci = kc * 32 + kch * 8 + e;
        int m = co / 96, ep = co % 96;
        const float* wm = (m == 0) ? wq : (m == 1) ? wk : wv;
        float s = 0.f;
        for (int c = 0; c < 96; ++c)
          s = fmaf(wm[ep * 96 + c], cf_w[((long)c * 64 + ci) * 9 + tap], s);
        unsigned short h = f2bf(s);
        WBQ[idx] = h;
        WBQ[165888 + idx] = f2bf(s - bf2f(h));
      }
      break;
    }
    case 1: wprep_mfma(oc1_w, WB1, 192, 0, 96, 96, 82944, idx); break;
    case 2: wprep_mfma(oc1_w, WB1 + 2 * 82944, 192, 96, 96, 96, 82944, idx); break;
    case 3: wprep_mfma(oc2_w, WB2, 96, 0, 96, 96, 82944, idx); break;
    case 4: wprep_mfma(om_w, WB3, 96, 0, 216, 256, 221184, idx); break;
    default: wprep_mfma(cl_w, WB4, 96, 0, 64, 64, 55296, idx); break;
  }
}

// ---------------- fea NCHW fp32 -> flat [img][px][64] bf16 hi/lo planes ----------------
__global__ __launch_bounds__(256) void nchw2bf(const float* __restrict__ fea,
                                               unsigned short* __restrict__ hi,
                                               unsigned short* __restrict__ lo) {
  const int y = blockIdx.x;
  const int img = blockIdx.y;
  const int t = threadIdx.x;
  const int x = t & 63, cg = t >> 6;
  __shared__ unsigned short sh[64][68], sl[64][68];
  const float* base = fea + ((long)img * 64) * PIXN + y * 64;
#pragma unroll
  for (int k = 0; k < 16; ++k) {
    int ci = cg * 16 + k;
    float v = base[(long)ci * PIXN + x];
    unsigned short h = f2bf(v);
    sh[x][ci] = h;
    sl[x][ci] = f2bf(v - bf2f(h));
  }
  __syncthreads();
  const long ob = (long)img * PIXN + y * 64;
  for (int i = t; i < 2048; i += 256) {
    int plane = i >> 10;
    int r = i & 1023;
    int px = r >> 4, q4 = r & 15;
    u16x4 v4 = *reinterpret_cast<const u16x4*>(plane ? &sl[px][q4 * 4] : &sh[px][q4 * 4]);
    unsigned short* dst = (plane ? lo : hi) + (ob + px) * 64 + q4 * 4;
    *reinterpret_cast<u16x4*>(dst) = v4;
  }
}

// ---------------- bf16x3-split MFMA 3x3 conv, B direct-from-L2, full-step prefetch ----------------
// Block: 512 thr = 8 waves as (WM=8/WN) m-waves x WN n-waves; tile = 128 px x COG.
// Each wave: MT=WN m-tiles of 16 px, NTW = COG/(WN*16) n-tiles.
// A in LDS per-kc (34 KB).  B fragments lane-addressable in [tap][kc][kch][co][8]
// layout; entire NEXT K-step prefetched into a register bank (pb) while current
// (cb) feeds MFMAs -> L2 latency hidden by a full step's MFMA cluster.
template <int CIN, int COUT, int COUTW, int NCOG, int IMODE, int ACT, int OMODE, int WN>
__global__ __launch_bounds__(512, 4) void conv3x3r(
    const float* __restrict__ in, const float* __restrict__ in2,
    const float* __restrict__ bias_in,
    const unsigned short* __restrict__ WB,
    const float* __restrict__ bias,
    float* __restrict__ out,
    const float* __restrict__ resid) {
  constexpr int KC = CIN / 32;             // 2 or 3
  constexpr int WM = 8 / WN;
  constexpr int MT = WN;                   // m-tiles per wave (M=128 total)
  constexpr int COG = COUTW / NCOG;
  constexpr int NTW = COG / (WN * 16);     // n-tiles per wave
  constexpr int AST = 4 * 66 * 8 + 8;      // padded ci8 stride (elems)
  constexpr int APL = 4 * AST;             // per-plane A elems (one kc = 4 ci8)
  constexpr int BSTEP = COUTW * 32;        // per-plane B elems per K-step
  constexpr int TOTB = 9 * KC * BSTEP;     // per-plane B elems total

  __shared__ __align__(16) unsigned short Abuf[2 * APL];

  const int tid = threadIdx.x;
  const int lane = tid & 63;
  const int wid = tid >> 6;
  const int wm = wid % WM;
  const int wn = wid / WM;
  const int iz = blockIdx.y;
  const int y0 = blockIdx.x * 2;
  const int zoff = (NCOG > 1) ? blockIdx.z * COG : 0;

  const float* baseA = nullptr;
  const float* baseB2 = nullptr;
  const unsigned short* hpl = nullptr;
  const unsigned short* lpl = nullptr;
  const unsigned short* wbe = WB;
  int LDV = CIN;
  if constexpr (IMODE == IN_UVPAIR) {
    int pair = iz >> 2, b = iz & 3;
    int jj = pair >> 1, rr2 = pair & 1;
    int ii = (rr2 == 0) ? (jj == 0 ? 1 : 0) : (jj == 2 ? 1 : 2);
    baseA = in + (long)(b * 3 + jj) * (PIXN * 96);
    baseB2 = in2 + (long)(b * 3 + ii) * (PIXN * 96);
    LDV = 96;
  } else if constexpr (IMODE == IN_QKV) {
    int sel = iz / 12, img = iz % 12;
    baseA = in + (long)img * (PIXN * 288) + sel * 96;
    wbe = WB + (long)sel * (2 * TOTB);
    LDV = 288;
  } else if constexpr (IMODE == IN_BF) {
    hpl = reinterpret_cast<const unsigned short*>(in) + (long)iz * (PIXN * 64);
    lpl = reinterpret_cast<const unsigned short*>(in2) + (long)iz * (PIXN * 64);
  } else {
    baseA = in + (long)iz * ((long)PIXN * CIN);
    LDV = CIN;
  }

  // ---- stage A for one kc group (32 ci) ----
  auto stageA = [&](int kc) {
    if constexpr (IMODE == IN_BF) {
      for (int i = tid; i < 4 * 66 * 4; i += 512) {
        int ci8 = i & 3;
        int t = i >> 2;
        int xp = t % 66, rr = t / 66;
        int y = y0 + rr - 1, x = xp - 1;
        s16x8 hv = {0, 0, 0, 0, 0, 0, 0, 0};
        s16x8 lv = {0, 0, 0, 0, 0, 0, 0, 0};
        if ((unsigned)y < 64u && (unsigned)x < 64u) {
          long off = (long)(y * 64 + x) * 64 + kc * 32 + ci8 * 8;
          hv = *reinterpret_cast<const s16x8*>(hpl + off);
          lv = *reinterpret_cast<const s16x8*>(lpl + off);
        }
        int base = ci8 * AST + (rr * 66 + xp) * 8;
        *reinterpret_cast<s16x8*>(&Abuf[base]) = hv;
        *reinterpret_cast<s16x8*>(&Abuf[APL + base]) = lv;
      }
    } else {
      for (int i = tid; i < 4 * 66 * 8; i += 512) {
        int ci4 = i & 7;
        int t = i >> 3;
        int xp = t % 66, rr = t / 66;
        int y = y0 + rr - 1, x = xp - 1;
        float4 v = make_float4(0.f, 0.f, 0.f, 0.f);
        if ((unsigned)y < 64u && (unsigned)x < 64u) {
          long off = (long)(y * 64 + x) * LDV + kc * 32 + ci4 * 4;
          if constexpr (IMODE == IN_UVPAIR) {
            float4 u = *reinterpret_cast<const float4*>(baseA + off);
            float4 w2 = *reinterpret_cast<const float4*>(baseB2 + off);
            float4 bi = *reinterpret_cast<const float4*>(bias_in + kc * 32 + ci4 * 4);
            v.x = u.x + w2.x + bi.x; v.x = v.x >= 0.f ? v.x : 0.1f * v.x;
            v.y = u.y + w2.y + bi.y; v.y = v.y >= 0.f ? v.y : 0.1f * v.y;
            v.z = u.z + w2.z + bi.z; v.z = v.z >= 0.f ? v.z : 0.1f * v.z;
            v.w = u.w + w2.w + bi.w; v.w = v.w >= 0.f ? v.w : 0.1f * v.w;
          } else {
            v = *reinterpret_cast<const float4*>(baseA + off);
          }
        }
        unsigned short h0 = f2bf(v.x), h1 = f2bf(v.y), h2 = f2bf(v.z), h3 = f2bf(v.w);
        u16x4 hv = {h0, h1, h2, h3};
        u16x4 lv = {f2bf(v.x - bf2f(h0)), f2bf(v.y - bf2f(h1)),
                    f2bf(v.z - bf2f(h2)), f2bf(v.w - bf2f(h3))};
        int base = (ci4 >> 1) * AST + (rr * 66 + xp) * 8 + (ci4 & 1) * 4;
        *reinterpret_cast<u16x4*>(&Abuf[base]) = hv;
        *reinterpret_cast<u16x4*>(&Abuf[APL + base]) = lv;
      }
    }
  };

  // ---- init acc ----
  f32x4 acc[MT][NTW];
#pragma unroll
  for (int nt = 0; nt < NTW; ++nt) {
    int co = zoff + (wn * NTW + nt) * 16 + (lane & 15);
    float b0 = 0.f;
    if (bias != nullptr && co < COUT) b0 = bias[co];
#pragma unroll
    for (int mt = 0; mt < MT; ++mt) {
      acc[mt][nt][0] = b0; acc[mt][nt][1] = b0;
      acc[mt][nt][2] = b0; acc[mt][nt][3] = b0;
    }
  }

  stageA(0);
  __syncthreads();

  // per-lane B fragment offset within a step (elems)
  const int blo = ((lane >> 4) * COUTW + zoff + (wn * NTW) * 16 + (lane & 15)) * 8;

  s16x8 cbh[NTW], cbl[NTW], pbh[NTW], pbl[NTW];
#pragma unroll
  for (int nt = 0; nt < NTW; ++nt) {
    const unsigned short* p = wbe + (long)nt * 128 + blo;
    pbh[nt] = *reinterpret_cast<const s16x8*>(p);
    pbl[nt] = *reinterpret_cast<const s16x8*>(p + TOTB);
  }

  long bo = 0;
#pragma unroll 1
  for (int kc = 0; kc < KC; ++kc) {
#pragma unroll 1
    for (int tap = 0; tap < 9; ++tap) {
      const int dy = tap / 3, dx = tap % 3;
      const bool last = (kc == KC - 1) && (tap == 8);
      const long bo_next = (tap < 8) ? bo + (long)KC * BSTEP : (long)(kc + 1) * BSTEP;

      // rotate prefetched bank into current (v_mov, overlaps MFMA pipe)
#pragma unroll
      for (int nt = 0; nt < NTW; ++nt) { cbh[nt] = pbh[nt]; cbl[nt] = pbl[nt]; }
      // issue ENTIRE next-step B loads now -> full-cluster latency window
      if (!last) {
#pragma unroll
        for (int nt = 0; nt < NTW; ++nt) {
          const unsigned short* np = wbe + bo_next + (long)nt * 128 + blo;
          pbh[nt] = *reinterpret_cast<const s16x8*>(np);
          pbl[nt] = *reinterpret_cast<const s16x8*>(np + TOTB);
        }
      }

      // A fragments for this tap
      s16x8 ah[MT], al[MT];
      {
        int ci8 = lane >> 4;
        int m = lane & 15;
#pragma unroll
        for (int mt = 0; mt < MT; ++mt) {
          int px = (wm * MT + mt) * 16 + m;
          int r = px >> 6, x = px & 63;
          int aoff = ci8 * AST + ((r + dy) * 66 + (x + dx)) * 8;
          ah[mt] = *reinterpret_cast<const s16x8*>(&Abuf[aoff]);
          al[mt] = *reinterpret_cast<const s16x8*>(&Abuf[APL + aoff]);
        }
      }

#pragma unroll
      for (int nt = 0; nt < NTW; ++nt) {
#pragma unroll
        for (int mt = 0; mt < MT; ++mt) {
          acc[mt][nt] = __builtin_amdgcn_mfma_f32_16x16x32_bf16(ah[mt], cbh[nt], acc[mt][nt], 0, 0, 0);
          acc[mt][nt] = __builtin_amdgcn_mfma_f32_16x16x32_bf16(al[mt], cbh[nt], acc[mt][nt], 0, 0, 0);
          acc[mt][nt] = __builtin_amdgcn_mfma_f32_16x16x32_bf16(ah[mt], cbl[nt], acc[mt][nt], 0, 0, 0);
        }
      }
      bo = bo_next;
    }
    if (kc + 1 < KC) {
      __syncthreads();
      stageA(kc + 1);
      __syncthreads();
    }
  }

  // ---- epilogue ----
#pragma unroll
  for (int mt = 0; mt < MT; ++mt) {
#pragma unroll
    for (int nt = 0; nt < NTW; ++nt) {
      int co = zoff + (wn * NTW + nt) * 16 + (lane & 15);
      if (COUTW > COUT && co >= COUT) continue;
#pragma unroll
      for (int r = 0; r < 4; ++r) {
        int px = (wm * MT + mt) * 16 + (lane >> 4) * 4 + r;
        float v = acc[mt][nt][r];
        if constexpr (ACT == ACT_LRELU) v = v >= 0.f ? v : 0.1f * v;
        if constexpr (ACT == ACT_SIG144) {
          if (co >= 144) v = 1.f / (1.f + expf(-v));
        }
        if constexpr (OMODE == OUT_FLAT) {
          const long obase = (long)iz * PIXN + blockIdx.x * 128;
          out[(obase + px) * COUT + co] = v;
        } else {
          long oo = (long)iz * ((long)COUT * PIXN) + (long)co * PIXN + blockIdx.x * 128 + px;
          out[oo] = v + resid[oo];
        }
      }
    }
  }
}

// ---------------- attn v3: 2 px/wave, 3 ch/lane, LDS-precomputed bilinear setup ----------------
#define CWSLOT 580  // 72*8 + 4 pad
__global__ __launch_bounds__(256) void attn3_k(const float* __restrict__ qkv,
                                               const float* __restrict__ om,
                                               float* __restrict__ w_buf,
                                               f16* __restrict__ vre) {
  const int pair = blockIdx.y;
  const int jj = pair >> 1, rr = pair & 1;
  const int ii = (rr == 0) ? (jj == 0 ? 1 : 0) : (jj == 2 ? 1 : 2);
  const int wv = threadIdx.x >> 6;
  const int lane = threadIdx.x & 63;
  const int bp0 = blockIdx.x * 8 + wv * 2;  // even; both px same b

  __shared__ float s_om[8 * 216];
  __shared__ float s_cw[8 * CWSLOT];

  {
    const float* omrow = om + ((long)pair * 16384 + bp0) * 216;
    float* dst = s_om + wv * 432;
    for (int i = lane; i < 432; i += 64) dst[i] = omrow[i];
  }
  __syncthreads();

  for (int t = lane; t < 144; t += 64) {
    int ph = t / 72, cmb = t - ph * 72;
    int g = cmb / 9, n = cmb - g * 9;
    int p = (bp0 + ph) & 4095;
    int y = p >> 6, x = p & 63;
    const float* so = s_om + (wv * 2 + ph) * 216;
    float oy = so[g * 9 + n], ox = so[72 + g * 9 + n], m = so[144 + g * 9 + n];
    float py = oy + (float)(y + n / 3 - 1);
    float px = ox + (float)(x + n % 3 - 1);
    float y0f = floorf(py), x0f = floorf(px);
    float wy = py - y0f, wx = px - x0f;
    float* dst = s_cw + (wv * 2 + ph) * CWSLOT + cmb * 8;
#pragma unroll
    for (int dy = 0; dy < 2; ++dy) {
#pragma unroll
      for (int dx = 0; dx < 2; ++dx) {
        float yc = y0f + dy, xc = x0f + dx;
        bool valid = (yc >= 0.f) & (yc < 64.f) & (xc >= 0.f) & (xc < 64.f);
        float w = (dy ? wy : 1.f - wy) * (dx ? wx : 1.f - wx) * m;
        w = valid ? w : 0.f;
        int yi = (int)fminf(fmaxf(yc, 0.f), 63.f);
        int xi = (int)fminf(fmaxf(xc, 0.f), 63.f);
        int idx = (yi * 64 + xi) * 288 + 96;  // K base; V adds +96
        dst[dy * 2 + dx] = w;
        dst[4 + dy * 2 + dx] = __int_as_float(idx);
      }
    }
  }
  __syncthreads();

  const int ph = lane >> 5;
  const int li = lane & 31;
  const int bp = bp0 + ph;
  const int b = bp >> 12;
  const int cb = li * 3;
  const int g = li >> 2;
  const float* kimg = qkv + (long)(b * 3 + ii) * (PIXN * 288);
  const float* qrow = qkv + ((long)(b * 3 + jj) * PIXN + (bp & 4095)) * 288 + cb;
  const float q0 = qrow[0], q1 = qrow[1], q2 = qrow[2];
  const float* cw = s_cw + (wv * 2 + ph) * CWSLOT + g * 9 * 8;

  float ka[9][3];
  float rel[9];
#pragma unroll
  for (int n = 0; n < 9; ++n) {
    float4 w4 = *reinterpret_cast<const float4*>(cw + n * 8);
    float4 i4 = *reinterpret_cast<const float4*>(cw + n * 8 + 4);
    int ia = __float_as_int(i4.x) + cb, ib = __float_as_int(i4.y) + cb;
    int ic = __float_as_int(i4.z) + cb, id = __float_as_int(i4.w) + cb;
#pragma unroll
    for (int j = 0; j < 3; ++j) {
      float a = w4.x * kimg[ia + j];
      a = fmaf(w4.y, kimg[ib + j], a);
      a = fmaf(w4.z, kimg[ic + j], a);
      a = fmaf(w4.w, kimg[id + j], a);
      ka[n][j] = a;
    }
    float part = q0 * ka[n][0];
    part = fmaf(q1, ka[n][1], part);
    part = fmaf(q2, ka[n][2], part);
#pragma unroll
    for (int off = 16; off > 0; off >>= 1) part += __shfl_xor(part, off, 64);
    rel[n] = part;
  }

  int i0 = 0; float v0 = rel[0];
  float ks0a = ka[0][0], ks0b = ka[0][1], ks0c = ka[0][2];
#pragma unroll
  for (int n = 1; n < 9; ++n) {
    bool t = rel[n] > v0;
    v0 = t ? rel[n] : v0; i0 = t ? n : i0;
    ks0a = t ? ka[n][0] : ks0a; ks0b = t ? ka[n][1] : ks0b; ks0c = t ? ka[n][2] : ks0c;
  }
  int i1 = 0; float v1 = -3.4e38f;
  float ks1a = 0.f, ks1b = 0.f, ks1c = 0.f;
#pragma unroll
  for (int n = 0; n < 9; ++n) {
    bool t = (n != i0) && rel[n] > v1;
    v1 = t ? rel[n] : v1; i1 = t ? n : i1;
    ks1a = t ? ka[n][0] : ks1a; ks1b = t ? ka[n][1] : ks1b; ks1c = t ? ka[n][2] : ks1c;
  }
  float e = expf(v1 - v0);
  float cw0 = 1.f / (1.f + e), cw1 = e * cw0;

  float wpart = q0 * (cw0 * ks0a + cw1 * ks1a);
  wpart = fmaf(q1, cw0 * ks0b + cw1 * ks1b, wpart);
  wpart = fmaf(q2, cw0 * ks0c + cw1 * ks1c, wpart);
#pragma unroll
  for (int off = 16; off > 0; off >>= 1) wpart += __shfl_xor(wpart, off, 64);
  if (li == 0) w_buf[(long)pair * 16384 + bp] = wpart;

  float4 wA = *reinterpret_cast<const float4*>(cw + i0 * 8);
  float4 iA = *reinterpret_cast<const float4*>(cw + i0 * 8 + 4);
  float4 wB = *reinterpret_cast<const float4*>(cw + i1 * 8);
  float4 iB = *reinterpret_cast<const float4*>(cw + i1 * 8 + 4);
  int a0 = __float_as_int(iA.x) + 96 + cb, a1 = __float_as_int(iA.y) + 96 + cb;
  int a2 = __float_as_int(iA.z) + 96 + cb, a3 = __float_as_int(iA.w) + 96 + cb;
  int b0 = __float_as_int(iB.x) + 96 + cb, b1 = __float_as_int(iB.y) + 96 + cb;
  int b2 = __float_as_int(iB.z) + 96 + cb, b3 = __float_as_int(iB.w) + 96 + cb;
  f16* vrow = vre + ((long)pair * 16384 + bp) * 96 + cb;
#pragma unroll
  for (int j = 0; j < 3; ++j) {
    float va = wA.x * kimg[a0 + j];
    va = fmaf(wA.y, kimg[a1 + j], va);
    va = fmaf(wA.z, kimg[a2 + j], va);
    va = fmaf(wA.w, kimg[a3 + j], va);
    float vb = wB.x * kimg[b0 + j];
    vb = fmaf(wB.y, kimg[b1 + j], vb);
    vb = fmaf(wB.z, kimg[b2 + j], vb);
    vb = fmaf(wB.w, kimg[b3 + j], vb);
    vrow[j] = f2h(cw0 * va + cw1 * vb);
  }
}

// ---------------- merge: softmax over the 2 source frames -> f_t fp32 flat ----------------
__global__ __launch_bounds__(256) void merge_k(const float* __restrict__ w_buf,
                                               const f16* __restrict__ vre,
                                               float* __restrict__ f_t) {
  long idx = (long)blockIdx.x * 256 + threadIdx.x;
  const long TOT = (long)4 * 3 * PIXN * 24;
  if (idx >= TOT) return;
  int c4 = idx % 24;
  long t = idx / 24;
  int p = t % PIXN;
  long t2 = t / PIXN;
  int jj = t2 % 3;
  int b = (int)(t2 / 3);
  long bpi = (long)b * PIXN + p;
  int pr0 = jj * 2, pr1 = jj * 2 + 1;
  float w0 = w_buf[(long)pr0 * 16384 + bpi];
  float w1 = w_buf[(long)pr1 * 16384 + bpi];
  float mx = fmaxf(w0, w1);
  float e0 = expf(w0 - mx), e1 = expf(w1 - mx);
  float inv = 1.f / (e0 + e1);
  float s0 = e0 * inv, s1 = e1 * inv;
  const f16* va = &vre[((long)pr0 * 16384 + bpi) * 96 + c4 * 4];
  const f16* vb = &vre[((long)pr1 * 16384 + bpi) * 96 + c4 * 4];
  float4 r;
  r.x = s0 * h2f(va[0]) + s1 * h2f(vb[0]);
  r.y = s0 * h2f(va[1]) + s1 * h2f(vb[1]);
  r.z = s0 * h2f(va[2]) + s1 * h2f(vb[2]);
  r.w = s0 * h2f(va[3]) + s1 * h2f(vb[3]);
  *reinterpret_cast<float4*>(f_t + ((long)(b * 3 + jj) * PIXN + p) * 96 + c4 * 4) = r;
}

// ---------------- host ----------------
extern "C" void kernel_launch(void* const* d_in, const int* in_sizes, int n_in,
                              void* d_out, int out_size, void* d_ws, size_t ws_size,
                              hipStream_t stream) {
  const float* fea = (const float*)d_in[0];
  const float* cf_w = (const float*)d_in[1];
  const float* cf_b = (const float*)d_in[2];
  const float* wq = (const float*)d_in[3];
  const float* bq = (const float*)d_in[4];
  const float* wk = (const float*)d_in[5];
  const float* bk = (const float*)d_in[6];
  const float* wv = (const float*)d_in[7];
  const float* bv = (const float*)d_in[8];
  const float* oc1_w = (const float*)d_in[9];
  const float* oc1_b = (const float*)d_in[10];
  const float* oc2_w = (const float*)d_in[11];
  const float* oc2_b = (const float*)d_in[12];
  const float* om_w = (const float*)d_in[13];
  const float* om_b = (const float*)d_in[14];
  const float* cl_w = (const float*)d_in[15];
  const float* cl_b = (const float*)d_in[16];

  char* base = (char*)d_ws;
  size_t o = 0;
  auto carve = [&](size_t bytes) { char* p = base + o; o += (bytes + 255) & ~255UL; return p; };

  unsigned short* WBQ = (unsigned short*)carve(2UL * 165888 * 2);  // composite qkv conv
  float* BQ = (float*)carve(288UL * 4);
  unsigned short* WB1 = (unsigned short*)carve(2UL * 2 * 82944 * 2);  // [sel][hi|lo]
  unsigned short* WB2 = (unsigned short*)carve(2UL * 82944 * 2);
  unsigned short* WB3 = (unsigned short*)carve(2UL * 221184 * 2);     // om, COUTP=256
  unsigned short* WB4 = (unsigned short*)carve(2UL * 55296 * 2);
  unsigned short* feaH = (unsigned short*)carve(12UL * PIXN * 64 * 2);
  unsigned short* feaL = (unsigned short*)carve(12UL * PIXN * 64 * 2);

  float* om_t = (float*)carve(21233664UL * 4);
  float* qkv_t = (float*)carve(14155776UL * 4);
  float* U_t = (float*)carve(4718592UL * 4);
  float* V_t = (float*)carve(4718592UL * 4);   // must stay contiguous after U_t
  float* off2_t = (float*)carve(9437184UL * 4);
  float* w_buf = (float*)carve(98304UL * 4);
  float* f_t = U_t;
  f16* vre_b = (f16*)V_t;

  // --- weight prep (6 jobs on grid.y; x covers max total 221184) ---
  prep_all<<<dim3(864, 6), 256, 0, stream>>>(cf_w, oc1_w, oc2_w, om_w, cl_w,
                                             wq, wk, wv, bq, bk, bv, cf_b,
                                             WBQ, BQ, WB1, WB2, WB3, WB4);

  // --- fea NCHW -> flat bf16 hi/lo planes ---
  nchw2bf<<<dim3(64, 12), 256, 0, stream>>>(fea, feaH, feaL);

  // --- fused emb+qkv conv (MFMA bf16x3, composite weights), co split in 3 ---
  conv3x3r<64, 288, 288, 3, IN_BF, ACT_NONE, OUT_FLAT, 2><<<dim3(32, 12, 3), 512, 0, stream>>>(
      (const float*)feaH, (const float*)feaL, nullptr, WBQ, BQ, qkv_t, nullptr);

  // --- off1 split (MFMA bf16x3): U = convA(q_img), V = convB(k_img) ---
  conv3x3r<96, 96, 96, 1, IN_QKV, ACT_NONE, OUT_FLAT, 2><<<dim3(32, 24, 1), 512, 0, stream>>>(
      qkv_t, nullptr, nullptr, WB1, nullptr, U_t, nullptr);

  // --- off2 (MFMA bf16x3) with fused off1 epilogue: stage lrelu(U+V+b1) ---
  conv3x3r<96, 96, 96, 1, IN_UVPAIR, ACT_LRELU, OUT_FLAT, 2><<<dim3(32, 24, 1), 512, 0, stream>>>(
      U_t, V_t, oc1_b, WB2, oc2_b, off2_t, nullptr);

  // --- om conv (MFMA bf16x3, COUT 216 padded to 256, 2 co-groups, WN=4) + sigmoid ---
  conv3x3r<96, 216, 256, 2, IN_FLAT, ACT_SIG144, OUT_FLAT, 4><<<dim3(32, 24, 2), 512, 0, stream>>>(
      off2_t, nullptr, nullptr, WB3, om_b, om_t, nullptr);

  // --- fused deformable attention (fp32; 2 px/wave, 3 ch/lane, LDS setup) ---
  attn3_k<<<dim3(2048, 6), 256, 0, stream>>>(qkv_t, om_t, w_buf, vre_b);
  merge_k<<<4608, 256, 0, stream>>>(w_buf, vre_b, f_t);

  // --- final conv (MFMA bf16x3) + residual -> NCHW fp32 ---
  conv3x3r<96, 64, 64, 1, IN_FLAT, ACT_NONE, OUT_NCHWRES, 2><<<dim3(32, 12, 1), 512, 0, stream>>>(
      f_t, nullptr, nullptr, WB4, cl_b, (float*)d_out, fea);
}